// Round 11
// baseline (4303.799 us; speedup 1.0000x reference)
//
#include <hip/hip_runtime.h>
#include <math.h>

namespace {

constexpr int cB = 32, cL = 1024, cCIN = 32, cDM = 512, cDFF = 2048;
constexpr int cH = 8, cE = 64, cM = 64, cPRED = 256;
constexpr int M2 = 2 * cM; // 128

typedef __attribute__((ext_vector_type(8))) short short8v;
typedef __attribute__((ext_vector_type(4))) float float4v;

__device__ inline unsigned short f2bf(float f) {
  unsigned int u = __builtin_bit_cast(unsigned int, f);
  u += 0x7FFFu + ((u >> 16) & 1u); // RNE
  return (unsigned short)(u >> 16);
}
__device__ inline float bf2f(unsigned short s) {
  return __builtin_bit_cast(float, (unsigned int)s << 16);
}

typedef const __attribute__((address_space(1))) unsigned int gu32_t;
typedef __attribute__((address_space(3))) unsigned int lu32_t;
__device__ inline void gld16(const void* g, void* l) {
  __builtin_amdgcn_global_load_lds((gu32_t*)g, (lu32_t*)l, 16, 0, 0);
}

// ================= one-time tables =================
__global__ void basis_kernel(short* __restrict__ basisdb, short* __restrict__ basisib) {
  int idx = blockIdx.x * 256 + threadIdx.x;
  if (idx >= M2 * cL) return;
  int t = idx & (cL - 1);
  int m2 = idx >> 10;
  int m = m2 >> 1;
  float ang = 6.2831853071795864f * (float)((m * t) & (cL - 1)) / (float)cL;
  float cv = cosf(ang), sv = sinf(ang);
  float vd = (m2 & 1) ? -sv : cv;
  basisdb[idx] = (short)f2bf(vd);
  float s = (m == 0) ? ((m2 & 1) ? 0.f : (1.f / (float)cL)) : (2.f / (float)cL);
  basisib[t * M2 + m2] = (short)f2bf(vd * s);
}

__global__ void pe_kernel(float* __restrict__ pe) {
  int idx = blockIdx.x * 256 + threadIdx.x;
  int o = idx & (cDM - 1), t = idx >> 9;
  int i = o >> 1;
  float freq = __expf((float)(2 * i) * (-9.210340371976184f / (float)cDM));
  float ang = freq * (float)t;
  pe[idx] = (o & 1) ? cosf(ang) : sinf(ang);
}

__global__ void cvt_kernel(const float* __restrict__ in, short* __restrict__ out, int n) {
  for (int i = blockIdx.x * 256 + threadIdx.x; i < n; i += gridDim.x * 256)
    out[i] = (short)f2bf(in[i]);
}

// Bpadb[o][j*32+c]=tok_W[o][c][j]; Wtr3b[o][j*512+c]=trW[o][c][j] (o<32); p3padb; p3bpadf
__global__ void prep_kernel(const float* __restrict__ tok_W, const float* __restrict__ trW,
                            const float* __restrict__ p3W, const float* __restrict__ p3b,
                            short* __restrict__ Bpadb, short* __restrict__ Wtr3b,
                            short* __restrict__ p3padb, float* __restrict__ p3bpadf) {
  int idx = blockIdx.x * 256 + threadIdx.x;
  if (idx < 512 * 128) {
    int o = idx >> 7, s = idx & 127, j = s >> 5, c = s & 31;
    Bpadb[idx] = (j < 3) ? (short)f2bf(tok_W[o * 96 + c * 3 + j]) : (short)0;
  }
  if (idx < 128 * 1536) {
    int o = idx / 1536, r = idx % 1536, j = r >> 9, c = r & 511;
    Wtr3b[idx] = (o < 32) ? (short)f2bf(trW[(long)o * 1536 + c * 3 + j]) : (short)0;
  }
  if (idx < 128 * 512) {
    int o = idx >> 9, k = idx & 511;
    p3padb[idx] = (o < 32) ? (short)f2bf(p3W[o * 512 + k]) : (short)0;
  }
  if (idx < 128) p3bpadf[idx] = (idx < 32) ? p3b[idx] : 0.f;
}

// win[row][128] bf16 = [x[t-1,:], x[t,:], x[t+1,:], 0] circular
__global__ void winbuild_kernel(const float* __restrict__ x, short* __restrict__ win) {
  int idx = blockIdx.x * 256 + threadIdx.x;
  int s4 = idx & 31;
  int row = idx >> 5;
  int t = row & (cL - 1), b = row >> 10;
  int j = s4 >> 3, c4 = s4 & 7;
  unsigned int lo = 0, hi = 0;
  if (j < 3) {
    int ts = (t + j + cL - 1) & (cL - 1);
    float4 v = *(const float4*)&x[((long)b * cL + ts) * cCIN + c4 * 4];
    lo = (unsigned int)f2bf(v.x) | ((unsigned int)f2bf(v.y) << 16);
    hi = (unsigned int)f2bf(v.z) | ((unsigned int)f2bf(v.w) << 16);
  }
  *(uint2*)&win[row * 128 + s4 * 4] = make_uint2(lo, hi);
}

// batched bf16 transpose: in [B][1024][512] -> out [B][512][1024] (emb stream only)
__global__ __launch_bounds__(256) void transpose_bf(const short* __restrict__ in,
                                                    short* __restrict__ out) {
  __shared__ short tile[32][33];
  int b = blockIdx.z;
  in += (long)b * cL * cDM;
  out += (long)b * cL * cDM;
  int c0 = blockIdx.x * 32, t0 = blockIdx.y * 32;
  int tx = threadIdx.x & 31, ty = threadIdx.x >> 5;
#pragma unroll
  for (int r = 0; r < 32; r += 8) tile[ty + r][tx] = in[(long)(t0 + ty + r) * cDM + c0 + tx];
  __syncthreads();
#pragma unroll
  for (int r = 0; r < 32; r += 8)
    out[(long)(c0 + ty + r) * cL + t0 + tx] = tile[tx][ty + r];
}

// ==== moving-average decomposition, sliding-window; optional transposed bf16 seasonal
//      shadow (sbt, C=512 only) and bf16 ma accumulate (maacc) ====
__global__ void decomp_kernel(const float* __restrict__ x, float* __restrict__ sf,
                              short* __restrict__ sb, short* __restrict__ sbt,
                              float* __restrict__ maf, short* __restrict__ mab, int maacc,
                              int n8, int C) {
  int idx = blockIdx.x * 256 + threadIdx.x;
  if (idx >= n8) return;
  int c = idx % C;
  int u = idx / C;
  int t0 = (u & 127) * 8;
  int b = u >> 7;
  long base = (long)b * cL * C + c;
  float s = 0.f;
#pragma unroll
  for (int j = -12; j <= 12; j++) {
    int tt = t0 + j;
    tt = tt < 0 ? 0 : (tt >= cL ? cL - 1 : tt);
    s += x[base + (long)tt * C];
  }
  short tloc[8];
#pragma unroll
  for (int k = 0; k < 8; k++) {
    int t = t0 + k;
    long e = base + (long)t * C;
    float ma = s * (1.0f / 25.0f);
    float se = x[e] - ma;
    if (sf) sf[e] = se;
    if (sb) sb[e] = (short)f2bf(se);
    tloc[k] = (short)f2bf(se);
    if (maf) maf[e] = ma;
    if (mab) {
      float v = maacc ? bf2f((unsigned short)mab[e]) + ma : ma;
      mab[e] = (short)f2bf(v);
    }
    int ta = t + 13;
    ta = ta >= cL ? cL - 1 : ta;
    int td = t - 12;
    td = td < 0 ? 0 : td;
    s += x[base + (long)ta * C] - x[base + (long)td * C];
  }
  if (sbt) { // transposed [b][c][t] bf16 store, 16B aligned
    *(uint4*)&sbt[((long)b * cDM + c) * cL + t0] = *(const uint4*)&tloc[0];
  }
}

// ================= final time projection =================
__global__ __launch_bounds__(256) void p2_kernel(const float* __restrict__ x,
                                                 const float* __restrict__ W,
                                                 const float* __restrict__ bias,
                                                 float* __restrict__ out) {
  __shared__ float tile[256 * 32];
  int b = blockIdx.x;
  int p0 = blockIdx.y * 8;
  int c = threadIdx.x & 31, pl = threadIdx.x >> 5;
  const float* xb = x + (long)b * cL * cCIN;
  const float* w = W + (long)(p0 + pl) * cL;
  float s = 0.f;
  for (int l0 = 0; l0 < cL; l0 += 256) {
    __syncthreads();
    for (int i = threadIdx.x; i < 256 * 32; i += 256) tile[i] = xb[(long)l0 * 32 + i];
    __syncthreads();
#pragma unroll 8
    for (int l = 0; l < 256; l++) s += tile[l * 32 + c] * w[l0 + l];
  }
  out[((long)b * cPRED + p0 + pl) * cCIN + c] = s + bias[p0 + pl];
}

// ====== per-(h,mode) complex mode mix; W bf16; h-major 1D grid (same-h -> same XCD) ======
__global__ __launch_bounds__(256) void modemix_t_kernel(const float* __restrict__ F,
                                                        const unsigned short* __restrict__ W,
                                                        short* __restrict__ Gt, float scale) {
  int b = blockIdx.x >> 3, h = blockIdx.x & 7;
  __shared__ float2 Fs[cE][cM];
  __shared__ short ot[128][72];
  const float* Fb = F + ((long)b * cDM + h * cE) * M2;
  for (int i = threadIdx.x; i < cE * cM; i += 256) {
    int e = i >> 6, x = i & 63;
    Fs[e][x] = ((const float2*)(Fb + (long)e * M2))[x];
  }
  __syncthreads();
  int x = threadIdx.x & 63, og = threadIdx.x >> 6;
  float2 acc[16];
#pragma unroll
  for (int i = 0; i < 16; i++) acc[i] = make_float2(0.f, 0.f);
  for (int e = 0; e < cE; e++) {
    float2 f = Fs[e][x];
#pragma unroll
    for (int i = 0; i < 16; i++) {
      int o = og * 16 + i;
      unsigned int wu = *(const unsigned int*)&W[((((long)h * cE + e) * cE + o) * cM + x) * 2];
      float wx = bf2f((unsigned short)wu), wy = bf2f((unsigned short)(wu >> 16));
      acc[i].x += f.x * wx - f.y * wy;
      acc[i].y += f.x * wy + f.y * wx;
    }
  }
#pragma unroll
  for (int i = 0; i < 16; i++) {
    int o = og * 16 + i;
    ot[2 * x][o] = (short)f2bf(acc[i].x * scale);
    ot[2 * x + 1][o] = (short)f2bf(acc[i].y * scale);
  }
  __syncthreads();
  short* gb = Gt + (long)b * (M2 * cDM) + h * cE;
  for (int u = threadIdx.x; u < 1024; u += 256) {
    int row = u >> 3, seg = u & 7;
    *(uint4*)&gb[(long)row * cDM + seg * 8] = *(const uint4*)&ot[row][seg * 8];
  }
}

// ====== fused cross attention (W bf16, h-major 1D grid) ======
__global__ __launch_bounds__(256) void fused_cross_kernel(const float* __restrict__ Fq,
                                                          const float* __restrict__ Fk,
                                                          const unsigned short* __restrict__ W,
                                                          short* __restrict__ Gt, float scale) {
  __shared__ __align__(16) char smem[65536];
  float2(*Ks)[cM] = (float2(*)[cM])smem;
  float2(*qks)[cM] = (float2(*)[cM])(smem + 32768);
  int b = blockIdx.x >> 3, h = blockIdx.x & 7;
  const float* kb = Fk + ((long)b * cDM + h * cE) * M2;
  for (int i = threadIdx.x; i < cE * cM; i += 256) {
    int e = i >> 6, y = i & 63;
    Ks[e][y] = ((const float2*)(kb + (long)e * M2))[y];
  }
  __syncthreads();
  { // phase 1: qk[x][y] = tanh(sum_e q[e][x] * k[e][y])
    int x = threadIdx.x & 63, yg = threadIdx.x >> 6;
    const float* qb = Fq + ((long)b * cDM + h * cE) * M2;
    float2 acc[16];
#pragma unroll
    for (int i = 0; i < 16; i++) acc[i] = make_float2(0.f, 0.f);
    for (int e = 0; e < cE; e++) {
      float2 q = ((const float2*)(qb + (long)e * M2))[x];
#pragma unroll
      for (int i = 0; i < 16; i++) {
        float2 k = Ks[e][yg * 16 + i];
        acc[i].x += q.x * k.x - q.y * k.y;
        acc[i].y += q.x * k.y + q.y * k.x;
      }
    }
#pragma unroll
    for (int i = 0; i < 16; i++) {
      int y = yg * 16 + i;
      float a = acc[i].x, bi = acc[i].y;
      float re, im;
      float t2a = 2.f * a;
      if (fabsf(t2a) > 60.f) {
        re = t2a > 0.f ? 1.f : -1.f;
        im = 0.f;
      } else {
        float denom = coshf(t2a) + cosf(2.f * bi);
        re = sinhf(t2a) / denom;
        im = sinf(2.f * bi) / denom;
      }
      qks[x][y] = make_float2(re, im);
    }
  }
  __syncthreads();
  // phase 2: qkv[e][x] = sum_y qk[x][y] * k[e][y]
  int e = threadIdx.x & 63, xg = threadIdx.x >> 6;
  float2 a2[16];
#pragma unroll
  for (int i = 0; i < 16; i++) a2[i] = make_float2(0.f, 0.f);
  for (int y = 0; y < cM; y++) {
    float2 k = Ks[e][y];
#pragma unroll
    for (int i = 0; i < 16; i++) {
      float2 qk = qks[xg * 16 + i][y];
      a2[i].x += qk.x * k.x - qk.y * k.y;
      a2[i].y += qk.x * k.y + qk.y * k.x;
    }
  }
  __syncthreads();
#pragma unroll
  for (int i = 0; i < 16; i++) Ks[e][xg * 16 + i] = a2[i];
  __syncthreads();
  { // phase 3: mix + transposed bf16 store
    int x = threadIdx.x & 63, og = threadIdx.x >> 6;
    float2 m[16];
#pragma unroll
    for (int i = 0; i < 16; i++) m[i] = make_float2(0.f, 0.f);
    for (int ee = 0; ee < cE; ee++) {
      float2 f = Ks[ee][x];
#pragma unroll
      for (int i = 0; i < 16; i++) {
        int o = og * 16 + i;
        unsigned int wu = *(const unsigned int*)&W[((((long)h * cE + ee) * cE + o) * cM + x) * 2];
        float wx = bf2f((unsigned short)wu), wy = bf2f((unsigned short)(wu >> 16));
        m[i].x += f.x * wx - f.y * wy;
        m[i].y += f.x * wy + f.y * wx;
      }
    }
    short(*ot)[72] = (short(*)[72])(smem + 32768);
#pragma unroll
    for (int i = 0; i < 16; i++) {
      int o = og * 16 + i;
      ot[2 * x][o] = (short)f2bf(m[i].x * scale);
      ot[2 * x + 1][o] = (short)f2bf(m[i].y * scale);
    }
    __syncthreads();
    short* gb = Gt + (long)b * (M2 * cDM) + h * cE;
    for (int u = threadIdx.x; u < 1024; u += 256) {
      int row = u >> 3, seg = u & 7;
      *(uint4*)&gb[(long)row * cDM + seg * 8] =
          *(const uint4*)&((short(*)[72])(smem + 32768))[row][seg * 8];
    }
  }
}

// ================= f32 shader GEMM (tiny p1 only) =================
constexpr int GBM = 128, GBN = 128, GBK = 16, LPAD = 132;

__global__ __launch_bounds__(256) void gemm_kernel(const float* __restrict__ A,
                                                   const float* __restrict__ B,
                                                   const float* __restrict__ bias,
                                                   float* __restrict__ C, int M, int N, int K) {
  __shared__ float As[GBK][LPAD];
  __shared__ float Bs[GBK][LPAD];
  int n0 = blockIdx.x * GBN, m0 = blockIdx.y * GBM;
  int tid = threadIdx.x;
  int tx = tid & 15, ty = tid >> 4;
  float acc[8][8];
#pragma unroll
  for (int i = 0; i < 8; i++)
#pragma unroll
    for (int j = 0; j < 8; j++) acc[i][j] = 0.f;

  for (int k0 = 0; k0 < K; k0 += GBK) {
#pragma unroll
    for (int p = 0; p < 8; p++) {
      int i = p * 256 + tid;
      int mm = i >> 4, kk = i & 15;
      int gm = m0 + mm;
      As[kk][mm] = (gm < M && k0 + kk < K) ? A[(long)gm * K + k0 + kk] : 0.f;
    }
#pragma unroll
    for (int p = 0; p < 8; p++) {
      int i = p * 256 + tid;
      int nn = i >> 4, kk = i & 15;
      int gn = n0 + nn;
      Bs[kk][nn] = (gn < N && k0 + kk < K) ? B[(long)gn * K + k0 + kk] : 0.f;
    }
    __syncthreads();
#pragma unroll
    for (int kk = 0; kk < GBK; kk++) {
      float a[8], bb[8];
      *(float4*)&a[0] = *(const float4*)&As[kk][ty * 8];
      *(float4*)&a[4] = *(const float4*)&As[kk][ty * 8 + 4];
      *(float4*)&bb[0] = *(const float4*)&Bs[kk][tx * 8];
      *(float4*)&bb[4] = *(const float4*)&Bs[kk][tx * 8 + 4];
#pragma unroll
      for (int i = 0; i < 8; i++)
#pragma unroll
        for (int j = 0; j < 8; j++) acc[i][j] += a[i] * bb[j];
    }
    __syncthreads();
  }

  for (int i = 0; i < 8; i++) {
    int gm = m0 + ty * 8 + i;
    if (gm >= M) break;
    long rowoff = (long)gm * N;
    for (int j = 0; j < 8; j++) {
      int gn = n0 + tx * 8 + j;
      if (gn < N) C[rowoff + gn] = acc[i][j] + (bias ? bias[gn] : 0.f);
    }
  }
}

// ===== bf16 MFMA GEMM (m97 single-buffer, swizzled, XCD-chunked; zsplit dual mode) =====
__global__ __launch_bounds__(256) void mfma_gemm_bf(
    const short* __restrict__ A, const short* __restrict__ B, const float* __restrict__ bias,
    const float* __restrict__ addend, const float* __restrict__ pe, const float* __restrict__ m0b,
    float* __restrict__ Cf, short* __restrict__ Cb, int M, int N, int K, int lda, long sA, long sB,
    long sC, int relu, int Nreal, int ldc, int amode, const short* __restrict__ A2,
    const short* __restrict__ B2, const float* __restrict__ m0b2, float* __restrict__ Cf2,
    int zsplit) {
  __shared__ __align__(16) short As[8192];
  __shared__ __align__(16) short Bs[8192];
  int nwg = gridDim.x * gridDim.y * gridDim.z;
  int orig = blockIdx.x + gridDim.x * (blockIdx.y + gridDim.y * blockIdx.z);
  int q = nwg >> 3, r = nwg & 7;
  int xcd = orig & 7, ii = orig >> 3;
  int flat = (xcd < r ? xcd * (q + 1) : r * (q + 1) + (xcd - r) * q) + ii;
  int bx = flat % (int)gridDim.x;
  int tmp = flat / (int)gridDim.x;
  int by = tmp % (int)gridDim.y;
  int bz = tmp / (int)gridDim.y;

  int z = bz;
  if (zsplit > 0 && bz >= zsplit) {
    A = A2;
    B = B2;
    m0b = m0b2;
    Cf = Cf2;
    z = bz - zsplit;
  }
  A += (long)z * sA;
  B += (long)z * sB;
  if (Cf) Cf += (long)z * sC;
  if (Cb) Cb += (long)z * sC;
  const float* Ad = addend ? addend + (long)z * sC : nullptr;
  int n0 = bx * 128, m0 = by * 128;
  int tid = threadIdx.x;
  int lane = tid & 63;
  int w = tid >> 6;
  int wm = w & 1, wn = w >> 1;
  int lr = lane & 15, lg = lane >> 4;
  int lrow = lane >> 3;
  int scol = ((lane & 7) * 8) ^ (lrow << 3);

  float4v acc[4][4];
#pragma unroll
  for (int i = 0; i < 4; i++)
#pragma unroll
    for (int j = 0; j < 4; j++) acc[i][j] = (float4v){0.f, 0.f, 0.f, 0.f};

  auto stage = [&](int k0) {
#pragma unroll
    for (int j = 0; j < 4; j++) {
      int seg = w * 4 + j;
      int row = seg * 8 + lrow;
      const short* ga;
      if (amode == 0) {
        ga = A + (long)(m0 + row) * lda + k0 + scol;
      } else {
        int r2 = m0 + row;
        int bb = r2 >> 10, t = r2 & 1023;
        int jj = k0 >> 9, c0 = k0 & 511;
        ga = A + ((((long)(bb << 10)) | ((t + jj + 1023) & 1023)) << 9) + c0 + scol;
      }
      gld16(ga, &As[seg * 512]);
      const short* gb = B + (long)(n0 + row) * K + k0 + scol;
      gld16(gb, &Bs[seg * 512]);
    }
  };

  int nk = K >> 6;
  int swr = (lr & 7) << 3;
  for (int t = 0; t < nk; ++t) {
    stage(t << 6);
    asm volatile("s_waitcnt vmcnt(0)" ::: "memory");
    __syncthreads();
#pragma unroll
    for (int ks = 0; ks < 2; ks++) {
      short8v af[4], bfr[4];
#pragma unroll
      for (int mi = 0; mi < 4; mi++)
        af[mi] = *(const short8v*)&As[(wm * 64 + mi * 16 + lr) * 64 + ((ks * 32 + lg * 8) ^ swr)];
#pragma unroll
      for (int ni = 0; ni < 4; ni++)
        bfr[ni] = *(const short8v*)&Bs[(wn * 64 + ni * 16 + lr) * 64 + ((ks * 32 + lg * 8) ^ swr)];
#pragma unroll
      for (int mi = 0; mi < 4; mi++)
#pragma unroll
        for (int ni = 0; ni < 4; ni++)
          acc[mi][ni] =
              __builtin_amdgcn_mfma_f32_16x16x32_bf16(af[mi], bfr[ni], acc[mi][ni], 0, 0, 0);
    }
    __syncthreads();
  }

#pragma unroll
  for (int mi = 0; mi < 4; mi++) {
#pragma unroll
    for (int i = 0; i < 4; i++) {
      int gr = m0 + wm * 64 + mi * 16 + lg * 4 + i;
      long rowoff = (long)gr * ldc;
#pragma unroll
      for (int ni = 0; ni < 4; ni++) {
        int gc = n0 + wn * 64 + ni * 16 + lr;
        if (gc < Nreal) {
          float v = acc[mi][ni][i];
          if (bias) v += bias[gc];
          if (pe) v += pe[((gr & (cL - 1)) << 9) + gc];
          if (m0b && gc == 0) v += 1024.f * m0b[gr];
          if (Ad) v += Ad[rowoff + gc];
          if (relu) v = fmaxf(v, 0.f);
          if (Cf) Cf[rowoff + gc] = v;
          if (Cb) Cb[rowoff + gc] = (short)f2bf(v);
        }
      }
    }
  }
}

} // namespace

extern "C" void kernel_launch(void* const* d_in, const int* in_sizes, int n_in, void* d_out,
                              int out_size, void* d_ws, size_t ws_size, hipStream_t stream) {
  const float* x_enc = (const float*)d_in[0];
  const float* tok_W = (const float*)d_in[1];
  const float* enc_Wq = (const float*)d_in[2];
  const float* enc_Wo = (const float*)d_in[5];
  const float* enc_bq = (const float*)d_in[6];
  const float* enc_bo = (const float*)d_in[9];
  const float* dsWq = (const float*)d_in[10];
  const float* dsWo = (const float*)d_in[13];
  const float* dsbq = (const float*)d_in[14];
  const float* dsbo = (const float*)d_in[17];
  const float* dcWq = (const float*)d_in[18];
  const float* dcWk = (const float*)d_in[19];
  const float* dcWo = (const float*)d_in[21];
  const float* dcbq = (const float*)d_in[22];
  const float* dcbk = (const float*)d_in[23];
  const float* dcbo = (const float*)d_in[25];
  const float* enc_c1W = (const float*)d_in[26];
  const float* enc_c1b = (const float*)d_in[27];
  const float* enc_c2W = (const float*)d_in[28];
  const float* enc_c2b = (const float*)d_in[29];
  const float* dec_c1W = (const float*)d_in[30];
  const float* dec_c1b = (const float*)d_in[31];
  const float* dec_c2W = (const float*)d_in[32];
  const float* dec_c2b = (const float*)d_in[33];
  const float* dec_trW = (const float*)d_in[34];
  const float* fb_enc = (const float*)d_in[35];
  const float* fb_dec = (const float*)d_in[36];
  const float* fc_w = (const float*)d_in[37];
  const float* p1W = (const float*)d_in[38];
  const float* p1b = (const float*)d_in[39];
  const float* p2W = (const float*)d_in[40];
  const float* p2b = (const float*)d_in[41];
  const float* p3W = (const float*)d_in[42];
  const float* p3b = (const float*)d_in[43];

  constexpr long MIXW = 8L * 64 * 64 * 64 * 2; // 4.19M elems per mix-weight tensor

  // ---- layout sizing (dry-run) ----
  auto layout_bytes = [&](long BG, long RH) -> size_t {
    size_t t = 0;
    auto add = [&](size_t b) { t = (t + b + 255) & ~(size_t)255; };
    add(2 * 262144 * 2); add(2 * 262144 * 2);
    add(262144 * 2); add(262144 * 2); add(262144 * 2); add(262144 * 2); add(262144 * 2);
    add(2 * 1048576 * 2); add(2 * 1048576 * 2); add(1048576 * 2); add(1048576 * 2);
    add(131072 * 2); add(131072 * 2); add(65536 * 2); add(196608 * 2); add(65536 * 2);
    add(128 * 4); add(524288 * 4);
    add(MIXW * 2); add(MIXW * 2); add(MIXW * 2);             // fbEb fbDb fcwb
    long GA = BG * cL * cDM;
    add(GA * 4); add(GA * 4); add(GA * 4);
    add(GA * 2); add(GA * 2); add(GA * 2); add(GA * 2);
    add(BG * cL * 128 * 2);
    size_t ub = (size_t)GA * 2;
    size_t hd = (size_t)RH * cDFF * 2;
    add(ub > hd ? ub : hd);
    add(BG * 65536 * 4); add(BG * 65536 * 4);
    add(BG * 65536 * 2); add(BG * 65536 * 2); add(BG * 65536 * 2); add(BG * 65536 * 2);
    add(BG * cL * cCIN * 4); add(BG * cL * cCIN * 4); add(BG * cL * cCIN * 4);
    return t;
  };
  int BG = cB;
  while (BG > 1 && layout_bytes(BG, 512) > ws_size) BG >>= 1;
  long RH = (long)BG * cL;
  while (RH > 512 && layout_bytes(BG, RH) > ws_size) RH >>= 1;

  long GBL = (long)BG * cL;
  char* base = (char*)d_ws;
  size_t off = 0;
  auto alloc = [&](size_t bytes) -> void* {
    void* p = base + off;
    off = (off + bytes + 255) & ~(size_t)255;
    return p;
  };
  short* WqbE = (short*)alloc(2 * 262144 * 2);
  short* WobE = (short*)alloc(2 * 262144 * 2);
  short* dsWqb = (short*)alloc(262144 * 2);
  short* dsWob = (short*)alloc(262144 * 2);
  short* dcWqb = (short*)alloc(262144 * 2);
  short* dcWkb = (short*)alloc(262144 * 2);
  short* dcWob = (short*)alloc(262144 * 2);
  short* c1bE = (short*)alloc(2 * 1048576 * 2);
  short* c2bE = (short*)alloc(2 * 1048576 * 2);
  short* c1bD = (short*)alloc(1048576 * 2);
  short* c2bD = (short*)alloc(1048576 * 2);
  short* basisdb = (short*)alloc(131072 * 2);
  short* basisib = (short*)alloc(131072 * 2);
  short* Bpadb = (short*)alloc(65536 * 2);
  short* Wtr3b = (short*)alloc(196608 * 2);
  short* p3padb = (short*)alloc(65536 * 2);
  float* p3bpadf = (float*)alloc(128 * 4);
  float* pe = (float*)alloc(524288 * 4);
  short* fbEb = (short*)alloc(MIXW * 2);
  short* fbDb = (short*)alloc(MIXW * 2);
  short* fcwb = (short*)alloc(MIXW * 2);
  long GA = GBL * cDM;
  float* E = (float*)alloc(GA * 4);
  float* X = (float*)alloc(GA * 4);
  float* A = (float*)alloc(GA * 4);
  short* Eb = (short*)alloc(GA * 2);
  short* Xb = (short*)alloc(GA * 2);
  short* Ab = (short*)alloc(GA * 2);
  short* Sb = (short*)alloc(GA * 2);
  short* winb = (short*)alloc(GBL * 128 * 2);
  size_t ubsz = (size_t)GA * 2;
  size_t hdsz = (size_t)RH * cDFF * 2;
  short* UB = (short*)alloc(ubsz > hdsz ? ubsz : hdsz); // Tb / HDb / transposed-shadow (disjoint)
  short* Tb = UB;
  short* HDb = UB;
  float* Fq = (float*)alloc((size_t)BG * 65536 * 4);
  float* Fk = (float*)alloc((size_t)BG * 65536 * 4);
  short* FEb = (short*)alloc((size_t)BG * 65536 * 2);
  short* FXb = (short*)alloc((size_t)BG * 65536 * 2);
  short* Gtb = (short*)alloc((size_t)BG * 65536 * 2);
  short* Hb = (short*)alloc((size_t)BG * 65536 * 2);
  float* TRD = (float*)alloc(GBL * cCIN * 4);
  float* O1 = (float*)alloc(GBL * cCIN * 4);
  float* O2 = (float*)alloc(GBL * cCIN * 4);

  auto mg = [&](const short* Am, const short* Bm, const float* bias, const float* add,
                const float* peA, const float* m0b, float* Cf, short* Cb, int Mm, int Nn, int Kk,
                int lda, long sA, long sB, long sC, int batch, int relu, int Nreal, int ldc,
                int amode) {
    dim3 g(Nn / 128, Mm / 128, batch);
    mfma_gemm_bf<<<g, 256, 0, stream>>>(Am, Bm, bias, add, peA, m0b, Cf, Cb, Mm, Nn, Kk, lda, sA,
                                        sB, sC, relu, Nreal, ldc, amode, nullptr, nullptr,
                                        nullptr, nullptr, 0);
  };
  auto cvt = [&](const float* in, short* out, long n) {
    int g = (int)((n + 255) / 256);
    if (g > 4096) g = 4096;
    cvt_kernel<<<g, 256, 0, stream>>>(in, out, (int)n);
  };
  auto decomp = [&](const float* x, float* sf, short* sb, short* sbt, float* maf, short* mab,
                    int maacc, long total, int C_) {
    int n8 = (int)(total / 8);
    decomp_kernel<<<(n8 + 255) / 256, 256, 0, stream>>>(x, sf, sb, sbt, maf, mab, maacc, n8, C_);
  };
  // dft gemm: F[b][m2][dm] bf16 = basisd @ T_b^T where T (=UB) holds [b][dm][t]
  auto dftg = [&](short* Fout) {
    mg(basisdb, Tb, nullptr, nullptr, nullptr, nullptr, nullptr, Fout, M2, cDM, cL, cL, 0,
       (long)cDM * cL, 65536, BG, 0, cDM, cDM, 0);
  };
  auto modeproj = [&](const short* Wb, const short* Fin, const float* m0b, float* Cf, short* Cb) {
    mg(Wb, Fin, nullptr, nullptr, nullptr, m0b, Cf, Cb, cDM, M2, cDM, cDM, 0, 65536, 65536, BG, 0,
       M2, M2, 0);
  };
  auto modeproj2 = [&](const short* Wa, const short* Fa, const float* ba, float* Ca,
                       const short* Wb2, const short* Fb2, const float* bb2, float* Cb2) {
    dim3 g(1, cDM / 128, 2 * BG);
    mfma_gemm_bf<<<g, 256, 0, stream>>>(Wa, Fa, nullptr, nullptr, nullptr, ba, Ca, nullptr, cDM,
                                        M2, cDM, cDM, 0, 65536, 65536, 0, M2, M2, 0, Wb2, Fb2,
                                        bb2, Cb2, BG);
  };
  auto idft = [&](const short* Hin, const float* bias, const float* add, float* Cf) {
    mg(basisib, Hin, bias, add, nullptr, nullptr, Cf, nullptr, cL, cDM, M2, M2, 0, 65536,
       (long)cL * cDM, BG, 0, cDM, cDM, 0);
  };
  auto ffn = [&](const short* inb, const float* addf, float* outf, const short* c1w,
                 const float* c1bias, const short* c2w, const float* c2bias) {
    for (long r = 0; r < GBL; r += RH) {
      mg(inb + r * cDM, c1w, c1bias, nullptr, nullptr, nullptr, nullptr, HDb, (int)RH, cDFF, cDM,
         cDM, 0, 0, 0, 1, 1, cDFF, cDFF, 0);
      mg(HDb, c2w, c2bias, addf + r * cDM, nullptr, nullptr, outf + r * cDM, nullptr, (int)RH,
         cDM, cDFF, cDFF, 0, 0, 0, 1, 0, cDM, cDM, 0);
    }
  };
  auto trendg = [&](const short* mab) {
    mg(mab, Wtr3b, nullptr, TRD, nullptr, nullptr, TRD, nullptr, (int)GBL, 128, 1536, 512, 0, 0,
       0, 1, 0, cCIN, cCIN, 1);
  };
  auto mixt = [&](const float* F, const short* W, float scale) {
    modemix_t_kernel<<<BG * cH, 256, 0, stream>>>(F, (const unsigned short*)W, Gtb, scale);
  };

  // ---- one-time setup ----
  basis_kernel<<<(M2 * cL) / 256, 256, 0, stream>>>(basisdb, basisib);
  pe_kernel<<<(cL * cDM) / 256, 256, 0, stream>>>(pe);
  prep_kernel<<<768, 256, 0, stream>>>(tok_W, dec_trW, p3W, p3b, Bpadb, Wtr3b, p3padb, p3bpadf);
  cvt(enc_Wq, WqbE, 524288);
  cvt(enc_Wo, WobE, 524288);
  cvt(dsWq, dsWqb, 262144);
  cvt(dsWo, dsWob, 262144);
  cvt(dcWq, dcWqb, 262144);
  cvt(dcWk, dcWkb, 262144);
  cvt(dcWo, dcWob, 262144);
  cvt(enc_c1W, c1bE, 2097152);
  cvt(enc_c2W, c2bE, 2097152);
  cvt(dec_c1W, c1bD, 1048576);
  cvt(dec_c2W, c2bD, 1048576);
  cvt(fb_enc, fbEb, MIXW);
  cvt(fb_dec, fbDb, MIXW);
  cvt(fc_w, fcwb, MIXW);

  for (int b0 = 0; b0 < cB; b0 += BG) {
    const float* xg = x_enc + (long)b0 * cL * cCIN;

    decomp(xg, nullptr, nullptr, nullptr, TRD, nullptr, 0, GBL * cCIN, cCIN); // trend_init
    winbuild_kernel<<<(int)(GBL * 32 / 256), 256, 0, stream>>>(xg, winb);
    mg(winb, Bpadb, nullptr, nullptr, pe, nullptr, E, Eb, (int)GBL, cDM, 128, 128, 0, 0, 0, 1, 0,
       cDM, cDM, 0); // embedding

    // ---- encoder ----
    for (int l = 0; l < 2; l++) {
      if (l == 0) transpose_bf<<<dim3(16, 32, BG), 256, 0, stream>>>(Eb, Tb); // emb stream only
      dftg(FEb);
      modeproj(WqbE + (long)l * 262144, FEb, enc_bq + l * cDM, Fq, nullptr);
      mixt(Fq, fbEb, 1.0f);
      modeproj(WobE + (long)l * 262144, Gtb, nullptr, nullptr, Hb);
      idft(Hb, enc_bo + l * cDM, E, A);
      decomp(A, X, Xb, nullptr, nullptr, nullptr, 0, GA, cDM);               // h -> X,Xb
      ffn(Xb, X, A, c1bE + (long)l * 1048576, enc_c1b + l * cDFF, c2bE + (long)l * 1048576,
          enc_c2b + l * cDM);
      decomp(A, E, Eb, Tb, nullptr, nullptr, 0, GA, cDM);                    // stream + EbT
    }

    // ---- decoder ----
    dftg(FEb); // uses EbT written by enc l=1 decomp
    modeproj(dsWqb, FEb, dsbq, Fq, nullptr);
    mixt(Fq, fbDb, 1.0f);
    modeproj(dsWob, Gtb, nullptr, nullptr, Hb);
    idft(Hb, dsbo, E, A);                                                    // x1 -> A
    decomp(A, X, Xb, Tb, nullptr, Sb, 0, GA, cDM);                           // x2 + XbT; ma->Sb
    dftg(FXb);                                                               // modes of x2
    modeproj2(dcWqb, FXb, dcbq, Fq, dcWkb, FEb, dcbk, Fk);
    fused_cross_kernel<<<BG * cH, 256, 0, stream>>>(Fq, Fk, (const unsigned short*)fcwb, Gtb,
                                                    1.0f / (float)(cDM * cDM));
    modeproj(dcWob, Gtb, nullptr, nullptr, Hb);
    idft(Hb, dcbo, X, E);                                                    // x3 -> E
    decomp(E, A, Ab, nullptr, nullptr, Sb, 1, GA, cDM);                      // x4; ma += Sb
    ffn(Ab, A, E, c1bD, dec_c1b, c2bD, dec_c2b);                             // x4+y -> E
    decomp(E, nullptr, Xb, nullptr, nullptr, Sb, 1, GA, cDM);                // x5; ma += Sb
    trendg(Sb);                                                              // conv(t1+t2+t3)

    // ---- final projections ----
    mg(Xb, p3padb, p3bpadf, TRD, nullptr, nullptr, O1, nullptr, (int)GBL, 128, cDM, cDM, 0, 0, 0,
       1, 0, cCIN, cCIN, 0);
    gemm_kernel<<<dim3(1, (int)(GBL / 128)), 256, 0, stream>>>(O1, p1W, p1b, O2, (int)GBL, cCIN,
                                                               cCIN);
    p2_kernel<<<dim3(BG, 32), 256, 0, stream>>>(O2, p2W, p2b,
                                                (float*)d_out + (long)b0 * cPRED * cCIN);
  }
}

// Round 12
// 4225.576 us; speedup vs baseline: 1.0185x; 1.0185x over previous
//
#include <hip/hip_runtime.h>
#include <math.h>

namespace {

constexpr int cB = 32, cL = 1024, cCIN = 32, cDM = 512, cDFF = 2048;
constexpr int cH = 8, cE = 64, cM = 64, cPRED = 256;
constexpr int M2 = 2 * cM; // 128

typedef __attribute__((ext_vector_type(8))) short short8v;
typedef __attribute__((ext_vector_type(4))) float float4v;

__device__ inline unsigned short f2bf(float f) {
  unsigned int u = __builtin_bit_cast(unsigned int, f);
  u += 0x7FFFu + ((u >> 16) & 1u); // RNE
  return (unsigned short)(u >> 16);
}
__device__ inline float bf2f(unsigned short s) {
  return __builtin_bit_cast(float, (unsigned int)s << 16);
}

typedef const __attribute__((address_space(1))) unsigned int gu32_t;
typedef __attribute__((address_space(3))) unsigned int lu32_t;
__device__ inline void gld16(const void* g, void* l) {
  __builtin_amdgcn_global_load_lds((gu32_t*)g, (lu32_t*)l, 16, 0, 0);
}

// ================= one-time tables =================
__global__ void basis_kernel(short* __restrict__ basisdb, short* __restrict__ basisib) {
  int idx = blockIdx.x * 256 + threadIdx.x;
  if (idx >= M2 * cL) return;
  int t = idx & (cL - 1);
  int m2 = idx >> 10;
  int m = m2 >> 1;
  float ang = 6.2831853071795864f * (float)((m * t) & (cL - 1)) / (float)cL;
  float cv = cosf(ang), sv = sinf(ang);
  float vd = (m2 & 1) ? -sv : cv;
  basisdb[idx] = (short)f2bf(vd);
  float s = (m == 0) ? ((m2 & 1) ? 0.f : (1.f / (float)cL)) : (2.f / (float)cL);
  basisib[t * M2 + m2] = (short)f2bf(vd * s);
}

__global__ void pe_kernel(float* __restrict__ pe) {
  int idx = blockIdx.x * 256 + threadIdx.x;
  int o = idx & (cDM - 1), t = idx >> 9;
  int i = o >> 1;
  float freq = __expf((float)(2 * i) * (-9.210340371976184f / (float)cDM));
  float ang = freq * (float)t;
  pe[idx] = (o & 1) ? cosf(ang) : sinf(ang);
}

__global__ void cvt_kernel(const float* __restrict__ in, short* __restrict__ out, int n) {
  for (int i = blockIdx.x * 256 + threadIdx.x; i < n; i += gridDim.x * 256)
    out[i] = (short)f2bf(in[i]);
}

// Bpadb[o][j*32+c]=tok_W[o][c][j]; Wtr3b[o][j*512+c]=trW[o][c][j] (o<32); p3padb; p3bpadf
__global__ void prep_kernel(const float* __restrict__ tok_W, const float* __restrict__ trW,
                            const float* __restrict__ p3W, const float* __restrict__ p3b,
                            short* __restrict__ Bpadb, short* __restrict__ Wtr3b,
                            short* __restrict__ p3padb, float* __restrict__ p3bpadf) {
  int idx = blockIdx.x * 256 + threadIdx.x;
  if (idx < 512 * 128) {
    int o = idx >> 7, s = idx & 127, j = s >> 5, c = s & 31;
    Bpadb[idx] = (j < 3) ? (short)f2bf(tok_W[o * 96 + c * 3 + j]) : (short)0;
  }
  if (idx < 128 * 1536) {
    int o = idx / 1536, r = idx % 1536, j = r >> 9, c = r & 511;
    Wtr3b[idx] = (o < 32) ? (short)f2bf(trW[(long)o * 1536 + c * 3 + j]) : (short)0;
  }
  if (idx < 128 * 512) {
    int o = idx >> 9, k = idx & 511;
    p3padb[idx] = (o < 32) ? (short)f2bf(p3W[o * 512 + k]) : (short)0;
  }
  if (idx < 128) p3bpadf[idx] = (idx < 32) ? p3b[idx] : 0.f;
}

// win[row][128] bf16 = [x[t-1,:], x[t,:], x[t+1,:], 0] circular
__global__ void winbuild_kernel(const float* __restrict__ x, short* __restrict__ win) {
  int idx = blockIdx.x * 256 + threadIdx.x;
  int s4 = idx & 31;
  int row = idx >> 5;
  int t = row & (cL - 1), b = row >> 10;
  int j = s4 >> 3, c4 = s4 & 7;
  unsigned int lo = 0, hi = 0;
  if (j < 3) {
    int ts = (t + j + cL - 1) & (cL - 1);
    float4 v = *(const float4*)&x[((long)b * cL + ts) * cCIN + c4 * 4];
    lo = (unsigned int)f2bf(v.x) | ((unsigned int)f2bf(v.y) << 16);
    hi = (unsigned int)f2bf(v.z) | ((unsigned int)f2bf(v.w) << 16);
  }
  *(uint2*)&win[row * 128 + s4 * 4] = make_uint2(lo, hi);
}

// batched bf16 transpose: in [B][1024][512] -> out [B][512][1024]
__global__ __launch_bounds__(256) void transpose_bf(const short* __restrict__ in,
                                                    short* __restrict__ out) {
  __shared__ short tile[32][33];
  int b = blockIdx.z;
  in += (long)b * cL * cDM;
  out += (long)b * cL * cDM;
  int c0 = blockIdx.x * 32, t0 = blockIdx.y * 32;
  int tx = threadIdx.x & 31, ty = threadIdx.x >> 5;
#pragma unroll
  for (int r = 0; r < 32; r += 8) tile[ty + r][tx] = in[(long)(t0 + ty + r) * cDM + c0 + tx];
  __syncthreads();
#pragma unroll
  for (int r = 0; r < 32; r += 8)
    out[(long)(c0 + ty + r) * cL + t0 + tx] = tile[tx][ty + r];
}

// ==== moving-average decomposition, sliding-window; optional bf16 ma accumulate ====
__global__ void decomp_kernel(const float* __restrict__ x, float* __restrict__ sf,
                              short* __restrict__ sb, float* __restrict__ maf,
                              short* __restrict__ mab, int maacc, int n8, int C) {
  int idx = blockIdx.x * 256 + threadIdx.x;
  if (idx >= n8) return;
  int c = idx % C;
  int u = idx / C;
  int t0 = (u & 127) * 8;
  int b = u >> 7;
  long base = (long)b * cL * C + c;
  float s = 0.f;
#pragma unroll
  for (int j = -12; j <= 12; j++) {
    int tt = t0 + j;
    tt = tt < 0 ? 0 : (tt >= cL ? cL - 1 : tt);
    s += x[base + (long)tt * C];
  }
#pragma unroll
  for (int k = 0; k < 8; k++) {
    int t = t0 + k;
    long e = base + (long)t * C;
    float ma = s * (1.0f / 25.0f);
    float se = x[e] - ma;
    if (sf) sf[e] = se;
    if (sb) sb[e] = (short)f2bf(se);
    if (maf) maf[e] = ma;
    if (mab) {
      float v = maacc ? bf2f((unsigned short)mab[e]) + ma : ma;
      mab[e] = (short)f2bf(v);
    }
    int ta = t + 13;
    ta = ta >= cL ? cL - 1 : ta;
    int td = t - 12;
    td = td < 0 ? 0 : td;
    s += x[base + (long)ta * C] - x[base + (long)td * C];
  }
}

// ================= final time projection =================
__global__ __launch_bounds__(256) void p2_kernel(const float* __restrict__ x,
                                                 const float* __restrict__ W,
                                                 const float* __restrict__ bias,
                                                 float* __restrict__ out) {
  __shared__ float tile[256 * 32];
  int b = blockIdx.x;
  int p0 = blockIdx.y * 8;
  int c = threadIdx.x & 31, pl = threadIdx.x >> 5;
  const float* xb = x + (long)b * cL * cCIN;
  const float* w = W + (long)(p0 + pl) * cL;
  float s = 0.f;
  for (int l0 = 0; l0 < cL; l0 += 256) {
    __syncthreads();
    for (int i = threadIdx.x; i < 256 * 32; i += 256) tile[i] = xb[(long)l0 * 32 + i];
    __syncthreads();
#pragma unroll 8
    for (int l = 0; l < 256; l++) s += tile[l * 32 + c] * w[l0 + l];
  }
  out[((long)b * cPRED + p0 + pl) * cCIN + c] = s + bias[p0 + pl];
}

// ====== per-(h,mode) complex mode mix; W bf16; o-split x2; transposed bf16 out ======
// grid: BG*8*2 blocks. id -> b = id>>4, h = (id>>1)&7, half = id&1 (o in [half*32, half*32+32))
__global__ __launch_bounds__(256) void modemix_t_kernel(const float* __restrict__ F,
                                                        const unsigned short* __restrict__ W,
                                                        short* __restrict__ Gt, float scale) {
  int id = blockIdx.x;
  int b = id >> 4, h = (id >> 1) & 7, half = id & 1;
  __shared__ float2 Fs[cE][cM];
  __shared__ short ot[128][40];
  const float* Fb = F + ((long)b * cDM + h * cE) * M2;
  for (int i = threadIdx.x; i < cE * cM; i += 256) {
    int e = i >> 6, x = i & 63;
    Fs[e][x] = ((const float2*)(Fb + (long)e * M2))[x];
  }
  __syncthreads();
  int x = threadIdx.x & 63, og = threadIdx.x >> 6;
  float2 acc[8];
#pragma unroll
  for (int i = 0; i < 8; i++) acc[i] = make_float2(0.f, 0.f);
  for (int e = 0; e < cE; e++) {
    float2 f = Fs[e][x];
#pragma unroll
    for (int i = 0; i < 8; i++) {
      int o = half * 32 + og * 8 + i;
      unsigned int wu = *(const unsigned int*)&W[((((long)h * cE + e) * cE + o) * cM + x) * 2];
      float wx = bf2f((unsigned short)wu), wy = bf2f((unsigned short)(wu >> 16));
      acc[i].x += f.x * wx - f.y * wy;
      acc[i].y += f.x * wy + f.y * wx;
    }
  }
#pragma unroll
  for (int i = 0; i < 8; i++) {
    int ol = og * 8 + i;
    ot[2 * x][ol] = (short)f2bf(acc[i].x * scale);
    ot[2 * x + 1][ol] = (short)f2bf(acc[i].y * scale);
  }
  __syncthreads();
  short* gb = Gt + (long)b * (M2 * cDM) + h * cE + half * 32;
  for (int u = threadIdx.x; u < 512; u += 256) {
    int row = u >> 2, seg = u & 3;
    *(uint4*)&gb[(long)row * cDM + seg * 8] = *(const uint4*)&ot[row][seg * 8];
  }
}

// ====== fused cross attention (W bf16, h-major grid, conflict-free LDS layouts) ======
// KsT[y][e] (K transposed), qks[y][x]; qkv overwrites KsT region as Qv[e][x].
__global__ __launch_bounds__(256) void fused_cross_kernel(const float* __restrict__ Fq,
                                                          const float* __restrict__ Fk,
                                                          const unsigned short* __restrict__ W,
                                                          short* __restrict__ Gt, float scale) {
  __shared__ __align__(16) char smem[65536];
  float2(*KsT)[cE] = (float2(*)[cE])smem;            // [y][e]
  float2(*qks)[cM] = (float2(*)[cM])(smem + 32768);  // [y][x]
  int b = blockIdx.x >> 3, h = blockIdx.x & 7;
  const float* kb = Fk + ((long)b * cDM + h * cE) * M2;
  for (int i = threadIdx.x; i < cE * cM; i += 256) {
    int e = i >> 6, y = i & 63;
    KsT[y][e] = ((const float2*)(kb + (long)e * M2))[y];
  }
  __syncthreads();
  { // phase 1: qk[y][x] = tanh(sum_e q[e][x] * k[e][y])
    int x = threadIdx.x & 63, yg = threadIdx.x >> 6;
    const float* qb = Fq + ((long)b * cDM + h * cE) * M2;
    float2 acc[16];
#pragma unroll
    for (int i = 0; i < 16; i++) acc[i] = make_float2(0.f, 0.f);
    for (int e = 0; e < cE; e++) {
      float2 q = ((const float2*)(qb + (long)e * M2))[x];
#pragma unroll
      for (int i = 0; i < 16; i++) {
        float2 k = KsT[yg * 16 + i][e]; // row uniform per i -> broadcast
        acc[i].x += q.x * k.x - q.y * k.y;
        acc[i].y += q.x * k.y + q.y * k.x;
      }
    }
#pragma unroll
    for (int i = 0; i < 16; i++) {
      int y = yg * 16 + i;
      float a = acc[i].x, bi = acc[i].y;
      float re, im;
      float t2a = 2.f * a;
      if (fabsf(t2a) > 60.f) {
        re = t2a > 0.f ? 1.f : -1.f;
        im = 0.f;
      } else {
        float denom = coshf(t2a) + cosf(2.f * bi);
        re = sinhf(t2a) / denom;
        im = sinf(2.f * bi) / denom;
      }
      qks[y][x] = make_float2(re, im); // x per-lane consecutive -> conflict-free
    }
  }
  __syncthreads();
  // phase 2: qkv[e][x] = sum_y qk[y][x] * k[e][y]
  int e = threadIdx.x & 63, xg = threadIdx.x >> 6;
  float2 a2[16];
#pragma unroll
  for (int i = 0; i < 16; i++) a2[i] = make_float2(0.f, 0.f);
  for (int y = 0; y < cM; y++) {
    float2 k = KsT[y][e]; // row uniform, col per-lane -> conflict-free
#pragma unroll
    for (int i = 0; i < 16; i++) {
      float2 qk = qks[y][xg * 16 + i]; // broadcast
      a2[i].x += qk.x * k.x - qk.y * k.y;
      a2[i].y += qk.x * k.y + qk.y * k.x;
    }
  }
  __syncthreads(); // all KsT/qks reads done
  float2(*Qv)[cM] = (float2(*)[cM])smem; // qkv[e][x] over KsT region
#pragma unroll
  for (int i = 0; i < 16; i++) Qv[e][xg * 16 + i] = a2[i];
  __syncthreads();
  { // phase 3: mix + transposed bf16 store
    int x = threadIdx.x & 63, og = threadIdx.x >> 6;
    float2 m[16];
#pragma unroll
    for (int i = 0; i < 16; i++) m[i] = make_float2(0.f, 0.f);
    for (int ee = 0; ee < cE; ee++) {
      float2 f = Qv[ee][x]; // 4-way (benign)
#pragma unroll
      for (int i = 0; i < 16; i++) {
        int o = og * 16 + i;
        unsigned int wu = *(const unsigned int*)&W[((((long)h * cE + ee) * cE + o) * cM + x) * 2];
        float wx = bf2f((unsigned short)wu), wy = bf2f((unsigned short)(wu >> 16));
        m[i].x += f.x * wx - f.y * wy;
        m[i].y += f.x * wy + f.y * wx;
      }
    }
    short(*ot)[72] = (short(*)[72])(smem + 32768);
#pragma unroll
    for (int i = 0; i < 16; i++) {
      int o = og * 16 + i;
      ot[2 * x][o] = (short)f2bf(m[i].x * scale);
      ot[2 * x + 1][o] = (short)f2bf(m[i].y * scale);
    }
    __syncthreads();
    short* gb = Gt + (long)b * (M2 * cDM) + h * cE;
    for (int u = threadIdx.x; u < 1024; u += 256) {
      int row = u >> 3, seg = u & 7;
      *(uint4*)&gb[(long)row * cDM + seg * 8] =
          *(const uint4*)&((short(*)[72])(smem + 32768))[row][seg * 8];
    }
  }
}

// ================= f32 shader GEMM (tiny p1 only) =================
constexpr int GBM = 128, GBN = 128, GBK = 16, LPAD = 132;

__global__ __launch_bounds__(256) void gemm_kernel(const float* __restrict__ A,
                                                   const float* __restrict__ B,
                                                   const float* __restrict__ bias,
                                                   float* __restrict__ C, int M, int N, int K) {
  __shared__ float As[GBK][LPAD];
  __shared__ float Bs[GBK][LPAD];
  int n0 = blockIdx.x * GBN, m0 = blockIdx.y * GBM;
  int tid = threadIdx.x;
  int tx = tid & 15, ty = tid >> 4;
  float acc[8][8];
#pragma unroll
  for (int i = 0; i < 8; i++)
#pragma unroll
    for (int j = 0; j < 8; j++) acc[i][j] = 0.f;

  for (int k0 = 0; k0 < K; k0 += GBK) {
#pragma unroll
    for (int p = 0; p < 8; p++) {
      int i = p * 256 + tid;
      int mm = i >> 4, kk = i & 15;
      int gm = m0 + mm;
      As[kk][mm] = (gm < M && k0 + kk < K) ? A[(long)gm * K + k0 + kk] : 0.f;
    }
#pragma unroll
    for (int p = 0; p < 8; p++) {
      int i = p * 256 + tid;
      int nn = i >> 4, kk = i & 15;
      int gn = n0 + nn;
      Bs[kk][nn] = (gn < N && k0 + kk < K) ? B[(long)gn * K + k0 + kk] : 0.f;
    }
    __syncthreads();
#pragma unroll
    for (int kk = 0; kk < GBK; kk++) {
      float a[8], bb[8];
      *(float4*)&a[0] = *(const float4*)&As[kk][ty * 8];
      *(float4*)&a[4] = *(const float4*)&As[kk][ty * 8 + 4];
      *(float4*)&bb[0] = *(const float4*)&Bs[kk][tx * 8];
      *(float4*)&bb[4] = *(const float4*)&Bs[kk][tx * 8 + 4];
#pragma unroll
      for (int i = 0; i < 8; i++)
#pragma unroll
        for (int j = 0; j < 8; j++) acc[i][j] += a[i] * bb[j];
    }
    __syncthreads();
  }

  for (int i = 0; i < 8; i++) {
    int gm = m0 + ty * 8 + i;
    if (gm >= M) break;
    long rowoff = (long)gm * N;
    for (int j = 0; j < 8; j++) {
      int gn = n0 + tx * 8 + j;
      if (gn < N) C[rowoff + gn] = acc[i][j] + (bias ? bias[gn] : 0.f);
    }
  }
}

// ===== bf16 MFMA GEMM (m97 single-buffer, swizzled, XCD-chunked; zsplit dual mode) =====
__global__ __launch_bounds__(256) void mfma_gemm_bf(
    const short* __restrict__ A, const short* __restrict__ B, const float* __restrict__ bias,
    const float* __restrict__ addend, const float* __restrict__ pe, const float* __restrict__ m0b,
    float* __restrict__ Cf, short* __restrict__ Cb, int M, int N, int K, int lda, long sA, long sB,
    long sC, int relu, int Nreal, int ldc, int amode, const short* __restrict__ A2,
    const short* __restrict__ B2, const float* __restrict__ m0b2, float* __restrict__ Cf2,
    int zsplit) {
  __shared__ __align__(16) short As[8192];
  __shared__ __align__(16) short Bs[8192];
  int nwg = gridDim.x * gridDim.y * gridDim.z;
  int orig = blockIdx.x + gridDim.x * (blockIdx.y + gridDim.y * blockIdx.z);
  int q = nwg >> 3, r = nwg & 7;
  int xcd = orig & 7, ii = orig >> 3;
  int flat = (xcd < r ? xcd * (q + 1) : r * (q + 1) + (xcd - r) * q) + ii;
  int bx = flat % (int)gridDim.x;
  int tmp = flat / (int)gridDim.x;
  int by = tmp % (int)gridDim.y;
  int bz = tmp / (int)gridDim.y;

  int z = bz;
  if (zsplit > 0 && bz >= zsplit) {
    A = A2;
    B = B2;
    m0b = m0b2;
    Cf = Cf2;
    z = bz - zsplit;
  }
  A += (long)z * sA;
  B += (long)z * sB;
  if (Cf) Cf += (long)z * sC;
  if (Cb) Cb += (long)z * sC;
  const float* Ad = addend ? addend + (long)z * sC : nullptr;
  int n0 = bx * 128, m0 = by * 128;
  int tid = threadIdx.x;
  int lane = tid & 63;
  int w = tid >> 6;
  int wm = w & 1, wn = w >> 1;
  int lr = lane & 15, lg = lane >> 4;
  int lrow = lane >> 3;
  int scol = ((lane & 7) * 8) ^ (lrow << 3);

  float4v acc[4][4];
#pragma unroll
  for (int i = 0; i < 4; i++)
#pragma unroll
    for (int j = 0; j < 4; j++) acc[i][j] = (float4v){0.f, 0.f, 0.f, 0.f};

  auto stage = [&](int k0) {
#pragma unroll
    for (int j = 0; j < 4; j++) {
      int seg = w * 4 + j;
      int row = seg * 8 + lrow;
      const short* ga;
      if (amode == 0) {
        ga = A + (long)(m0 + row) * lda + k0 + scol;
      } else {
        int r2 = m0 + row;
        int bb = r2 >> 10, t = r2 & 1023;
        int jj = k0 >> 9, c0 = k0 & 511;
        ga = A + ((((long)(bb << 10)) | ((t + jj + 1023) & 1023)) << 9) + c0 + scol;
      }
      gld16(ga, &As[seg * 512]);
      const short* gb = B + (long)(n0 + row) * K + k0 + scol;
      gld16(gb, &Bs[seg * 512]);
    }
  };

  int nk = K >> 6;
  int swr = (lr & 7) << 3;
  for (int t = 0; t < nk; ++t) {
    stage(t << 6);
    asm volatile("s_waitcnt vmcnt(0)" ::: "memory");
    __syncthreads();
#pragma unroll
    for (int ks = 0; ks < 2; ks++) {
      short8v af[4], bfr[4];
#pragma unroll
      for (int mi = 0; mi < 4; mi++)
        af[mi] = *(const short8v*)&As[(wm * 64 + mi * 16 + lr) * 64 + ((ks * 32 + lg * 8) ^ swr)];
#pragma unroll
      for (int ni = 0; ni < 4; ni++)
        bfr[ni] = *(const short8v*)&Bs[(wn * 64 + ni * 16 + lr) * 64 + ((ks * 32 + lg * 8) ^ swr)];
#pragma unroll
      for (int mi = 0; mi < 4; mi++)
#pragma unroll
        for (int ni = 0; ni < 4; ni++)
          acc[mi][ni] =
              __builtin_amdgcn_mfma_f32_16x16x32_bf16(af[mi], bfr[ni], acc[mi][ni], 0, 0, 0);
    }
    __syncthreads();
  }

#pragma unroll
  for (int mi = 0; mi < 4; mi++) {
#pragma unroll
    for (int i = 0; i < 4; i++) {
      int gr = m0 + wm * 64 + mi * 16 + lg * 4 + i;
      long rowoff = (long)gr * ldc;
#pragma unroll
      for (int ni = 0; ni < 4; ni++) {
        int gc = n0 + wn * 64 + ni * 16 + lr;
        if (gc < Nreal) {
          float v = acc[mi][ni][i];
          if (bias) v += bias[gc];
          if (pe) v += pe[((gr & (cL - 1)) << 9) + gc];
          if (m0b && gc == 0) v += 1024.f * m0b[gr];
          if (Ad) v += Ad[rowoff + gc];
          if (relu) v = fmaxf(v, 0.f);
          if (Cf) Cf[rowoff + gc] = v;
          if (Cb) Cb[rowoff + gc] = (short)f2bf(v);
        }
      }
    }
  }
}

} // namespace

extern "C" void kernel_launch(void* const* d_in, const int* in_sizes, int n_in, void* d_out,
                              int out_size, void* d_ws, size_t ws_size, hipStream_t stream) {
  const float* x_enc = (const float*)d_in[0];
  const float* tok_W = (const float*)d_in[1];
  const float* enc_Wq = (const float*)d_in[2];
  const float* enc_Wo = (const float*)d_in[5];
  const float* enc_bq = (const float*)d_in[6];
  const float* enc_bo = (const float*)d_in[9];
  const float* dsWq = (const float*)d_in[10];
  const float* dsWo = (const float*)d_in[13];
  const float* dsbq = (const float*)d_in[14];
  const float* dsbo = (const float*)d_in[17];
  const float* dcWq = (const float*)d_in[18];
  const float* dcWk = (const float*)d_in[19];
  const float* dcWo = (const float*)d_in[21];
  const float* dcbq = (const float*)d_in[22];
  const float* dcbk = (const float*)d_in[23];
  const float* dcbo = (const float*)d_in[25];
  const float* enc_c1W = (const float*)d_in[26];
  const float* enc_c1b = (const float*)d_in[27];
  const float* enc_c2W = (const float*)d_in[28];
  const float* enc_c2b = (const float*)d_in[29];
  const float* dec_c1W = (const float*)d_in[30];
  const float* dec_c1b = (const float*)d_in[31];
  const float* dec_c2W = (const float*)d_in[32];
  const float* dec_c2b = (const float*)d_in[33];
  const float* dec_trW = (const float*)d_in[34];
  const float* fb_enc = (const float*)d_in[35];
  const float* fb_dec = (const float*)d_in[36];
  const float* fc_w = (const float*)d_in[37];
  const float* p1W = (const float*)d_in[38];
  const float* p1b = (const float*)d_in[39];
  const float* p2W = (const float*)d_in[40];
  const float* p2b = (const float*)d_in[41];
  const float* p3W = (const float*)d_in[42];
  const float* p3b = (const float*)d_in[43];

  constexpr long MIXW = 8L * 64 * 64 * 64 * 2;

  // ---- layout sizing (dry-run) ----
  auto layout_bytes = [&](long BG, long RH) -> size_t {
    size_t t = 0;
    auto add = [&](size_t b) { t = (t + b + 255) & ~(size_t)255; };
    add(2 * 262144 * 2); add(2 * 262144 * 2);
    add(262144 * 2); add(262144 * 2); add(262144 * 2); add(262144 * 2); add(262144 * 2);
    add(2 * 1048576 * 2); add(2 * 1048576 * 2); add(1048576 * 2); add(1048576 * 2);
    add(131072 * 2); add(131072 * 2); add(65536 * 2); add(196608 * 2); add(65536 * 2);
    add(128 * 4); add(524288 * 4);
    add(MIXW * 2); add(MIXW * 2); add(MIXW * 2);
    long GA = BG * cL * cDM;
    add(GA * 4); add(GA * 4); add(GA * 4);
    add(GA * 2); add(GA * 2); add(GA * 2); add(GA * 2);
    add(BG * cL * 128 * 2);
    size_t ub = (size_t)GA * 2;
    size_t hd = (size_t)RH * cDFF * 2;
    add(ub > hd ? ub : hd);
    add(BG * 65536 * 4); add(BG * 65536 * 4);
    add(BG * 65536 * 2); add(BG * 65536 * 2); add(BG * 65536 * 2); add(BG * 65536 * 2);
    add(BG * cL * cCIN * 4); add(BG * cL * cCIN * 4); add(BG * cL * cCIN * 4);
    return t;
  };
  int BG = cB;
  while (BG > 1 && layout_bytes(BG, 512) > ws_size) BG >>= 1;
  long RH = (long)BG * cL;
  while (RH > 512 && layout_bytes(BG, RH) > ws_size) RH >>= 1;

  long GBL = (long)BG * cL;
  char* base = (char*)d_ws;
  size_t off = 0;
  auto alloc = [&](size_t bytes) -> void* {
    void* p = base + off;
    off = (off + bytes + 255) & ~(size_t)255;
    return p;
  };
  short* WqbE = (short*)alloc(2 * 262144 * 2);
  short* WobE = (short*)alloc(2 * 262144 * 2);
  short* dsWqb = (short*)alloc(262144 * 2);
  short* dsWob = (short*)alloc(262144 * 2);
  short* dcWqb = (short*)alloc(262144 * 2);
  short* dcWkb = (short*)alloc(262144 * 2);
  short* dcWob = (short*)alloc(262144 * 2);
  short* c1bE = (short*)alloc(2 * 1048576 * 2);
  short* c2bE = (short*)alloc(2 * 1048576 * 2);
  short* c1bD = (short*)alloc(1048576 * 2);
  short* c2bD = (short*)alloc(1048576 * 2);
  short* basisdb = (short*)alloc(131072 * 2);
  short* basisib = (short*)alloc(131072 * 2);
  short* Bpadb = (short*)alloc(65536 * 2);
  short* Wtr3b = (short*)alloc(196608 * 2);
  short* p3padb = (short*)alloc(65536 * 2);
  float* p3bpadf = (float*)alloc(128 * 4);
  float* pe = (float*)alloc(524288 * 4);
  short* fbEb = (short*)alloc(MIXW * 2);
  short* fbDb = (short*)alloc(MIXW * 2);
  short* fcwb = (short*)alloc(MIXW * 2);
  long GA = GBL * cDM;
  float* E = (float*)alloc(GA * 4);
  float* X = (float*)alloc(GA * 4);
  float* A = (float*)alloc(GA * 4);
  short* Eb = (short*)alloc(GA * 2);
  short* Xb = (short*)alloc(GA * 2);
  short* Ab = (short*)alloc(GA * 2);
  short* Sb = (short*)alloc(GA * 2);
  short* winb = (short*)alloc(GBL * 128 * 2);
  size_t ubsz = (size_t)GA * 2;
  size_t hdsz = (size_t)RH * cDFF * 2;
  short* UB = (short*)alloc(ubsz > hdsz ? ubsz : hdsz); // Tb / HDb (disjoint in time)
  short* Tb = UB;
  short* HDb = UB;
  float* Fq = (float*)alloc((size_t)BG * 65536 * 4);
  float* Fk = (float*)alloc((size_t)BG * 65536 * 4);
  short* FEb = (short*)alloc((size_t)BG * 65536 * 2);
  short* FXb = (short*)alloc((size_t)BG * 65536 * 2);
  short* Gtb = (short*)alloc((size_t)BG * 65536 * 2);
  short* Hb = (short*)alloc((size_t)BG * 65536 * 2);
  float* TRD = (float*)alloc(GBL * cCIN * 4);
  float* O1 = (float*)alloc(GBL * cCIN * 4);
  float* O2 = (float*)alloc(GBL * cCIN * 4);

  auto mg = [&](const short* Am, const short* Bm, const float* bias, const float* add,
                const float* peA, const float* m0b, float* Cf, short* Cb, int Mm, int Nn, int Kk,
                int lda, long sA, long sB, long sC, int batch, int relu, int Nreal, int ldc,
                int amode) {
    dim3 g(Nn / 128, Mm / 128, batch);
    mfma_gemm_bf<<<g, 256, 0, stream>>>(Am, Bm, bias, add, peA, m0b, Cf, Cb, Mm, Nn, Kk, lda, sA,
                                        sB, sC, relu, Nreal, ldc, amode, nullptr, nullptr,
                                        nullptr, nullptr, 0);
  };
  auto cvt = [&](const float* in, short* out, long n) {
    int g = (int)((n + 255) / 256);
    if (g > 4096) g = 4096;
    cvt_kernel<<<g, 256, 0, stream>>>(in, out, (int)n);
  };
  auto decomp = [&](const float* x, float* sf, short* sb, float* maf, short* mab, int maacc,
                    long total, int C_) {
    int n8 = (int)(total / 8);
    decomp_kernel<<<(n8 + 255) / 256, 256, 0, stream>>>(x, sf, sb, maf, mab, maacc, n8, C_);
  };
  // dft: LDS-staged transpose (coalesced) then F[b][m2][dm] bf16 = basisd @ T_b^T
  auto dft = [&](const short* srcb, short* Fout) {
    transpose_bf<<<dim3(16, 32, BG), 256, 0, stream>>>(srcb, Tb);
    mg(basisdb, Tb, nullptr, nullptr, nullptr, nullptr, nullptr, Fout, M2, cDM, cL, cL, 0,
       (long)cDM * cL, 65536, BG, 0, cDM, cDM, 0);
  };
  auto modeproj = [&](const short* Wb, const short* Fin, const float* m0b, float* Cf, short* Cb) {
    mg(Wb, Fin, nullptr, nullptr, nullptr, m0b, Cf, Cb, cDM, M2, cDM, cDM, 0, 65536, 65536, BG, 0,
       M2, M2, 0);
  };
  auto modeproj2 = [&](const short* Wa, const short* Fa, const float* ba, float* Ca,
                       const short* Wb2, const short* Fb2, const float* bb2, float* Cb2) {
    dim3 g(1, cDM / 128, 2 * BG);
    mfma_gemm_bf<<<g, 256, 0, stream>>>(Wa, Fa, nullptr, nullptr, nullptr, ba, Ca, nullptr, cDM,
                                        M2, cDM, cDM, 0, 65536, 65536, 0, M2, M2, 0, Wb2, Fb2,
                                        bb2, Cb2, BG);
  };
  auto idft = [&](const short* Hin, const float* bias, const float* add, float* Cf) {
    mg(basisib, Hin, bias, add, nullptr, nullptr, Cf, nullptr, cL, cDM, M2, M2, 0, 65536,
       (long)cL * cDM, BG, 0, cDM, cDM, 0);
  };
  auto ffn = [&](const short* inb, const float* addf, float* outf, const short* c1w,
                 const float* c1bias, const short* c2w, const float* c2bias) {
    for (long r = 0; r < GBL; r += RH) {
      mg(inb + r * cDM, c1w, c1bias, nullptr, nullptr, nullptr, nullptr, HDb, (int)RH, cDFF, cDM,
         cDM, 0, 0, 0, 1, 1, cDFF, cDFF, 0);
      mg(HDb, c2w, c2bias, addf + r * cDM, nullptr, nullptr, outf + r * cDM, nullptr, (int)RH,
         cDM, cDFF, cDFF, 0, 0, 0, 1, 0, cDM, cDM, 0);
    }
  };
  auto trendg = [&](const short* mab) {
    mg(mab, Wtr3b, nullptr, TRD, nullptr, nullptr, TRD, nullptr, (int)GBL, 128, 1536, 512, 0, 0,
       0, 1, 0, cCIN, cCIN, 1);
  };
  auto mixt = [&](const float* F, const short* W, float scale) {
    modemix_t_kernel<<<BG * cH * 2, 256, 0, stream>>>(F, (const unsigned short*)W, Gtb, scale);
  };

  // ---- one-time setup ----
  basis_kernel<<<(M2 * cL) / 256, 256, 0, stream>>>(basisdb, basisib);
  pe_kernel<<<(cL * cDM) / 256, 256, 0, stream>>>(pe);
  prep_kernel<<<768, 256, 0, stream>>>(tok_W, dec_trW, p3W, p3b, Bpadb, Wtr3b, p3padb, p3bpadf);
  cvt(enc_Wq, WqbE, 524288);
  cvt(enc_Wo, WobE, 524288);
  cvt(dsWq, dsWqb, 262144);
  cvt(dsWo, dsWob, 262144);
  cvt(dcWq, dcWqb, 262144);
  cvt(dcWk, dcWkb, 262144);
  cvt(dcWo, dcWob, 262144);
  cvt(enc_c1W, c1bE, 2097152);
  cvt(enc_c2W, c2bE, 2097152);
  cvt(dec_c1W, c1bD, 1048576);
  cvt(dec_c2W, c2bD, 1048576);
  cvt(fb_enc, fbEb, MIXW);
  cvt(fb_dec, fbDb, MIXW);
  cvt(fc_w, fcwb, MIXW);

  for (int b0 = 0; b0 < cB; b0 += BG) {
    const float* xg = x_enc + (long)b0 * cL * cCIN;

    decomp(xg, nullptr, nullptr, TRD, nullptr, 0, GBL * cCIN, cCIN); // trend_init
    winbuild_kernel<<<(int)(GBL * 32 / 256), 256, 0, stream>>>(xg, winb);
    mg(winb, Bpadb, nullptr, nullptr, pe, nullptr, E, Eb, (int)GBL, cDM, 128, 128, 0, 0, 0, 1, 0,
       cDM, cDM, 0); // embedding

    // ---- encoder ----
    for (int l = 0; l < 2; l++) {
      dft(Eb, FEb);
      modeproj(WqbE + (long)l * 262144, FEb, enc_bq + l * cDM, Fq, nullptr);
      mixt(Fq, fbEb, 1.0f);
      modeproj(WobE + (long)l * 262144, Gtb, nullptr, nullptr, Hb);
      idft(Hb, enc_bo + l * cDM, E, A);
      decomp(A, X, Xb, nullptr, nullptr, 0, GA, cDM);                // h -> X,Xb
      ffn(Xb, X, A, c1bE + (long)l * 1048576, enc_c1b + l * cDFF, c2bE + (long)l * 1048576,
          enc_c2b + l * cDM);
      decomp(A, E, Eb, nullptr, nullptr, 0, GA, cDM);                // stream -> E,Eb
    }

    // ---- decoder ----
    dft(Eb, FEb);
    modeproj(dsWqb, FEb, dsbq, Fq, nullptr);
    mixt(Fq, fbDb, 1.0f);
    modeproj(dsWob, Gtb, nullptr, nullptr, Hb);
    idft(Hb, dsbo, E, A);                                            // x1 -> A
    decomp(A, X, Xb, nullptr, Sb, 0, GA, cDM);                       // x2 -> X,Xb; ma -> Sb
    dft(Xb, FXb);
    modeproj2(dcWqb, FXb, dcbq, Fq, dcWkb, FEb, dcbk, Fk);
    fused_cross_kernel<<<BG * cH, 256, 0, stream>>>(Fq, Fk, (const unsigned short*)fcwb, Gtb,
                                                    1.0f / (float)(cDM * cDM));
    modeproj(dcWob, Gtb, nullptr, nullptr, Hb);
    idft(Hb, dcbo, X, E);                                            // x3 -> E
    decomp(E, A, Ab, nullptr, Sb, 1, GA, cDM);                       // x4; ma += Sb
    ffn(Ab, A, E, c1bD, dec_c1b, c2bD, dec_c2b);                     // x4+y -> E
    decomp(E, nullptr, Xb, nullptr, Sb, 1, GA, cDM);                 // x5 -> Xb; ma += Sb
    trendg(Sb);                                                      // conv(t1+t2+t3)

    // ---- final projections ----
    mg(Xb, p3padb, p3bpadf, TRD, nullptr, nullptr, O1, nullptr, (int)GBL, 128, cDM, cDM, 0, 0, 0,
       1, 0, cCIN, cCIN, 0);
    gemm_kernel<<<dim3(1, (int)(GBL / 128)), 256, 0, stream>>>(O1, p1W, p1b, O2, (int)GBL, cCIN,
                                                               cCIN);
    p2_kernel<<<dim3(BG, 32), 256, 0, stream>>>(O2, p2W, p2b,
                                                (float*)d_out + (long)b0 * cPRED * cCIN);
  }
}

// Round 13
// 3303.745 us; speedup vs baseline: 1.3027x; 1.2790x over previous
//
#include <hip/hip_runtime.h>
#include <math.h>

namespace {

constexpr int cB = 32, cL = 1024, cCIN = 32, cDM = 512, cDFF = 2048;
constexpr int cH = 8, cE = 64, cM = 64, cPRED = 256;
constexpr int M2 = 2 * cM; // 128

typedef __attribute__((ext_vector_type(8))) short short8v;
typedef __attribute__((ext_vector_type(4))) float float4v;

__device__ inline unsigned short f2bf(float f) {
  unsigned int u = __builtin_bit_cast(unsigned int, f);
  u += 0x7FFFu + ((u >> 16) & 1u); // RNE
  return (unsigned short)(u >> 16);
}
__device__ inline float bf2f(unsigned short s) {
  return __builtin_bit_cast(float, (unsigned int)s << 16);
}

typedef const __attribute__((address_space(1))) unsigned int gu32_t;
typedef __attribute__((address_space(3))) unsigned int lu32_t;
__device__ inline void gld16(const void* g, void* l) {
  __builtin_amdgcn_global_load_lds((gu32_t*)g, (lu32_t*)l, 16, 0, 0);
}

// ================= one-time tables =================
__global__ void basis_kernel(short* __restrict__ basisdb, short* __restrict__ basisib) {
  int idx = blockIdx.x * 256 + threadIdx.x;
  if (idx >= M2 * cL) return;
  int t = idx & (cL - 1);
  int m2 = idx >> 10;
  int m = m2 >> 1;
  float ang = 6.2831853071795864f * (float)((m * t) & (cL - 1)) / (float)cL;
  float cv = cosf(ang), sv = sinf(ang);
  float vd = (m2 & 1) ? -sv : cv;
  basisdb[idx] = (short)f2bf(vd);
  float s = (m == 0) ? ((m2 & 1) ? 0.f : (1.f / (float)cL)) : (2.f / (float)cL);
  basisib[t * M2 + m2] = (short)f2bf(vd * s);
}

__global__ void pe_kernel(float* __restrict__ pe) {
  int idx = blockIdx.x * 256 + threadIdx.x;
  int o = idx & (cDM - 1), t = idx >> 9;
  int i = o >> 1;
  float freq = __expf((float)(2 * i) * (-9.210340371976184f / (float)cDM));
  float ang = freq * (float)t;
  pe[idx] = (o & 1) ? cosf(ang) : sinf(ang);
}

__global__ void cvt_kernel(const float* __restrict__ in, short* __restrict__ out, int n) {
  for (int i = blockIdx.x * 256 + threadIdx.x; i < n; i += gridDim.x * 256)
    out[i] = (short)f2bf(in[i]);
}

// Bpadb[o][j*32+c]=tok_W[o][c][j]; Wtr3b[o][j*512+c]=trW[o][c][j] (o<32); p3padb; p3bpadf
__global__ void prep_kernel(const float* __restrict__ tok_W, const float* __restrict__ trW,
                            const float* __restrict__ p3W, const float* __restrict__ p3b,
                            short* __restrict__ Bpadb, short* __restrict__ Wtr3b,
                            short* __restrict__ p3padb, float* __restrict__ p3bpadf) {
  int idx = blockIdx.x * 256 + threadIdx.x;
  if (idx < 512 * 128) {
    int o = idx >> 7, s = idx & 127, j = s >> 5, c = s & 31;
    Bpadb[idx] = (j < 3) ? (short)f2bf(tok_W[o * 96 + c * 3 + j]) : (short)0;
  }
  if (idx < 128 * 1536) {
    int o = idx / 1536, r = idx % 1536, j = r >> 9, c = r & 511;
    Wtr3b[idx] = (o < 32) ? (short)f2bf(trW[(long)o * 1536 + c * 3 + j]) : (short)0;
  }
  if (idx < 128 * 512) {
    int o = idx >> 9, k = idx & 511;
    p3padb[idx] = (o < 32) ? (short)f2bf(p3W[o * 512 + k]) : (short)0;
  }
  if (idx < 128) p3bpadf[idx] = (idx < 32) ? p3b[idx] : 0.f;
}

// win[row][128] bf16 = [x[t-1,:], x[t,:], x[t+1,:], 0] circular
__global__ void winbuild_kernel(const float* __restrict__ x, short* __restrict__ win) {
  int idx = blockIdx.x * 256 + threadIdx.x;
  int s4 = idx & 31;
  int row = idx >> 5;
  int t = row & (cL - 1), b = row >> 10;
  int j = s4 >> 3, c4 = s4 & 7;
  unsigned int lo = 0, hi = 0;
  if (j < 3) {
    int ts = (t + j + cL - 1) & (cL - 1);
    float4 v = *(const float4*)&x[((long)b * cL + ts) * cCIN + c4 * 4];
    lo = (unsigned int)f2bf(v.x) | ((unsigned int)f2bf(v.y) << 16);
    hi = (unsigned int)f2bf(v.z) | ((unsigned int)f2bf(v.w) << 16);
  }
  *(uint2*)&win[row * 128 + s4 * 4] = make_uint2(lo, hi);
}

// batched bf16 transpose: in [B][1024][512] -> out [B][512][1024]
__global__ __launch_bounds__(256) void transpose_bf(const short* __restrict__ in,
                                                    short* __restrict__ out) {
  __shared__ short tile[32][33];
  int b = blockIdx.z;
  in += (long)b * cL * cDM;
  out += (long)b * cL * cDM;
  int c0 = blockIdx.x * 32, t0 = blockIdx.y * 32;
  int tx = threadIdx.x & 31, ty = threadIdx.x >> 5;
#pragma unroll
  for (int r = 0; r < 32; r += 8) tile[ty + r][tx] = in[(long)(t0 + ty + r) * cDM + c0 + tx];
  __syncthreads();
#pragma unroll
  for (int r = 0; r < 32; r += 8)
    out[(long)(c0 + ty + r) * cL + t0 + tx] = tile[tx][ty + r];
}

// ==== moving-average decomposition, sliding-window; bf16 seasonal out + optional ma acc ====
__global__ void decomp_kernel(const float* __restrict__ x, short* __restrict__ sb,
                              float* __restrict__ maf, short* __restrict__ mab, int maacc,
                              int n8, int C) {
  int idx = blockIdx.x * 256 + threadIdx.x;
  if (idx >= n8) return;
  int c = idx % C;
  int u = idx / C;
  int t0 = (u & 127) * 8;
  int b = u >> 7;
  long base = (long)b * cL * C + c;
  float s = 0.f;
#pragma unroll
  for (int j = -12; j <= 12; j++) {
    int tt = t0 + j;
    tt = tt < 0 ? 0 : (tt >= cL ? cL - 1 : tt);
    s += x[base + (long)tt * C];
  }
#pragma unroll
  for (int k = 0; k < 8; k++) {
    int t = t0 + k;
    long e = base + (long)t * C;
    float ma = s * (1.0f / 25.0f);
    if (sb) sb[e] = (short)f2bf(x[e] - ma);
    if (maf) maf[e] = ma;
    if (mab) {
      float v = maacc ? bf2f((unsigned short)mab[e]) + ma : ma;
      mab[e] = (short)f2bf(v);
    }
    int ta = t + 13;
    ta = ta >= cL ? cL - 1 : ta;
    int td = t - 12;
    td = td < 0 ? 0 : td;
    s += x[base + (long)ta * C] - x[base + (long)td * C];
  }
}

// ================= final time projection =================
__global__ __launch_bounds__(256) void p2_kernel(const float* __restrict__ x,
                                                 const float* __restrict__ W,
                                                 const float* __restrict__ bias,
                                                 float* __restrict__ out) {
  __shared__ float tile[256 * 32];
  int b = blockIdx.x;
  int p0 = blockIdx.y * 8;
  int c = threadIdx.x & 31, pl = threadIdx.x >> 5;
  const float* xb = x + (long)b * cL * cCIN;
  const float* w = W + (long)(p0 + pl) * cL;
  float s = 0.f;
  for (int l0 = 0; l0 < cL; l0 += 256) {
    __syncthreads();
    for (int i = threadIdx.x; i < 256 * 32; i += 256) tile[i] = xb[(long)l0 * 32 + i];
    __syncthreads();
#pragma unroll 8
    for (int l = 0; l < 256; l++) s += tile[l * 32 + c] * w[l0 + l];
  }
  out[((long)b * cPRED + p0 + pl) * cCIN + c] = s + bias[p0 + pl];
}

// ====== per-(h,mode) complex mode mix; W bf16; r10 2-D grid; transposed bf16 out ======
__global__ __launch_bounds__(256) void modemix_t_kernel(const float* __restrict__ F,
                                                        const unsigned short* __restrict__ W,
                                                        short* __restrict__ Gt, float scale) {
  int b = blockIdx.x, h = blockIdx.y;
  __shared__ float2 Fs[cE][cM];
  __shared__ short ot[128][72];
  const float* Fb = F + ((long)b * cDM + h * cE) * M2;
  for (int i = threadIdx.x; i < cE * cM; i += 256) {
    int e = i >> 6, x = i & 63;
    Fs[e][x] = ((const float2*)(Fb + (long)e * M2))[x];
  }
  __syncthreads();
  int x = threadIdx.x & 63, og = threadIdx.x >> 6;
  float2 acc[16];
#pragma unroll
  for (int i = 0; i < 16; i++) acc[i] = make_float2(0.f, 0.f);
  for (int e = 0; e < cE; e++) {
    float2 f = Fs[e][x];
#pragma unroll
    for (int i = 0; i < 16; i++) {
      int o = og * 16 + i;
      unsigned int wu = *(const unsigned int*)&W[((((long)h * cE + e) * cE + o) * cM + x) * 2];
      float wx = bf2f((unsigned short)wu), wy = bf2f((unsigned short)(wu >> 16));
      acc[i].x += f.x * wx - f.y * wy;
      acc[i].y += f.x * wy + f.y * wx;
    }
  }
#pragma unroll
  for (int i = 0; i < 16; i++) {
    int o = og * 16 + i;
    ot[2 * x][o] = (short)f2bf(acc[i].x * scale);
    ot[2 * x + 1][o] = (short)f2bf(acc[i].y * scale);
  }
  __syncthreads();
  short* gb = Gt + (long)b * (M2 * cDM) + h * cE;
  for (int u = threadIdx.x; u < 1024; u += 256) {
    int row = u >> 3, seg = u & 7;
    *(uint4*)&gb[(long)row * cDM + seg * 8] = *(const uint4*)&ot[row][seg * 8];
  }
}

// ====== fused cross attention (W bf16, 2-D grid, conflict-free LDS layouts) ======
__global__ __launch_bounds__(256) void fused_cross_kernel(const float* __restrict__ Fq,
                                                          const float* __restrict__ Fk,
                                                          const unsigned short* __restrict__ W,
                                                          short* __restrict__ Gt, float scale) {
  __shared__ __align__(16) char smem[65536];
  float2(*KsT)[cE] = (float2(*)[cE])smem;            // [y][e]
  float2(*qks)[cM] = (float2(*)[cM])(smem + 32768);  // [y][x]
  int b = blockIdx.x, h = blockIdx.y;
  const float* kb = Fk + ((long)b * cDM + h * cE) * M2;
  for (int i = threadIdx.x; i < cE * cM; i += 256) {
    int e = i >> 6, y = i & 63;
    KsT[y][e] = ((const float2*)(kb + (long)e * M2))[y];
  }
  __syncthreads();
  { // phase 1: qk[y][x] = tanh(sum_e q[e][x] * k[e][y])
    int x = threadIdx.x & 63, yg = threadIdx.x >> 6;
    const float* qb = Fq + ((long)b * cDM + h * cE) * M2;
    float2 acc[16];
#pragma unroll
    for (int i = 0; i < 16; i++) acc[i] = make_float2(0.f, 0.f);
    for (int e = 0; e < cE; e++) {
      float2 q = ((const float2*)(qb + (long)e * M2))[x];
#pragma unroll
      for (int i = 0; i < 16; i++) {
        float2 k = KsT[yg * 16 + i][e];
        acc[i].x += q.x * k.x - q.y * k.y;
        acc[i].y += q.x * k.y + q.y * k.x;
      }
    }
#pragma unroll
    for (int i = 0; i < 16; i++) {
      int y = yg * 16 + i;
      float a = acc[i].x, bi = acc[i].y;
      float re, im;
      float t2a = 2.f * a;
      if (fabsf(t2a) > 60.f) {
        re = t2a > 0.f ? 1.f : -1.f;
        im = 0.f;
      } else {
        float denom = coshf(t2a) + cosf(2.f * bi);
        re = sinhf(t2a) / denom;
        im = sinf(2.f * bi) / denom;
      }
      qks[y][x] = make_float2(re, im);
    }
  }
  __syncthreads();
  // phase 2: qkv[e][x] = sum_y qk[y][x] * k[e][y]
  int e = threadIdx.x & 63, xg = threadIdx.x >> 6;
  float2 a2[16];
#pragma unroll
  for (int i = 0; i < 16; i++) a2[i] = make_float2(0.f, 0.f);
  for (int y = 0; y < cM; y++) {
    float2 k = KsT[y][e];
#pragma unroll
    for (int i = 0; i < 16; i++) {
      float2 qk = qks[y][xg * 16 + i];
      a2[i].x += qk.x * k.x - qk.y * k.y;
      a2[i].y += qk.x * k.y + qk.y * k.x;
    }
  }
  __syncthreads();
  float2(*Qv)[cM] = (float2(*)[cM])smem;
#pragma unroll
  for (int i = 0; i < 16; i++) Qv[e][xg * 16 + i] = a2[i];
  __syncthreads();
  { // phase 3: mix + transposed bf16 store
    int x = threadIdx.x & 63, og = threadIdx.x >> 6;
    float2 m[16];
#pragma unroll
    for (int i = 0; i < 16; i++) m[i] = make_float2(0.f, 0.f);
    for (int ee = 0; ee < cE; ee++) {
      float2 f = Qv[ee][x];
#pragma unroll
      for (int i = 0; i < 16; i++) {
        int o = og * 16 + i;
        unsigned int wu = *(const unsigned int*)&W[((((long)h * cE + ee) * cE + o) * cM + x) * 2];
        float wx = bf2f((unsigned short)wu), wy = bf2f((unsigned short)(wu >> 16));
        m[i].x += f.x * wx - f.y * wy;
        m[i].y += f.x * wy + f.y * wx;
      }
    }
    short(*ot)[72] = (short(*)[72])(smem + 32768);
#pragma unroll
    for (int i = 0; i < 16; i++) {
      int o = og * 16 + i;
      ot[2 * x][o] = (short)f2bf(m[i].x * scale);
      ot[2 * x + 1][o] = (short)f2bf(m[i].y * scale);
    }
    __syncthreads();
    short* gb = Gt + (long)b * (M2 * cDM) + h * cE;
    for (int u = threadIdx.x; u < 1024; u += 256) {
      int row = u >> 3, seg = u & 7;
      *(uint4*)&gb[(long)row * cDM + seg * 8] =
          *(const uint4*)&((short(*)[72])(smem + 32768))[row][seg * 8];
    }
  }
}

// ================= f32 shader GEMM (tiny p1 only) =================
constexpr int GBM = 128, GBN = 128, GBK = 16, LPAD = 132;

__global__ __launch_bounds__(256) void gemm_kernel(const float* __restrict__ A,
                                                   const float* __restrict__ B,
                                                   const float* __restrict__ bias,
                                                   float* __restrict__ C, int M, int N, int K) {
  __shared__ float As[GBK][LPAD];
  __shared__ float Bs[GBK][LPAD];
  int n0 = blockIdx.x * GBN, m0 = blockIdx.y * GBM;
  int tid = threadIdx.x;
  int tx = tid & 15, ty = tid >> 4;
  float acc[8][8];
#pragma unroll
  for (int i = 0; i < 8; i++)
#pragma unroll
    for (int j = 0; j < 8; j++) acc[i][j] = 0.f;

  for (int k0 = 0; k0 < K; k0 += GBK) {
#pragma unroll
    for (int p = 0; p < 8; p++) {
      int i = p * 256 + tid;
      int mm = i >> 4, kk = i & 15;
      int gm = m0 + mm;
      As[kk][mm] = (gm < M && k0 + kk < K) ? A[(long)gm * K + k0 + kk] : 0.f;
    }
#pragma unroll
    for (int p = 0; p < 8; p++) {
      int i = p * 256 + tid;
      int nn = i >> 4, kk = i & 15;
      int gn = n0 + nn;
      Bs[kk][nn] = (gn < N && k0 + kk < K) ? B[(long)gn * K + k0 + kk] : 0.f;
    }
    __syncthreads();
#pragma unroll
    for (int kk = 0; kk < GBK; kk++) {
      float a[8], bb[8];
      *(float4*)&a[0] = *(const float4*)&As[kk][ty * 8];
      *(float4*)&a[4] = *(const float4*)&As[kk][ty * 8 + 4];
      *(float4*)&bb[0] = *(const float4*)&Bs[kk][tx * 8];
      *(float4*)&bb[4] = *(const float4*)&Bs[kk][tx * 8 + 4];
#pragma unroll
      for (int i = 0; i < 8; i++)
#pragma unroll
        for (int j = 0; j < 8; j++) acc[i][j] += a[i] * bb[j];
    }
    __syncthreads();
  }

  for (int i = 0; i < 8; i++) {
    int gm = m0 + ty * 8 + i;
    if (gm >= M) break;
    long rowoff = (long)gm * N;
    for (int j = 0; j < 8; j++) {
      int gn = n0 + tx * 8 + j;
      if (gn < N) C[rowoff + gn] = acc[i][j] + (bias ? bias[gn] : 0.f);
    }
  }
}

// ===== bf16 MFMA GEMM (m97 single-buffer, swizzled, XCD-chunked; zsplit dual mode) =====
// Epilogue: +bias +pe +m0b +Ad(f32 addend) +Adb(bf16 addend) relu; writes Cf/Cb.
__global__ __launch_bounds__(256) void mfma_gemm_bf(
    const short* __restrict__ A, const short* __restrict__ B, const float* __restrict__ bias,
    const float* __restrict__ addend, const short* __restrict__ addendb,
    const float* __restrict__ pe, const float* __restrict__ m0b, float* __restrict__ Cf,
    short* __restrict__ Cb, int M, int N, int K, int lda, long sA, long sB, long sC, int relu,
    int Nreal, int ldc, int amode, const short* __restrict__ A2, const short* __restrict__ B2,
    const float* __restrict__ m0b2, float* __restrict__ Cf2, int zsplit) {
  __shared__ __align__(16) short As[8192];
  __shared__ __align__(16) short Bs[8192];
  int nwg = gridDim.x * gridDim.y * gridDim.z;
  int orig = blockIdx.x + gridDim.x * (blockIdx.y + gridDim.y * blockIdx.z);
  int q = nwg >> 3, r = nwg & 7;
  int xcd = orig & 7, ii = orig >> 3;
  int flat = (xcd < r ? xcd * (q + 1) : r * (q + 1) + (xcd - r) * q) + ii;
  int bx = flat % (int)gridDim.x;
  int tmp = flat / (int)gridDim.x;
  int by = tmp % (int)gridDim.y;
  int bz = tmp / (int)gridDim.y;

  int z = bz;
  if (zsplit > 0 && bz >= zsplit) {
    A = A2;
    B = B2;
    m0b = m0b2;
    Cf = Cf2;
    z = bz - zsplit;
  }
  A += (long)z * sA;
  B += (long)z * sB;
  if (Cf) Cf += (long)z * sC;
  if (Cb) Cb += (long)z * sC;
  const float* Ad = addend ? addend + (long)z * sC : nullptr;
  const short* Adb = addendb ? addendb + (long)z * sC : nullptr;
  int n0 = bx * 128, m0 = by * 128;
  int tid = threadIdx.x;
  int lane = tid & 63;
  int w = tid >> 6;
  int wm = w & 1, wn = w >> 1;
  int lr = lane & 15, lg = lane >> 4;
  int lrow = lane >> 3;
  int scol = ((lane & 7) * 8) ^ (lrow << 3);

  float4v acc[4][4];
#pragma unroll
  for (int i = 0; i < 4; i++)
#pragma unroll
    for (int j = 0; j < 4; j++) acc[i][j] = (float4v){0.f, 0.f, 0.f, 0.f};

  auto stage = [&](int k0) {
#pragma unroll
    for (int j = 0; j < 4; j++) {
      int seg = w * 4 + j;
      int row = seg * 8 + lrow;
      const short* ga;
      if (amode == 0) {
        ga = A + (long)(m0 + row) * lda + k0 + scol;
      } else {
        int r2 = m0 + row;
        int bb = r2 >> 10, t = r2 & 1023;
        int jj = k0 >> 9, c0 = k0 & 511;
        ga = A + ((((long)(bb << 10)) | ((t + jj + 1023) & 1023)) << 9) + c0 + scol;
      }
      gld16(ga, &As[seg * 512]);
      const short* gb = B + (long)(n0 + row) * K + k0 + scol;
      gld16(gb, &Bs[seg * 512]);
    }
  };

  int nk = K >> 6;
  int swr = (lr & 7) << 3;
  for (int t = 0; t < nk; ++t) {
    stage(t << 6);
    asm volatile("s_waitcnt vmcnt(0)" ::: "memory");
    __syncthreads();
#pragma unroll
    for (int ks = 0; ks < 2; ks++) {
      short8v af[4], bfr[4];
#pragma unroll
      for (int mi = 0; mi < 4; mi++)
        af[mi] = *(const short8v*)&As[(wm * 64 + mi * 16 + lr) * 64 + ((ks * 32 + lg * 8) ^ swr)];
#pragma unroll
      for (int ni = 0; ni < 4; ni++)
        bfr[ni] = *(const short8v*)&Bs[(wn * 64 + ni * 16 + lr) * 64 + ((ks * 32 + lg * 8) ^ swr)];
#pragma unroll
      for (int mi = 0; mi < 4; mi++)
#pragma unroll
        for (int ni = 0; ni < 4; ni++)
          acc[mi][ni] =
              __builtin_amdgcn_mfma_f32_16x16x32_bf16(af[mi], bfr[ni], acc[mi][ni], 0, 0, 0);
    }
    __syncthreads();
  }

#pragma unroll
  for (int mi = 0; mi < 4; mi++) {
#pragma unroll
    for (int i = 0; i < 4; i++) {
      int gr = m0 + wm * 64 + mi * 16 + lg * 4 + i;
      long rowoff = (long)gr * ldc;
#pragma unroll
      for (int ni = 0; ni < 4; ni++) {
        int gc = n0 + wn * 64 + ni * 16 + lr;
        if (gc < Nreal) {
          float v = acc[mi][ni][i];
          if (bias) v += bias[gc];
          if (pe) v += pe[((gr & (cL - 1)) << 9) + gc];
          if (m0b && gc == 0) v += 1024.f * m0b[gr];
          if (Ad) v += Ad[rowoff + gc];
          if (Adb) v += bf2f((unsigned short)Adb[rowoff + gc]);
          if (relu) v = fmaxf(v, 0.f);
          if (Cf) Cf[rowoff + gc] = v;
          if (Cb) Cb[rowoff + gc] = (short)f2bf(v);
        }
      }
    }
  }
}

} // namespace

extern "C" void kernel_launch(void* const* d_in, const int* in_sizes, int n_in, void* d_out,
                              int out_size, void* d_ws, size_t ws_size, hipStream_t stream) {
  const float* x_enc = (const float*)d_in[0];
  const float* tok_W = (const float*)d_in[1];
  const float* enc_Wq = (const float*)d_in[2];
  const float* enc_Wo = (const float*)d_in[5];
  const float* enc_bq = (const float*)d_in[6];
  const float* enc_bo = (const float*)d_in[9];
  const float* dsWq = (const float*)d_in[10];
  const float* dsWo = (const float*)d_in[13];
  const float* dsbq = (const float*)d_in[14];
  const float* dsbo = (const float*)d_in[17];
  const float* dcWq = (const float*)d_in[18];
  const float* dcWk = (const float*)d_in[19];
  const float* dcWo = (const float*)d_in[21];
  const float* dcbq = (const float*)d_in[22];
  const float* dcbk = (const float*)d_in[23];
  const float* dcbo = (const float*)d_in[25];
  const float* enc_c1W = (const float*)d_in[26];
  const float* enc_c1b = (const float*)d_in[27];
  const float* enc_c2W = (const float*)d_in[28];
  const float* enc_c2b = (const float*)d_in[29];
  const float* dec_c1W = (const float*)d_in[30];
  const float* dec_c1b = (const float*)d_in[31];
  const float* dec_c2W = (const float*)d_in[32];
  const float* dec_c2b = (const float*)d_in[33];
  const float* dec_trW = (const float*)d_in[34];
  const float* fb_enc = (const float*)d_in[35];
  const float* fb_dec = (const float*)d_in[36];
  const float* fc_w = (const float*)d_in[37];
  const float* p1W = (const float*)d_in[38];
  const float* p1b = (const float*)d_in[39];
  const float* p2W = (const float*)d_in[40];
  const float* p2b = (const float*)d_in[41];
  const float* p3W = (const float*)d_in[42];
  const float* p3b = (const float*)d_in[43];

  constexpr long MIXW = 8L * 64 * 64 * 64 * 2;

  // ---- layout sizing (dry-run) ----
  auto layout_bytes = [&](long BG, long RH) -> size_t {
    size_t t = 0;
    auto add = [&](size_t b) { t = (t + b + 255) & ~(size_t)255; };
    add(2 * 262144 * 2); add(2 * 262144 * 2);
    add(262144 * 2); add(262144 * 2); add(262144 * 2); add(262144 * 2); add(262144 * 2);
    add(2 * 1048576 * 2); add(2 * 1048576 * 2); add(1048576 * 2); add(1048576 * 2);
    add(131072 * 2); add(131072 * 2); add(65536 * 2); add(196608 * 2); add(65536 * 2);
    add(128 * 4); add(524288 * 4);
    add(MIXW * 2); add(MIXW * 2); add(MIXW * 2);
    long GA = BG * cL * cDM;
    add(GA * 4); add(GA * 4);                                  // A E (f32)
    add(GA * 2); add(GA * 2); add(GA * 2); add(GA * 2);        // Eb Xb Ab Sb
    add(BG * cL * 128 * 2);
    size_t ub = (size_t)GA * 2;
    size_t hd = (size_t)RH * cDFF * 2;
    add(ub > hd ? ub : hd);
    add(BG * 65536 * 4); add(BG * 65536 * 4);
    add(BG * 65536 * 2); add(BG * 65536 * 2); add(BG * 65536 * 2); add(BG * 65536 * 2);
    add(BG * cL * cCIN * 4); add(BG * cL * cCIN * 4); add(BG * cL * cCIN * 4);
    return t;
  };
  int BG = cB;
  while (BG > 1 && layout_bytes(BG, 512) > ws_size) BG >>= 1;
  long RH = (long)BG * cL;
  while (RH > 512 && layout_bytes(BG, RH) > ws_size) RH >>= 1;

  long GBL = (long)BG * cL;
  char* base = (char*)d_ws;
  size_t off = 0;
  auto alloc = [&](size_t bytes) -> void* {
    void* p = base + off;
    off = (off + bytes + 255) & ~(size_t)255;
    return p;
  };
  short* WqbE = (short*)alloc(2 * 262144 * 2);
  short* WobE = (short*)alloc(2 * 262144 * 2);
  short* dsWqb = (short*)alloc(262144 * 2);
  short* dsWob = (short*)alloc(262144 * 2);
  short* dcWqb = (short*)alloc(262144 * 2);
  short* dcWkb = (short*)alloc(262144 * 2);
  short* dcWob = (short*)alloc(262144 * 2);
  short* c1bE = (short*)alloc(2 * 1048576 * 2);
  short* c2bE = (short*)alloc(2 * 1048576 * 2);
  short* c1bD = (short*)alloc(1048576 * 2);
  short* c2bD = (short*)alloc(1048576 * 2);
  short* basisdb = (short*)alloc(131072 * 2);
  short* basisib = (short*)alloc(131072 * 2);
  short* Bpadb = (short*)alloc(65536 * 2);
  short* Wtr3b = (short*)alloc(196608 * 2);
  short* p3padb = (short*)alloc(65536 * 2);
  float* p3bpadf = (float*)alloc(128 * 4);
  float* pe = (float*)alloc(524288 * 4);
  short* fbEb = (short*)alloc(MIXW * 2);
  short* fbDb = (short*)alloc(MIXW * 2);
  short* fcwb = (short*)alloc(MIXW * 2);
  long GA = GBL * cDM;
  float* A = (float*)alloc(GA * 4);
  float* E = (float*)alloc(GA * 4);
  short* Eb = (short*)alloc(GA * 2);
  short* Xb = (short*)alloc(GA * 2);
  short* Ab = (short*)alloc(GA * 2);
  short* Sb = (short*)alloc(GA * 2);
  short* winb = (short*)alloc(GBL * 128 * 2);
  size_t ubsz = (size_t)GA * 2;
  size_t hdsz = (size_t)RH * cDFF * 2;
  short* UB = (short*)alloc(ubsz > hdsz ? ubsz : hdsz); // Tb / HDb (disjoint in time)
  short* Tb = UB;
  short* HDb = UB;
  float* Fq = (float*)alloc((size_t)BG * 65536 * 4);
  float* Fk = (float*)alloc((size_t)BG * 65536 * 4);
  short* FEb = (short*)alloc((size_t)BG * 65536 * 2);
  short* FXb = (short*)alloc((size_t)BG * 65536 * 2);
  short* Gtb = (short*)alloc((size_t)BG * 65536 * 2);
  short* Hb = (short*)alloc((size_t)BG * 65536 * 2);
  float* TRD = (float*)alloc(GBL * cCIN * 4);
  float* O1 = (float*)alloc(GBL * cCIN * 4);
  float* O2 = (float*)alloc(GBL * cCIN * 4);

  auto mg = [&](const short* Am, const short* Bm, const float* bias, const float* add,
                const short* adb, const float* peA, const float* m0b, float* Cf, short* Cb,
                int Mm, int Nn, int Kk, int lda, long sA, long sB, long sC, int batch, int relu,
                int Nreal, int ldc, int amode) {
    dim3 g(Nn / 128, Mm / 128, batch);
    mfma_gemm_bf<<<g, 256, 0, stream>>>(Am, Bm, bias, add, adb, peA, m0b, Cf, Cb, Mm, Nn, Kk,
                                        lda, sA, sB, sC, relu, Nreal, ldc, amode, nullptr,
                                        nullptr, nullptr, nullptr, 0);
  };
  auto cvt = [&](const float* in, short* out, long n) {
    int g = (int)((n + 255) / 256);
    if (g > 4096) g = 4096;
    cvt_kernel<<<g, 256, 0, stream>>>(in, out, (int)n);
  };
  auto decomp = [&](const float* x, short* sb, float* maf, short* mab, int maacc, long total,
                    int C_) {
    int n8 = (int)(total / 8);
    decomp_kernel<<<(n8 + 255) / 256, 256, 0, stream>>>(x, sb, maf, mab, maacc, n8, C_);
  };
  auto dft = [&](const short* srcb, short* Fout) {
    transpose_bf<<<dim3(16, 32, BG), 256, 0, stream>>>(srcb, Tb);
    mg(basisdb, Tb, nullptr, nullptr, nullptr, nullptr, nullptr, nullptr, Fout, M2, cDM, cL, cL,
       0, (long)cDM * cL, 65536, BG, 0, cDM, cDM, 0);
  };
  auto modeproj = [&](const short* Wb, const short* Fin, const float* m0b, float* Cf, short* Cb) {
    mg(Wb, Fin, nullptr, nullptr, nullptr, nullptr, m0b, Cf, Cb, cDM, M2, cDM, cDM, 0, 65536,
       65536, BG, 0, M2, M2, 0);
  };
  auto modeproj2 = [&](const short* Wa, const short* Fa, const float* ba, float* Ca,
                       const short* Wb2, const short* Fb2, const float* bb2, float* Cb2) {
    dim3 g(1, cDM / 128, 2 * BG);
    mfma_gemm_bf<<<g, 256, 0, stream>>>(Wa, Fa, nullptr, nullptr, nullptr, nullptr, ba, Ca,
                                        nullptr, cDM, M2, cDM, cDM, 0, 65536, 65536, 0, M2, M2,
                                        0, Wb2, Fb2, bb2, Cb2, BG);
  };
  auto idft = [&](const short* Hin, const float* bias, const short* adb, float* Cf) {
    mg(basisib, Hin, bias, nullptr, adb, nullptr, nullptr, Cf, nullptr, cL, cDM, M2, M2, 0,
       65536, (long)cL * cDM, BG, 0, cDM, cDM, 0);
  };
  auto ffn = [&](const short* inb, const short* addb, float* outf, const short* c1w,
                 const float* c1bias, const short* c2w, const float* c2bias) {
    for (long r = 0; r < GBL; r += RH) {
      mg(inb + r * cDM, c1w, c1bias, nullptr, nullptr, nullptr, nullptr, nullptr, HDb, (int)RH,
         cDFF, cDM, cDM, 0, 0, 0, 1, 1, cDFF, cDFF, 0);
      mg(HDb, c2w, c2bias, nullptr, addb + r * cDM, nullptr, nullptr, outf + r * cDM, nullptr,
         (int)RH, cDM, cDFF, cDFF, 0, 0, 0, 1, 0, cDM, cDM, 0);
    }
  };
  auto trendg = [&](const short* mab) {
    mg(mab, Wtr3b, nullptr, TRD, nullptr, nullptr, nullptr, TRD, nullptr, (int)GBL, 128, 1536,
       512, 0, 0, 0, 1, 0, cCIN, cCIN, 1);
  };
  auto mixt = [&](const float* F, const short* W, float scale) {
    modemix_t_kernel<<<dim3(BG, cH), 256, 0, stream>>>(F, (const unsigned short*)W, Gtb, scale);
  };

  // ---- one-time setup ----
  basis_kernel<<<(M2 * cL) / 256, 256, 0, stream>>>(basisdb, basisib);
  pe_kernel<<<(cL * cDM) / 256, 256, 0, stream>>>(pe);
  prep_kernel<<<768, 256, 0, stream>>>(tok_W, dec_trW, p3W, p3b, Bpadb, Wtr3b, p3padb, p3bpadf);
  cvt(enc_Wq, WqbE, 524288);
  cvt(enc_Wo, WobE, 524288);
  cvt(dsWq, dsWqb, 262144);
  cvt(dsWo, dsWob, 262144);
  cvt(dcWq, dcWqb, 262144);
  cvt(dcWk, dcWkb, 262144);
  cvt(dcWo, dcWob, 262144);
  cvt(enc_c1W, c1bE, 2097152);
  cvt(enc_c2W, c2bE, 2097152);
  cvt(dec_c1W, c1bD, 1048576);
  cvt(dec_c2W, c2bD, 1048576);
  cvt(fb_enc, fbEb, MIXW);
  cvt(fb_dec, fbDb, MIXW);
  cvt(fc_w, fcwb, MIXW);

  for (int b0 = 0; b0 < cB; b0 += BG) {
    const float* xg = x_enc + (long)b0 * cL * cCIN;

    decomp(xg, nullptr, TRD, nullptr, 0, GBL * cCIN, cCIN); // trend_init -> TRD (f32)
    winbuild_kernel<<<(int)(GBL * 32 / 256), 256, 0, stream>>>(xg, winb);
    mg(winb, Bpadb, nullptr, nullptr, nullptr, pe, nullptr, nullptr, Eb, (int)GBL, cDM, 128, 128,
       0, 0, 0, 1, 0, cDM, cDM, 0); // embedding -> Eb only

    // ---- encoder ----
    for (int l = 0; l < 2; l++) {
      dft(Eb, FEb);
      modeproj(WqbE + (long)l * 262144, FEb, enc_bq + l * cDM, Fq, nullptr);
      mixt(Fq, fbEb, 1.0f);
      modeproj(WobE + (long)l * 262144, Gtb, nullptr, nullptr, Hb);
      idft(Hb, enc_bo + l * cDM, Eb, A);                      // x + attn -> A (f32)
      decomp(A, Xb, nullptr, nullptr, 0, GA, cDM);            // h -> Xb (bf16 only)
      ffn(Xb, Xb, A, c1bE + (long)l * 1048576, enc_c1b + l * cDFF, c2bE + (long)l * 1048576,
          enc_c2b + l * cDM);                                 // h + y -> A (f32)
      decomp(A, Eb, nullptr, nullptr, 0, GA, cDM);            // stream -> Eb
    }

    // ---- decoder ----
    dft(Eb, FEb);
    modeproj(dsWqb, FEb, dsbq, Fq, nullptr);
    mixt(Fq, fbDb, 1.0f);
    modeproj(dsWob, Gtb, nullptr, nullptr, Hb);
    idft(Hb, dsbo, Eb, A);                                    // x1 -> A
    decomp(A, Xb, nullptr, Sb, 0, GA, cDM);                   // x2 -> Xb; ma -> Sb (fresh)
    dft(Xb, FXb);
    modeproj2(dcWqb, FXb, dcbq, Fq, dcWkb, FEb, dcbk, Fk);
    fused_cross_kernel<<<dim3(BG, cH), 256, 0, stream>>>(Fq, Fk, (const unsigned short*)fcwb,
                                                         Gtb, 1.0f / (float)(cDM * cDM));
    modeproj(dcWob, Gtb, nullptr, nullptr, Hb);
    idft(Hb, dcbo, Xb, E);                                    // x3 -> E
    decomp(E, Ab, nullptr, Sb, 1, GA, cDM);                   // x4 -> Ab; ma += Sb
    ffn(Ab, Ab, E, c1bD, dec_c1b, c2bD, dec_c2b);             // x4 + y -> E
    decomp(E, Xb, nullptr, Sb, 1, GA, cDM);                   // x5 -> Xb; ma += Sb
    trendg(Sb);                                               // conv(t1+t2+t3)

    // ---- final projections ----
    mg(Xb, p3padb, p3bpadf, TRD, nullptr, nullptr, nullptr, O1, nullptr, (int)GBL, 128, cDM, cDM,
       0, 0, 0, 1, 0, cCIN, cCIN, 0);                         // trend + x@p3
    gemm_kernel<<<dim3(1, (int)(GBL / 128)), 256, 0, stream>>>(O1, p1W, p1b, O2, (int)GBL, cCIN,
                                                               cCIN);
    p2_kernel<<<dim3(BG, 32), 256, 0, stream>>>(O2, p2W, p2b,
                                                (float*)d_out + (long)b0 * cPRED * cCIN);
  }
}

// Round 14
// 2484.138 us; speedup vs baseline: 1.7325x; 1.3299x over previous
//
#include <hip/hip_runtime.h>
#include <math.h>

namespace {

constexpr int cB = 32, cL = 1024, cCIN = 32, cDM = 512, cDFF = 2048;
constexpr int cH = 8, cE = 64, cM = 64, cPRED = 256;
constexpr int M2 = 2 * cM; // 128

typedef __attribute__((ext_vector_type(8))) short short8v;
typedef __attribute__((ext_vector_type(4))) float float4v;

__device__ inline unsigned short f2bf(float f) {
  unsigned int u = __builtin_bit_cast(unsigned int, f);
  u += 0x7FFFu + ((u >> 16) & 1u); // RNE
  return (unsigned short)(u >> 16);
}
__device__ inline float bf2f(unsigned short s) {
  return __builtin_bit_cast(float, (unsigned int)s << 16);
}

typedef const __attribute__((address_space(1))) unsigned int gu32_t;
typedef __attribute__((address_space(3))) unsigned int lu32_t;
__device__ inline void gld16(const void* g, void* l) {
  __builtin_amdgcn_global_load_lds((gu32_t*)g, (lu32_t*)l, 16, 0, 0);
}

// ================= one-time tables =================
__global__ void basis_kernel(short* __restrict__ basisdb, short* __restrict__ basisib) {
  int idx = blockIdx.x * 256 + threadIdx.x;
  if (idx >= M2 * cL) return;
  int t = idx & (cL - 1);
  int m2 = idx >> 10;
  int m = m2 >> 1;
  float ang = 6.2831853071795864f * (float)((m * t) & (cL - 1)) / (float)cL;
  float cv = cosf(ang), sv = sinf(ang);
  float vd = (m2 & 1) ? -sv : cv;
  basisdb[idx] = (short)f2bf(vd);
  float s = (m == 0) ? ((m2 & 1) ? 0.f : (1.f / (float)cL)) : (2.f / (float)cL);
  basisib[t * M2 + m2] = (short)f2bf(vd * s);
}

__global__ void pe_kernel(float* __restrict__ pe) {
  int idx = blockIdx.x * 256 + threadIdx.x;
  int o = idx & (cDM - 1), t = idx >> 9;
  int i = o >> 1;
  float freq = __expf((float)(2 * i) * (-9.210340371976184f / (float)cDM));
  float ang = freq * (float)t;
  pe[idx] = (o & 1) ? cosf(ang) : sinf(ang);
}

constexpr int NJOB = 14;
struct CvtArgs {
  const float* src[NJOB];
  short* dst[NJOB];
  int n[NJOB];
};
__global__ void cvtm_kernel(CvtArgs a) {
  int j = blockIdx.y;
  const float* s = a.src[j];
  short* d = a.dst[j];
  int n = a.n[j];
  for (int i = blockIdx.x * 256 + threadIdx.x; i < n; i += gridDim.x * 256)
    d[i] = (short)f2bf(s[i]);
}

// Bpadb[o][j*32+c]=tok_W[o][c][j]; Wtr3b[o][j*512+c]=trW[o][c][j] (o<32); p3padb; p3bpadf
__global__ void prep_kernel(const float* __restrict__ tok_W, const float* __restrict__ trW,
                            const float* __restrict__ p3W, const float* __restrict__ p3b,
                            short* __restrict__ Bpadb, short* __restrict__ Wtr3b,
                            short* __restrict__ p3padb, float* __restrict__ p3bpadf) {
  int idx = blockIdx.x * 256 + threadIdx.x;
  if (idx < 512 * 128) {
    int o = idx >> 7, s = idx & 127, j = s >> 5, c = s & 31;
    Bpadb[idx] = (j < 3) ? (short)f2bf(tok_W[o * 96 + c * 3 + j]) : (short)0;
  }
  if (idx < 128 * 1536) {
    int o = idx / 1536, r = idx % 1536, j = r >> 9, c = r & 511;
    Wtr3b[idx] = (o < 32) ? (short)f2bf(trW[(long)o * 1536 + c * 3 + j]) : (short)0;
  }
  if (idx < 128 * 512) {
    int o = idx >> 9, k = idx & 511;
    p3padb[idx] = (o < 32) ? (short)f2bf(p3W[o * 512 + k]) : (short)0;
  }
  if (idx < 128) p3bpadf[idx] = (idx < 32) ? p3b[idx] : 0.f;
}

// win[row][128] bf16 = [x[t-1,:], x[t,:], x[t+1,:], 0] circular
__global__ void winbuild_kernel(const float* __restrict__ x, short* __restrict__ win) {
  int idx = blockIdx.x * 256 + threadIdx.x;
  int s4 = idx & 31;
  int row = idx >> 5;
  int t = row & (cL - 1), b = row >> 10;
  int j = s4 >> 3, c4 = s4 & 7;
  unsigned int lo = 0, hi = 0;
  if (j < 3) {
    int ts = (t + j + cL - 1) & (cL - 1);
    float4 v = *(const float4*)&x[((long)b * cL + ts) * cCIN + c4 * 4];
    lo = (unsigned int)f2bf(v.x) | ((unsigned int)f2bf(v.y) << 16);
    hi = (unsigned int)f2bf(v.z) | ((unsigned int)f2bf(v.w) << 16);
  }
  *(uint2*)&win[row * 128 + s4 * 4] = make_uint2(lo, hi);
}

// batched bf16 transpose: in [B][1024][512] -> out [B][512][1024]
__global__ __launch_bounds__(256) void transpose_bf(const short* __restrict__ in,
                                                    short* __restrict__ out) {
  __shared__ short tile[32][33];
  int b = blockIdx.z;
  in += (long)b * cL * cDM;
  out += (long)b * cL * cDM;
  int c0 = blockIdx.x * 32, t0 = blockIdx.y * 32;
  int tx = threadIdx.x & 31, ty = threadIdx.x >> 5;
#pragma unroll
  for (int r = 0; r < 32; r += 8) tile[ty + r][tx] = in[(long)(t0 + ty + r) * cDM + c0 + tx];
  __syncthreads();
#pragma unroll
  for (int r = 0; r < 32; r += 8)
    out[(long)(c0 + ty + r) * cL + t0 + tx] = tile[tx][ty + r];
}

// ==== f32-input decomp (trend-init only): ma -> maf ====
__global__ void decomp_kernel(const float* __restrict__ x, float* __restrict__ maf, int n8,
                              int C) {
  int idx = blockIdx.x * 256 + threadIdx.x;
  if (idx >= n8) return;
  int c = idx % C;
  int u = idx / C;
  int t0 = (u & 127) * 8;
  int b = u >> 7;
  long base = (long)b * cL * C + c;
  float s = 0.f;
#pragma unroll
  for (int j = -12; j <= 12; j++) {
    int tt = t0 + j;
    tt = tt < 0 ? 0 : (tt >= cL ? cL - 1 : tt);
    s += x[base + (long)tt * C];
  }
#pragma unroll
  for (int k = 0; k < 8; k++) {
    int t = t0 + k;
    maf[base + (long)t * C] = s * (1.0f / 25.0f);
    int ta = t + 13;
    ta = ta >= cL ? cL - 1 : ta;
    int td = t - 12;
    td = td < 0 ? 0 : td;
    s += x[base + (long)ta * C] - x[base + (long)td * C];
  }
}

// ==== bf16-input decomp: seasonal bf16 + optional accumulated ma bf16 ====
__global__ void decompb_kernel(const short* __restrict__ x, short* __restrict__ sb,
                               short* __restrict__ mab, int maacc, int n8, int C) {
  int idx = blockIdx.x * 256 + threadIdx.x;
  if (idx >= n8) return;
  int c = idx % C;
  int u = idx / C;
  int t0 = (u & 127) * 8;
  int b = u >> 7;
  long base = (long)b * cL * C + c;
  float s = 0.f;
#pragma unroll
  for (int j = -12; j <= 12; j++) {
    int tt = t0 + j;
    tt = tt < 0 ? 0 : (tt >= cL ? cL - 1 : tt);
    s += bf2f((unsigned short)x[base + (long)tt * C]);
  }
#pragma unroll
  for (int k = 0; k < 8; k++) {
    int t = t0 + k;
    long e = base + (long)t * C;
    float ma = s * (1.0f / 25.0f);
    if (sb) sb[e] = (short)f2bf(bf2f((unsigned short)x[e]) - ma);
    if (mab) {
      float v = maacc ? bf2f((unsigned short)mab[e]) + ma : ma;
      mab[e] = (short)f2bf(v);
    }
    int ta = t + 13;
    ta = ta >= cL ? cL - 1 : ta;
    int td = t - 12;
    td = td < 0 ? 0 : td;
    s += bf2f((unsigned short)x[base + (long)ta * C]) - bf2f((unsigned short)x[base + (long)td * C]);
  }
}

// ================= final time projection =================
__global__ __launch_bounds__(256) void p2_kernel(const float* __restrict__ x,
                                                 const float* __restrict__ W,
                                                 const float* __restrict__ bias,
                                                 float* __restrict__ out) {
  __shared__ float tile[256 * 32];
  int b = blockIdx.x;
  int p0 = blockIdx.y * 8;
  int c = threadIdx.x & 31, pl = threadIdx.x >> 5;
  const float* xb = x + (long)b * cL * cCIN;
  const float* w = W + (long)(p0 + pl) * cL;
  float s = 0.f;
  for (int l0 = 0; l0 < cL; l0 += 256) {
    __syncthreads();
    for (int i = threadIdx.x; i < 256 * 32; i += 256) tile[i] = xb[(long)l0 * 32 + i];
    __syncthreads();
#pragma unroll 8
    for (int l = 0; l < 256; l++) s += tile[l * 32 + c] * w[l0 + l];
  }
  out[((long)b * cPRED + p0 + pl) * cCIN + c] = s + bias[p0 + pl];
}

// ====== per-(h,mode) complex mode mix; W bf16; transposed bf16 out ======
__global__ __launch_bounds__(256) void modemix_t_kernel(const float* __restrict__ F,
                                                        const unsigned short* __restrict__ W,
                                                        short* __restrict__ Gt, float scale) {
  int b = blockIdx.x, h = blockIdx.y;
  __shared__ float2 Fs[cE][cM];
  __shared__ short ot[128][72];
  const float* Fb = F + ((long)b * cDM + h * cE) * M2;
  for (int i = threadIdx.x; i < cE * cM; i += 256) {
    int e = i >> 6, x = i & 63;
    Fs[e][x] = ((const float2*)(Fb + (long)e * M2))[x];
  }
  __syncthreads();
  int x = threadIdx.x & 63, og = threadIdx.x >> 6;
  float2 acc[16];
#pragma unroll
  for (int i = 0; i < 16; i++) acc[i] = make_float2(0.f, 0.f);
  for (int e = 0; e < cE; e++) {
    float2 f = Fs[e][x];
#pragma unroll
    for (int i = 0; i < 16; i++) {
      int o = og * 16 + i;
      unsigned int wu = *(const unsigned int*)&W[((((long)h * cE + e) * cE + o) * cM + x) * 2];
      float wx = bf2f((unsigned short)wu), wy = bf2f((unsigned short)(wu >> 16));
      acc[i].x += f.x * wx - f.y * wy;
      acc[i].y += f.x * wy + f.y * wx;
    }
  }
#pragma unroll
  for (int i = 0; i < 16; i++) {
    int o = og * 16 + i;
    ot[2 * x][o] = (short)f2bf(acc[i].x * scale);
    ot[2 * x + 1][o] = (short)f2bf(acc[i].y * scale);
  }
  __syncthreads();
  short* gb = Gt + (long)b * (M2 * cDM) + h * cE;
  for (int u = threadIdx.x; u < 1024; u += 256) {
    int row = u >> 3, seg = u & 7;
    *(uint4*)&gb[(long)row * cDM + seg * 8] = *(const uint4*)&ot[row][seg * 8];
  }
}

// ====== fused cross attention (W bf16, conflict-free LDS layouts) ======
__global__ __launch_bounds__(256) void fused_cross_kernel(const float* __restrict__ Fq,
                                                          const float* __restrict__ Fk,
                                                          const unsigned short* __restrict__ W,
                                                          short* __restrict__ Gt, float scale) {
  __shared__ __align__(16) char smem[65536];
  float2(*KsT)[cE] = (float2(*)[cE])smem;            // [y][e]
  float2(*qks)[cM] = (float2(*)[cM])(smem + 32768);  // [y][x]
  int b = blockIdx.x, h = blockIdx.y;
  const float* kb = Fk + ((long)b * cDM + h * cE) * M2;
  for (int i = threadIdx.x; i < cE * cM; i += 256) {
    int e = i >> 6, y = i & 63;
    KsT[y][e] = ((const float2*)(kb + (long)e * M2))[y];
  }
  __syncthreads();
  {
    int x = threadIdx.x & 63, yg = threadIdx.x >> 6;
    const float* qb = Fq + ((long)b * cDM + h * cE) * M2;
    float2 acc[16];
#pragma unroll
    for (int i = 0; i < 16; i++) acc[i] = make_float2(0.f, 0.f);
    for (int e = 0; e < cE; e++) {
      float2 q = ((const float2*)(qb + (long)e * M2))[x];
#pragma unroll
      for (int i = 0; i < 16; i++) {
        float2 k = KsT[yg * 16 + i][e];
        acc[i].x += q.x * k.x - q.y * k.y;
        acc[i].y += q.x * k.y + q.y * k.x;
      }
    }
#pragma unroll
    for (int i = 0; i < 16; i++) {
      int y = yg * 16 + i;
      float a = acc[i].x, bi = acc[i].y;
      float re, im;
      float t2a = 2.f * a;
      if (fabsf(t2a) > 60.f) {
        re = t2a > 0.f ? 1.f : -1.f;
        im = 0.f;
      } else {
        float denom = coshf(t2a) + cosf(2.f * bi);
        re = sinhf(t2a) / denom;
        im = sinf(2.f * bi) / denom;
      }
      qks[y][x] = make_float2(re, im);
    }
  }
  __syncthreads();
  int e = threadIdx.x & 63, xg = threadIdx.x >> 6;
  float2 a2[16];
#pragma unroll
  for (int i = 0; i < 16; i++) a2[i] = make_float2(0.f, 0.f);
  for (int y = 0; y < cM; y++) {
    float2 k = KsT[y][e];
#pragma unroll
    for (int i = 0; i < 16; i++) {
      float2 qk = qks[y][xg * 16 + i];
      a2[i].x += qk.x * k.x - qk.y * k.y;
      a2[i].y += qk.x * k.y + qk.y * k.x;
    }
  }
  __syncthreads();
  float2(*Qv)[cM] = (float2(*)[cM])smem;
#pragma unroll
  for (int i = 0; i < 16; i++) Qv[e][xg * 16 + i] = a2[i];
  __syncthreads();
  {
    int x = threadIdx.x & 63, og = threadIdx.x >> 6;
    float2 m[16];
#pragma unroll
    for (int i = 0; i < 16; i++) m[i] = make_float2(0.f, 0.f);
    for (int ee = 0; ee < cE; ee++) {
      float2 f = Qv[ee][x];
#pragma unroll
      for (int i = 0; i < 16; i++) {
        int o = og * 16 + i;
        unsigned int wu = *(const unsigned int*)&W[((((long)h * cE + ee) * cE + o) * cM + x) * 2];
        float wx = bf2f((unsigned short)wu), wy = bf2f((unsigned short)(wu >> 16));
        m[i].x += f.x * wx - f.y * wy;
        m[i].y += f.x * wy + f.y * wx;
      }
    }
    short(*ot)[72] = (short(*)[72])(smem + 32768);
#pragma unroll
    for (int i = 0; i < 16; i++) {
      int o = og * 16 + i;
      ot[2 * x][o] = (short)f2bf(m[i].x * scale);
      ot[2 * x + 1][o] = (short)f2bf(m[i].y * scale);
    }
    __syncthreads();
    short* gb = Gt + (long)b * (M2 * cDM) + h * cE;
    for (int u = threadIdx.x; u < 1024; u += 256) {
      int row = u >> 3, seg = u & 7;
      *(uint4*)&gb[(long)row * cDM + seg * 8] =
          *(const uint4*)&((short(*)[72])(smem + 32768))[row][seg * 8];
    }
  }
}

// ================= f32 shader GEMM (tiny p1 only) =================
constexpr int GBM = 128, GBN = 128, GBK = 16, LPAD = 132;

__global__ __launch_bounds__(256) void gemm_kernel(const float* __restrict__ A,
                                                   const float* __restrict__ B,
                                                   const float* __restrict__ bias,
                                                   float* __restrict__ C, int M, int N, int K) {
  __shared__ float As[GBK][LPAD];
  __shared__ float Bs[GBK][LPAD];
  int n0 = blockIdx.x * GBN, m0 = blockIdx.y * GBM;
  int tid = threadIdx.x;
  int tx = tid & 15, ty = tid >> 4;
  float acc[8][8];
#pragma unroll
  for (int i = 0; i < 8; i++)
#pragma unroll
    for (int j = 0; j < 8; j++) acc[i][j] = 0.f;

  for (int k0 = 0; k0 < K; k0 += GBK) {
#pragma unroll
    for (int p = 0; p < 8; p++) {
      int i = p * 256 + tid;
      int mm = i >> 4, kk = i & 15;
      int gm = m0 + mm;
      As[kk][mm] = (gm < M && k0 + kk < K) ? A[(long)gm * K + k0 + kk] : 0.f;
    }
#pragma unroll
    for (int p = 0; p < 8; p++) {
      int i = p * 256 + tid;
      int nn = i >> 4, kk = i & 15;
      int gn = n0 + nn;
      Bs[kk][nn] = (gn < N && k0 + kk < K) ? B[(long)gn * K + k0 + kk] : 0.f;
    }
    __syncthreads();
#pragma unroll
    for (int kk = 0; kk < GBK; kk++) {
      float a[8], bb[8];
      *(float4*)&a[0] = *(const float4*)&As[kk][ty * 8];
      *(float4*)&a[4] = *(const float4*)&As[kk][ty * 8 + 4];
      *(float4*)&bb[0] = *(const float4*)&Bs[kk][tx * 8];
      *(float4*)&bb[4] = *(const float4*)&Bs[kk][tx * 8 + 4];
#pragma unroll
      for (int i = 0; i < 8; i++)
#pragma unroll
        for (int j = 0; j < 8; j++) acc[i][j] += a[i] * bb[j];
    }
    __syncthreads();
  }

  for (int i = 0; i < 8; i++) {
    int gm = m0 + ty * 8 + i;
    if (gm >= M) break;
    long rowoff = (long)gm * N;
    for (int j = 0; j < 8; j++) {
      int gn = n0 + tx * 8 + j;
      if (gn < N) C[rowoff + gn] = acc[i][j] + (bias ? bias[gn] : 0.f);
    }
  }
}

// ===== bf16 MFMA GEMM 128x128 (m97 single-buffer, swizzled, XCD-chunked) =====
__global__ __launch_bounds__(256) void mfma_gemm_bf(
    const short* __restrict__ A, const short* __restrict__ B, const float* __restrict__ bias,
    const float* __restrict__ addend, const short* __restrict__ addendb,
    const float* __restrict__ pe, const float* __restrict__ m0b, float* __restrict__ Cf,
    short* __restrict__ Cb, int M, int N, int K, int lda, long sA, long sB, long sC, int relu,
    int Nreal, int ldc, int amode) {
  __shared__ __align__(16) short As[8192];
  __shared__ __align__(16) short Bs[8192];
  int nwg = gridDim.x * gridDim.y * gridDim.z;
  int orig = blockIdx.x + gridDim.x * (blockIdx.y + gridDim.y * blockIdx.z);
  int q = nwg >> 3, r = nwg & 7;
  int xcd = orig & 7, ii = orig >> 3;
  int flat = (xcd < r ? xcd * (q + 1) : r * (q + 1) + (xcd - r) * q) + ii;
  int bx = flat % (int)gridDim.x;
  int tmp = flat / (int)gridDim.x;
  int by = tmp % (int)gridDim.y;
  int bz = tmp / (int)gridDim.y;

  int z = bz;
  A += (long)z * sA;
  B += (long)z * sB;
  if (Cf) Cf += (long)z * sC;
  if (Cb) Cb += (long)z * sC;
  const float* Ad = addend ? addend + (long)z * sC : nullptr;
  const short* Adb = addendb ? addendb + (long)z * sC : nullptr;
  int n0 = bx * 128, m0 = by * 128;
  int tid = threadIdx.x;
  int lane = tid & 63;
  int w = tid >> 6;
  int wm = w & 1, wn = w >> 1;
  int lr = lane & 15, lg = lane >> 4;
  int lrow = lane >> 3;
  int scol = ((lane & 7) * 8) ^ (lrow << 3);

  float4v acc[4][4];
#pragma unroll
  for (int i = 0; i < 4; i++)
#pragma unroll
    for (int j = 0; j < 4; j++) acc[i][j] = (float4v){0.f, 0.f, 0.f, 0.f};

  auto stage = [&](int k0) {
#pragma unroll
    for (int j = 0; j < 4; j++) {
      int seg = w * 4 + j;
      int row = seg * 8 + lrow;
      const short* ga;
      if (amode == 0) {
        ga = A + (long)(m0 + row) * lda + k0 + scol;
      } else {
        int r2 = m0 + row;
        int bb = r2 >> 10, t = r2 & 1023;
        int jj = k0 >> 9, c0 = k0 & 511;
        ga = A + ((((long)(bb << 10)) | ((t + jj + 1023) & 1023)) << 9) + c0 + scol;
      }
      gld16(ga, &As[seg * 512]);
      const short* gb = B + (long)(n0 + row) * K + k0 + scol;
      gld16(gb, &Bs[seg * 512]);
    }
  };

  int nk = K >> 6;
  int swr = (lr & 7) << 3;
  for (int t = 0; t < nk; ++t) {
    stage(t << 6);
    asm volatile("s_waitcnt vmcnt(0)" ::: "memory");
    __syncthreads();
#pragma unroll
    for (int ks = 0; ks < 2; ks++) {
      short8v af[4], bfr[4];
#pragma unroll
      for (int mi = 0; mi < 4; mi++)
        af[mi] = *(const short8v*)&As[(wm * 64 + mi * 16 + lr) * 64 + ((ks * 32 + lg * 8) ^ swr)];
#pragma unroll
      for (int ni = 0; ni < 4; ni++)
        bfr[ni] = *(const short8v*)&Bs[(wn * 64 + ni * 16 + lr) * 64 + ((ks * 32 + lg * 8) ^ swr)];
#pragma unroll
      for (int mi = 0; mi < 4; mi++)
#pragma unroll
        for (int ni = 0; ni < 4; ni++)
          acc[mi][ni] =
              __builtin_amdgcn_mfma_f32_16x16x32_bf16(af[mi], bfr[ni], acc[mi][ni], 0, 0, 0);
    }
    __syncthreads();
  }

#pragma unroll
  for (int mi = 0; mi < 4; mi++) {
#pragma unroll
    for (int i = 0; i < 4; i++) {
      int gr = m0 + wm * 64 + mi * 16 + lg * 4 + i;
      long rowoff = (long)gr * ldc;
#pragma unroll
      for (int ni = 0; ni < 4; ni++) {
        int gc = n0 + wn * 64 + ni * 16 + lr;
        if (gc < Nreal) {
          float v = acc[mi][ni][i];
          if (bias) v += bias[gc];
          if (pe) v += pe[((gr & (cL - 1)) << 9) + gc];
          if (m0b && gc == 0) v += 1024.f * m0b[gr];
          if (Ad) v += Ad[rowoff + gc];
          if (Adb) v += bf2f((unsigned short)Adb[rowoff + gc]);
          if (relu) v = fmaxf(v, 0.f);
          if (Cf) Cf[rowoff + gc] = v;
          if (Cb) Cb[rowoff + gc] = (short)f2bf(v);
        }
      }
    }
  }
}

// ===== bf16 MFMA GEMM 64x64 (small mode-space shapes; zsplit dual mode) =====
__global__ __launch_bounds__(256) void mfma_gemm64(
    const short* __restrict__ A, const short* __restrict__ B, const float* __restrict__ m0b,
    float* __restrict__ Cf, short* __restrict__ Cb, int M, int N, int K, int lda, long sA,
    long sB, long sC, int ldc, const short* __restrict__ A2, const short* __restrict__ B2,
    const float* __restrict__ m0b2, float* __restrict__ Cf2, int zsplit) {
  __shared__ __align__(16) short As[4096];
  __shared__ __align__(16) short Bs[4096];
  int nwg = gridDim.x * gridDim.y * gridDim.z;
  int orig = blockIdx.x + gridDim.x * (blockIdx.y + gridDim.y * blockIdx.z);
  int q = nwg >> 3, r = nwg & 7;
  int xcd = orig & 7, ii = orig >> 3;
  int flat = (xcd < r ? xcd * (q + 1) : r * (q + 1) + (xcd - r) * q) + ii;
  int bx = flat % (int)gridDim.x;
  int tmp = flat / (int)gridDim.x;
  int by = tmp % (int)gridDim.y;
  int bz = tmp / (int)gridDim.y;

  int z = bz;
  if (zsplit > 0 && bz >= zsplit) {
    A = A2;
    B = B2;
    m0b = m0b2;
    Cf = Cf2;
    z = bz - zsplit;
  }
  A += (long)z * sA;
  B += (long)z * sB;
  if (Cf) Cf += (long)z * sC;
  if (Cb) Cb += (long)z * sC;
  int n0 = bx * 64, m0 = by * 64;
  int tid = threadIdx.x;
  int lane = tid & 63;
  int w = tid >> 6;
  int wm = w & 1, wn = w >> 1;
  int lr = lane & 15, lg = lane >> 4;
  int lrow = lane >> 3;
  int scol = ((lane & 7) * 8) ^ (lrow << 3);

  float4v acc[2][2];
#pragma unroll
  for (int i = 0; i < 2; i++)
#pragma unroll
    for (int j = 0; j < 2; j++) acc[i][j] = (float4v){0.f, 0.f, 0.f, 0.f};

  int nk = K >> 6;
  int swr = (lr & 7) << 3;
  for (int t = 0; t < nk; ++t) {
    int k0 = t << 6;
#pragma unroll
    for (int j = 0; j < 2; j++) {
      int seg = w * 2 + j;
      int row = seg * 8 + lrow;
      gld16(A + (long)(m0 + row) * lda + k0 + scol, &As[seg * 512]);
      gld16(B + (long)(n0 + row) * K + k0 + scol, &Bs[seg * 512]);
    }
    asm volatile("s_waitcnt vmcnt(0)" ::: "memory");
    __syncthreads();
#pragma unroll
    for (int ks = 0; ks < 2; ks++) {
      short8v af[2], bfr[2];
#pragma unroll
      for (int mi = 0; mi < 2; mi++)
        af[mi] = *(const short8v*)&As[(wm * 32 + mi * 16 + lr) * 64 + ((ks * 32 + lg * 8) ^ swr)];
#pragma unroll
      for (int ni = 0; ni < 2; ni++)
        bfr[ni] = *(const short8v*)&Bs[(wn * 32 + ni * 16 + lr) * 64 + ((ks * 32 + lg * 8) ^ swr)];
#pragma unroll
      for (int mi = 0; mi < 2; mi++)
#pragma unroll
        for (int ni = 0; ni < 2; ni++)
          acc[mi][ni] =
              __builtin_amdgcn_mfma_f32_16x16x32_bf16(af[mi], bfr[ni], acc[mi][ni], 0, 0, 0);
    }
    __syncthreads();
  }

#pragma unroll
  for (int mi = 0; mi < 2; mi++) {
#pragma unroll
    for (int i = 0; i < 4; i++) {
      int gr = m0 + wm * 32 + mi * 16 + lg * 4 + i;
      long rowoff = (long)gr * ldc;
#pragma unroll
      for (int ni = 0; ni < 2; ni++) {
        int gc = n0 + wn * 32 + ni * 16 + lr;
        float v = acc[mi][ni][i];
        if (m0b && gc == 0) v += 1024.f * m0b[gr];
        if (Cf) Cf[rowoff + gc] = v;
        if (Cb) Cb[rowoff + gc] = (short)f2bf(v);
      }
    }
  }
}

} // namespace

extern "C" void kernel_launch(void* const* d_in, const int* in_sizes, int n_in, void* d_out,
                              int out_size, void* d_ws, size_t ws_size, hipStream_t stream) {
  const float* x_enc = (const float*)d_in[0];
  const float* tok_W = (const float*)d_in[1];
  const float* enc_Wq = (const float*)d_in[2];
  const float* enc_Wo = (const float*)d_in[5];
  const float* enc_bq = (const float*)d_in[6];
  const float* enc_bo = (const float*)d_in[9];
  const float* dsWq = (const float*)d_in[10];
  const float* dsWo = (const float*)d_in[13];
  const float* dsbq = (const float*)d_in[14];
  const float* dsbo = (const float*)d_in[17];
  const float* dcWq = (const float*)d_in[18];
  const float* dcWk = (const float*)d_in[19];
  const float* dcWo = (const float*)d_in[21];
  const float* dcbq = (const float*)d_in[22];
  const float* dcbk = (const float*)d_in[23];
  const float* dcbo = (const float*)d_in[25];
  const float* enc_c1W = (const float*)d_in[26];
  const float* enc_c1b = (const float*)d_in[27];
  const float* enc_c2W = (const float*)d_in[28];
  const float* enc_c2b = (const float*)d_in[29];
  const float* dec_c1W = (const float*)d_in[30];
  const float* dec_c1b = (const float*)d_in[31];
  const float* dec_c2W = (const float*)d_in[32];
  const float* dec_c2b = (const float*)d_in[33];
  const float* dec_trW = (const float*)d_in[34];
  const float* fb_enc = (const float*)d_in[35];
  const float* fb_dec = (const float*)d_in[36];
  const float* fc_w = (const float*)d_in[37];
  const float* p1W = (const float*)d_in[38];
  const float* p1b = (const float*)d_in[39];
  const float* p2W = (const float*)d_in[40];
  const float* p2b = (const float*)d_in[41];
  const float* p3W = (const float*)d_in[42];
  const float* p3b = (const float*)d_in[43];

  constexpr long MIXW = 8L * 64 * 64 * 64 * 2;

  // ---- layout sizing (dry-run) ----
  auto layout_bytes = [&](long BG, long RH) -> size_t {
    size_t t = 0;
    auto add = [&](size_t b) { t = (t + b + 255) & ~(size_t)255; };
    add(2 * 262144 * 2); add(2 * 262144 * 2);
    add(262144 * 2); add(262144 * 2); add(262144 * 2); add(262144 * 2); add(262144 * 2);
    add(2 * 1048576 * 2); add(2 * 1048576 * 2); add(1048576 * 2); add(1048576 * 2);
    add(131072 * 2); add(131072 * 2); add(65536 * 2); add(196608 * 2); add(65536 * 2);
    add(128 * 4); add(524288 * 4);
    add(MIXW * 2); add(MIXW * 2); add(MIXW * 2);
    long GA = BG * cL * cDM;
    add(GA * 2); add(GA * 2); add(GA * 2); add(GA * 2); add(GA * 2); // Eb Xb Ab Sb Yb
    add(BG * cL * 128 * 2);
    size_t ub = (size_t)GA * 2;
    size_t hd = (size_t)RH * cDFF * 2;
    add(ub > hd ? ub : hd);
    add(BG * 65536 * 4); add(BG * 65536 * 4);
    add(BG * 65536 * 2); add(BG * 65536 * 2); add(BG * 65536 * 2); add(BG * 65536 * 2);
    add(BG * cL * cCIN * 4); add(BG * cL * cCIN * 4); add(BG * cL * cCIN * 4);
    return t;
  };
  int BG = cB;
  while (BG > 1 && layout_bytes(BG, 512) > ws_size) BG >>= 1;
  long RH = (long)BG * cL;
  while (RH > 512 && layout_bytes(BG, RH) > ws_size) RH >>= 1;

  long GBL = (long)BG * cL;
  char* base = (char*)d_ws;
  size_t off = 0;
  auto alloc = [&](size_t bytes) -> void* {
    void* p = base + off;
    off = (off + bytes + 255) & ~(size_t)255;
    return p;
  };
  short* WqbE = (short*)alloc(2 * 262144 * 2);
  short* WobE = (short*)alloc(2 * 262144 * 2);
  short* dsWqb = (short*)alloc(262144 * 2);
  short* dsWob = (short*)alloc(262144 * 2);
  short* dcWqb = (short*)alloc(262144 * 2);
  short* dcWkb = (short*)alloc(262144 * 2);
  short* dcWob = (short*)alloc(262144 * 2);
  short* c1bE = (short*)alloc(2 * 1048576 * 2);
  short* c2bE = (short*)alloc(2 * 1048576 * 2);
  short* c1bD = (short*)alloc(1048576 * 2);
  short* c2bD = (short*)alloc(1048576 * 2);
  short* basisdb = (short*)alloc(131072 * 2);
  short* basisib = (short*)alloc(131072 * 2);
  short* Bpadb = (short*)alloc(65536 * 2);
  short* Wtr3b = (short*)alloc(196608 * 2);
  short* p3padb = (short*)alloc(65536 * 2);
  float* p3bpadf = (float*)alloc(128 * 4);
  float* pe = (float*)alloc(524288 * 4);
  short* fbEb = (short*)alloc(MIXW * 2);
  short* fbDb = (short*)alloc(MIXW * 2);
  short* fcwb = (short*)alloc(MIXW * 2);
  long GA = GBL * cDM;
  short* Eb = (short*)alloc(GA * 2);
  short* Xb = (short*)alloc(GA * 2);
  short* Ab = (short*)alloc(GA * 2);
  short* Sb = (short*)alloc(GA * 2);
  short* Yb = (short*)alloc(GA * 2);
  short* winb = (short*)alloc(GBL * 128 * 2);
  size_t ubsz = (size_t)GA * 2;
  size_t hdsz = (size_t)RH * cDFF * 2;
  short* UB = (short*)alloc(ubsz > hdsz ? ubsz : hdsz);
  short* Tb = UB;
  short* HDb = UB;
  float* Fq = (float*)alloc((size_t)BG * 65536 * 4);
  float* Fk = (float*)alloc((size_t)BG * 65536 * 4);
  short* FEb = (short*)alloc((size_t)BG * 65536 * 2);
  short* FXb = (short*)alloc((size_t)BG * 65536 * 2);
  short* Gtb = (short*)alloc((size_t)BG * 65536 * 2);
  short* Hb = (short*)alloc((size_t)BG * 65536 * 2);
  float* TRD = (float*)alloc(GBL * cCIN * 4);
  float* O1 = (float*)alloc(GBL * cCIN * 4);
  float* O2 = (float*)alloc(GBL * cCIN * 4);

  auto mg = [&](const short* Am, const short* Bm, const float* bias, const float* add,
                const short* adb, const float* peA, const float* m0b, float* Cf, short* Cb,
                int Mm, int Nn, int Kk, int lda, long sA, long sB, long sC, int batch, int relu,
                int Nreal, int ldc, int amode) {
    dim3 g(Nn / 128, Mm / 128, batch);
    mfma_gemm_bf<<<g, 256, 0, stream>>>(Am, Bm, bias, add, adb, peA, m0b, Cf, Cb, Mm, Nn, Kk,
                                        lda, sA, sB, sC, relu, Nreal, ldc, amode);
  };
  auto decompf = [&](const float* x, float* maf, long total, int C_) {
    int n8 = (int)(total / 8);
    decomp_kernel<<<(n8 + 255) / 256, 256, 0, stream>>>(x, maf, n8, C_);
  };
  auto decompb = [&](const short* x, short* sb, short* mab, int maacc, long total, int C_) {
    int n8 = (int)(total / 8);
    decompb_kernel<<<(n8 + 255) / 256, 256, 0, stream>>>(x, sb, mab, maacc, n8, C_);
  };
  // dft: transpose then F[b][m2][dm] bf16 = basisd @ T_b^T  (64-tile: grid 8x2xBG)
  auto dft = [&](const short* srcb, short* Fout) {
    transpose_bf<<<dim3(16, 32, BG), 256, 0, stream>>>(srcb, Tb);
    dim3 g(cDM / 64, M2 / 64, BG);
    mfma_gemm64<<<g, 256, 0, stream>>>(basisdb, Tb, nullptr, nullptr, Fout, M2, cDM, cL, cL, 0,
                                       (long)cDM * cL, 65536, cDM, nullptr, nullptr, nullptr,
                                       nullptr, 0);
  };
  // mode-space projection (64-tile: grid 2x8xBG)
  auto modeproj = [&](const short* Wb, const short* Fin, const float* m0b, float* Cf, short* Cb) {
    dim3 g(M2 / 64, cDM / 64, BG);
    mfma_gemm64<<<g, 256, 0, stream>>>(Wb, Fin, m0b, Cf, Cb, cDM, M2, cDM, cDM, 0, 65536, 65536,
                                       M2, nullptr, nullptr, nullptr, nullptr, 0);
  };
  auto modeproj2 = [&](const short* Wa, const short* Fa, const float* ba, float* Ca,
                       const short* Wb2, const short* Fb2, const float* bb2, float* Cb2) {
    dim3 g(M2 / 64, cDM / 64, 2 * BG);
    mfma_gemm64<<<g, 256, 0, stream>>>(Wa, Fa, ba, Ca, nullptr, cDM, M2, cDM, cDM, 0, 65536,
                                       65536, M2, Wb2, Fb2, bb2, Cb2, BG);
  };
  // idft: out bf16 = basisi @ H_b^T (+bias +bf16 addend)
  auto idft = [&](const short* Hin, const float* bias, const short* adb, short* Cbout) {
    mg(basisib, Hin, bias, nullptr, adb, nullptr, nullptr, nullptr, Cbout, cL, cDM, M2, M2, 0,
       65536, (long)cL * cDM, BG, 0, cDM, cDM, 0);
  };
  auto ffn = [&](const short* inb, const short* addb, short* outb, const short* c1w,
                 const float* c1bias, const short* c2w, const float* c2bias) {
    for (long r = 0; r < GBL; r += RH) {
      mg(inb + r * cDM, c1w, c1bias, nullptr, nullptr, nullptr, nullptr, nullptr, HDb, (int)RH,
         cDFF, cDM, cDM, 0, 0, 0, 1, 1, cDFF, cDFF, 0);
      mg(HDb, c2w, c2bias, nullptr, addb + r * cDM, nullptr, nullptr, nullptr, outb + r * cDM,
         (int)RH, cDM, cDFF, cDFF, 0, 0, 0, 1, 0, cDM, cDM, 0);
    }
  };
  auto trendg = [&](const short* mab) {
    mg(mab, Wtr3b, nullptr, TRD, nullptr, nullptr, nullptr, TRD, nullptr, (int)GBL, 128, 1536,
       512, 0, 0, 0, 1, 0, cCIN, cCIN, 1);
  };
  auto mixt = [&](const float* F, const short* W, float scale) {
    modemix_t_kernel<<<dim3(BG, cH), 256, 0, stream>>>(F, (const unsigned short*)W, Gtb, scale);
  };

  // ---- one-time setup ----
  basis_kernel<<<(M2 * cL) / 256, 256, 0, stream>>>(basisdb, basisib);
  pe_kernel<<<(cL * cDM) / 256, 256, 0, stream>>>(pe);
  prep_kernel<<<768, 256, 0, stream>>>(tok_W, dec_trW, p3W, p3b, Bpadb, Wtr3b, p3padb, p3bpadf);
  {
    CvtArgs ca;
    const float* srcs[NJOB] = {enc_Wq, enc_Wo, dsWq, dsWo, dcWq, dcWk, dcWo,
                               enc_c1W, enc_c2W, dec_c1W, dec_c2W, fb_enc, fb_dec, fc_w};
    short* dsts[NJOB] = {WqbE, WobE, dsWqb, dsWob, dcWqb, dcWkb, dcWob,
                         c1bE, c2bE, c1bD, c2bD, fbEb, fbDb, fcwb};
    int ns[NJOB] = {524288, 524288, 262144, 262144, 262144, 262144, 262144,
                    2097152, 2097152, 1048576, 1048576, (int)MIXW, (int)MIXW, (int)MIXW};
    for (int j = 0; j < NJOB; j++) {
      ca.src[j] = srcs[j];
      ca.dst[j] = dsts[j];
      ca.n[j] = ns[j];
    }
    cvtm_kernel<<<dim3(256, NJOB), 256, 0, stream>>>(ca);
  }

  for (int b0 = 0; b0 < cB; b0 += BG) {
    const float* xg = x_enc + (long)b0 * cL * cCIN;

    decompf(xg, TRD, GBL * cCIN, cCIN); // trend_init -> TRD (f32)
    winbuild_kernel<<<(int)(GBL * 32 / 256), 256, 0, stream>>>(xg, winb);
    mg(winb, Bpadb, nullptr, nullptr, nullptr, pe, nullptr, nullptr, Eb, (int)GBL, cDM, 128, 128,
       0, 0, 0, 1, 0, cDM, cDM, 0); // embedding -> Eb

    // ---- encoder ----
    for (int l = 0; l < 2; l++) {
      dft(Eb, FEb);
      modeproj(WqbE + (long)l * 262144, FEb, enc_bq + l * cDM, Fq, nullptr);
      mixt(Fq, fbEb, 1.0f);
      modeproj(WobE + (long)l * 262144, Gtb, nullptr, nullptr, Hb);
      idft(Hb, enc_bo + l * cDM, Eb, Yb);                     // x + attn -> Yb (bf16)
      decompb(Yb, Xb, nullptr, 0, GA, cDM);                   // h -> Xb
      ffn(Xb, Xb, Yb, c1bE + (long)l * 1048576, enc_c1b + l * cDFF, c2bE + (long)l * 1048576,
          enc_c2b + l * cDM);                                 // h + y -> Yb
      decompb(Yb, Eb, nullptr, 0, GA, cDM);                   // stream -> Eb
    }

    // ---- decoder ----
    dft(Eb, FEb);
    modeproj(dsWqb, FEb, dsbq, Fq, nullptr);
    mixt(Fq, fbDb, 1.0f);
    modeproj(dsWob, Gtb, nullptr, nullptr, Hb);
    idft(Hb, dsbo, Eb, Yb);                                   // x1 -> Yb
    decompb(Yb, Xb, Sb, 0, GA, cDM);                          // x2 -> Xb; ma -> Sb (fresh)
    dft(Xb, FXb);
    modeproj2(dcWqb, FXb, dcbq, Fq, dcWkb, FEb, dcbk, Fk);
    fused_cross_kernel<<<dim3(BG, cH), 256, 0, stream>>>(Fq, Fk, (const unsigned short*)fcwb,
                                                         Gtb, 1.0f / (float)(cDM * cDM));
    modeproj(dcWob, Gtb, nullptr, nullptr, Hb);
    idft(Hb, dcbo, Xb, Yb);                                   // x3 -> Yb
    decompb(Yb, Ab, Sb, 1, GA, cDM);                          // x4 -> Ab; ma += Sb
    ffn(Ab, Ab, Yb, c1bD, dec_c1b, c2bD, dec_c2b);            // x4 + y -> Yb
    decompb(Yb, Xb, Sb, 1, GA, cDM);                          // x5 -> Xb; ma += Sb
    trendg(Sb);                                               // conv(t1+t2+t3)

    // ---- final projections ----
    mg(Xb, p3padb, p3bpadf, TRD, nullptr, nullptr, nullptr, O1, nullptr, (int)GBL, 128, cDM, cDM,
       0, 0, 0, 1, 0, cCIN, cCIN, 0);                         // trend + x@p3
    gemm_kernel<<<dim3(1, (int)(GBL / 128)), 256, 0, stream>>>(O1, p1W, p1b, O2, (int)GBL, cCIN,
                                                               cCIN);
    p2_kernel<<<dim3(BG, 32), 256, 0, stream>>>(O2, p2W, p2b,
                                                (float*)d_out + (long)b0 * cPRED * cCIN);
  }
}

// Round 15
// 2183.974 us; speedup vs baseline: 1.9706x; 1.1374x over previous
//
#include <hip/hip_runtime.h>
#include <math.h>

namespace {

constexpr int cB = 32, cL = 1024, cCIN = 32, cDM = 512, cDFF = 2048;
constexpr int cH = 8, cE = 64, cM = 64, cPRED = 256;
constexpr int M2 = 2 * cM; // 128

typedef __attribute__((ext_vector_type(8))) short short8v;
typedef __attribute__((ext_vector_type(4))) float float4v;

__device__ inline unsigned short f2bf(float f) {
  unsigned int u = __builtin_bit_cast(unsigned int, f);
  u += 0x7FFFu + ((u >> 16) & 1u); // RNE
  return (unsigned short)(u >> 16);
}
__device__ inline float bf2f(unsigned short s) {
  return __builtin_bit_cast(float, (unsigned int)s << 16);
}

typedef const __attribute__((address_space(1))) unsigned int gu32_t;
typedef __attribute__((address_space(3))) unsigned int lu32_t;
__device__ inline void gld16(const void* g, void* l) {
  __builtin_amdgcn_global_load_lds((gu32_t*)g, (lu32_t*)l, 16, 0, 0);
}

// ================= one-time tables =================
__global__ void basis_kernel(short* __restrict__ basisdb, short* __restrict__ basisib) {
  int idx = blockIdx.x * 256 + threadIdx.x;
  if (idx >= M2 * cL) return;
  int t = idx & (cL - 1);
  int m2 = idx >> 10;
  int m = m2 >> 1;
  float ang = 6.2831853071795864f * (float)((m * t) & (cL - 1)) / (float)cL;
  float cv = cosf(ang), sv = sinf(ang);
  float vd = (m2 & 1) ? -sv : cv;
  basisdb[idx] = (short)f2bf(vd);
  float s = (m == 0) ? ((m2 & 1) ? 0.f : (1.f / (float)cL)) : (2.f / (float)cL);
  basisib[t * M2 + m2] = (short)f2bf(vd * s);
}

__global__ void pe_kernel(float* __restrict__ pe) {
  int idx = blockIdx.x * 256 + threadIdx.x;
  int o = idx & (cDM - 1), t = idx >> 9;
  int i = o >> 1;
  float freq = __expf((float)(2 * i) * (-9.210340371976184f / (float)cDM));
  float ang = freq * (float)t;
  pe[idx] = (o & 1) ? cosf(ang) : sinf(ang);
}

constexpr int NJOB = 14;
struct CvtArgs {
  const float* src[NJOB];
  short* dst[NJOB];
  int n[NJOB];
};
__global__ void cvtm_kernel(CvtArgs a) {
  int j = blockIdx.y;
  const float* s = a.src[j];
  short* d = a.dst[j];
  int n = a.n[j];
  for (int i = blockIdx.x * 256 + threadIdx.x; i < n; i += gridDim.x * 256)
    d[i] = (short)f2bf(s[i]);
}

// Bpadb[o][j*32+c]=tok_W[o][c][j]; Wtr3b[o][j*512+c]=trW[o][c][j] (o<32); p3padb; p3bpadf
__global__ void prep_kernel(const float* __restrict__ tok_W, const float* __restrict__ trW,
                            const float* __restrict__ p3W, const float* __restrict__ p3b,
                            short* __restrict__ Bpadb, short* __restrict__ Wtr3b,
                            short* __restrict__ p3padb, float* __restrict__ p3bpadf) {
  int idx = blockIdx.x * 256 + threadIdx.x;
  if (idx < 512 * 128) {
    int o = idx >> 7, s = idx & 127, j = s >> 5, c = s & 31;
    Bpadb[idx] = (j < 3) ? (short)f2bf(tok_W[o * 96 + c * 3 + j]) : (short)0;
  }
  if (idx < 128 * 1536) {
    int o = idx / 1536, r = idx % 1536, j = r >> 9, c = r & 511;
    Wtr3b[idx] = (o < 32) ? (short)f2bf(trW[(long)o * 1536 + c * 3 + j]) : (short)0;
  }
  if (idx < 128 * 512) {
    int o = idx >> 9, k = idx & 511;
    p3padb[idx] = (o < 32) ? (short)f2bf(p3W[o * 512 + k]) : (short)0;
  }
  if (idx < 128) p3bpadf[idx] = (idx < 32) ? p3b[idx] : 0.f;
}

// win[row][128] bf16 = [x[t-1,:], x[t,:], x[t+1,:], 0] circular
__global__ void winbuild_kernel(const float* __restrict__ x, short* __restrict__ win) {
  int idx = blockIdx.x * 256 + threadIdx.x;
  int s4 = idx & 31;
  int row = idx >> 5;
  int t = row & (cL - 1), b = row >> 10;
  int j = s4 >> 3, c4 = s4 & 7;
  unsigned int lo = 0, hi = 0;
  if (j < 3) {
    int ts = (t + j + cL - 1) & (cL - 1);
    float4 v = *(const float4*)&x[((long)b * cL + ts) * cCIN + c4 * 4];
    lo = (unsigned int)f2bf(v.x) | ((unsigned int)f2bf(v.y) << 16);
    hi = (unsigned int)f2bf(v.z) | ((unsigned int)f2bf(v.w) << 16);
  }
  *(uint2*)&win[row * 128 + s4 * 4] = make_uint2(lo, hi);
}

// batched bf16 transpose: in [B][1024][512] -> out [B][512][1024]
__global__ __launch_bounds__(256) void transpose_bf(const short* __restrict__ in,
                                                    short* __restrict__ out) {
  __shared__ short tile[32][33];
  int b = blockIdx.z;
  in += (long)b * cL * cDM;
  out += (long)b * cL * cDM;
  int c0 = blockIdx.x * 32, t0 = blockIdx.y * 32;
  int tx = threadIdx.x & 31, ty = threadIdx.x >> 5;
#pragma unroll
  for (int r = 0; r < 32; r += 8) tile[ty + r][tx] = in[(long)(t0 + ty + r) * cDM + c0 + tx];
  __syncthreads();
#pragma unroll
  for (int r = 0; r < 32; r += 8)
    out[(long)(c0 + ty + r) * cL + t0 + tx] = tile[tx][ty + r];
}

// ==== f32-input decomp (trend-init only): ma -> maf ====
__global__ void decomp_kernel(const float* __restrict__ x, float* __restrict__ maf, int n8,
                              int C) {
  int idx = blockIdx.x * 256 + threadIdx.x;
  if (idx >= n8) return;
  int c = idx % C;
  int u = idx / C;
  int t0 = (u & 127) * 8;
  int b = u >> 7;
  long base = (long)b * cL * C + c;
  float s = 0.f;
#pragma unroll
  for (int j = -12; j <= 12; j++) {
    int tt = t0 + j;
    tt = tt < 0 ? 0 : (tt >= cL ? cL - 1 : tt);
    s += x[base + (long)tt * C];
  }
#pragma unroll
  for (int k = 0; k < 8; k++) {
    int t = t0 + k;
    maf[base + (long)t * C] = s * (1.0f / 25.0f);
    int ta = t + 13;
    ta = ta >= cL ? cL - 1 : ta;
    int td = t - 12;
    td = td < 0 ? 0 : td;
    s += x[base + (long)ta * C] - x[base + (long)td * C];
  }
}

// ==== bf16-input decomp: seasonal bf16 + optional accumulated ma bf16 ====
__global__ void decompb_kernel(const short* __restrict__ x, short* __restrict__ sb,
                               short* __restrict__ mab, int maacc, int n8, int C) {
  int idx = blockIdx.x * 256 + threadIdx.x;
  if (idx >= n8) return;
  int c = idx % C;
  int u = idx / C;
  int t0 = (u & 127) * 8;
  int b = u >> 7;
  long base = (long)b * cL * C + c;
  float s = 0.f;
#pragma unroll
  for (int j = -12; j <= 12; j++) {
    int tt = t0 + j;
    tt = tt < 0 ? 0 : (tt >= cL ? cL - 1 : tt);
    s += bf2f((unsigned short)x[base + (long)tt * C]);
  }
#pragma unroll
  for (int k = 0; k < 8; k++) {
    int t = t0 + k;
    long e = base + (long)t * C;
    float ma = s * (1.0f / 25.0f);
    if (sb) sb[e] = (short)f2bf(bf2f((unsigned short)x[e]) - ma);
    if (mab) {
      float v = maacc ? bf2f((unsigned short)mab[e]) + ma : ma;
      mab[e] = (short)f2bf(v);
    }
    int ta = t + 13;
    ta = ta >= cL ? cL - 1 : ta;
    int td = t - 12;
    td = td < 0 ? 0 : td;
    s += bf2f((unsigned short)x[base + (long)ta * C]) - bf2f((unsigned short)x[base + (long)td * C]);
  }
}

// ================= final time projection =================
__global__ __launch_bounds__(256) void p2_kernel(const float* __restrict__ x,
                                                 const float* __restrict__ W,
                                                 const float* __restrict__ bias,
                                                 float* __restrict__ out) {
  __shared__ float tile[256 * 32];
  int b = blockIdx.x;
  int p0 = blockIdx.y * 8;
  int c = threadIdx.x & 31, pl = threadIdx.x >> 5;
  const float* xb = x + (long)b * cL * cCIN;
  const float* w = W + (long)(p0 + pl) * cL;
  float s = 0.f;
  for (int l0 = 0; l0 < cL; l0 += 256) {
    __syncthreads();
    for (int i = threadIdx.x; i < 256 * 32; i += 256) tile[i] = xb[(long)l0 * 32 + i];
    __syncthreads();
#pragma unroll 8
    for (int l = 0; l < 256; l++) s += tile[l * 32 + c] * w[l0 + l];
  }
  out[((long)b * cPRED + p0 + pl) * cCIN + c] = s + bias[p0 + pl];
}

// ====== per-(h,mode) complex mode mix; W bf16; 512 threads; transposed bf16 out ======
__global__ __launch_bounds__(512) void modemix_t_kernel(const float* __restrict__ F,
                                                        const unsigned short* __restrict__ W,
                                                        short* __restrict__ Gt, float scale) {
  int b = blockIdx.x, h = blockIdx.y;
  __shared__ float2 Fs[cE][cM];
  __shared__ short ot[128][72];
  const float* Fb = F + ((long)b * cDM + h * cE) * M2;
  for (int i = threadIdx.x; i < cE * cM; i += 512) {
    int e = i >> 6, x = i & 63;
    Fs[e][x] = ((const float2*)(Fb + (long)e * M2))[x];
  }
  __syncthreads();
  int x = threadIdx.x & 63, og = threadIdx.x >> 6; // og in [0,8)
  float2 acc[8];
#pragma unroll
  for (int i = 0; i < 8; i++) acc[i] = make_float2(0.f, 0.f);
  for (int e = 0; e < cE; e++) {
    float2 f = Fs[e][x];
#pragma unroll
    for (int i = 0; i < 8; i++) {
      int o = og * 8 + i;
      unsigned int wu = *(const unsigned int*)&W[((((long)h * cE + e) * cE + o) * cM + x) * 2];
      float wx = bf2f((unsigned short)wu), wy = bf2f((unsigned short)(wu >> 16));
      acc[i].x += f.x * wx - f.y * wy;
      acc[i].y += f.x * wy + f.y * wx;
    }
  }
#pragma unroll
  for (int i = 0; i < 8; i++) {
    int o = og * 8 + i;
    ot[2 * x][o] = (short)f2bf(acc[i].x * scale);
    ot[2 * x + 1][o] = (short)f2bf(acc[i].y * scale);
  }
  __syncthreads();
  short* gb = Gt + (long)b * (M2 * cDM) + h * cE;
  for (int u = threadIdx.x; u < 1024; u += 512) {
    int row = u >> 3, seg = u & 7;
    *(uint4*)&gb[(long)row * cDM + seg * 8] = *(const uint4*)&ot[row][seg * 8];
  }
}

// ====== fused cross attention (W bf16, 1024 threads, conflict-free LDS layouts) ======
__global__ __launch_bounds__(1024) void fused_cross_kernel(const float* __restrict__ Fq,
                                                           const float* __restrict__ Fk,
                                                           const unsigned short* __restrict__ W,
                                                           short* __restrict__ Gt, float scale) {
  __shared__ __align__(16) char smem[65536];
  float2(*KsT)[cE] = (float2(*)[cE])smem;            // [y][e]
  float2(*qks)[cM] = (float2(*)[cM])(smem + 32768);  // [y][x]
  int b = blockIdx.x, h = blockIdx.y;
  const float* kb = Fk + ((long)b * cDM + h * cE) * M2;
  for (int i = threadIdx.x; i < cE * cM; i += 1024) {
    int e = i >> 6, y = i & 63;
    KsT[y][e] = ((const float2*)(kb + (long)e * M2))[y];
  }
  __syncthreads();
  { // phase 1: qk[y][x] = tanh(sum_e q[e][x] * k[e][y]); 4 y per thread
    int x = threadIdx.x & 63, yg = threadIdx.x >> 6; // yg in [0,16)
    const float* qb = Fq + ((long)b * cDM + h * cE) * M2;
    float2 acc[4];
#pragma unroll
    for (int i = 0; i < 4; i++) acc[i] = make_float2(0.f, 0.f);
    for (int e = 0; e < cE; e++) {
      float2 q = ((const float2*)(qb + (long)e * M2))[x];
#pragma unroll
      for (int i = 0; i < 4; i++) {
        float2 k = KsT[yg * 4 + i][e];
        acc[i].x += q.x * k.x - q.y * k.y;
        acc[i].y += q.x * k.y + q.y * k.x;
      }
    }
#pragma unroll
    for (int i = 0; i < 4; i++) {
      int y = yg * 4 + i;
      float a = acc[i].x, bi = acc[i].y;
      float re, im;
      float t2a = 2.f * a;
      if (fabsf(t2a) > 60.f) {
        re = t2a > 0.f ? 1.f : -1.f;
        im = 0.f;
      } else {
        float denom = coshf(t2a) + cosf(2.f * bi);
        re = sinhf(t2a) / denom;
        im = sinf(2.f * bi) / denom;
      }
      qks[y][x] = make_float2(re, im);
    }
  }
  __syncthreads();
  // phase 2: qkv[e][x] = sum_y qk[y][x] * k[e][y]; 4 x per thread
  int e = threadIdx.x & 63, xg = threadIdx.x >> 6;
  float2 a2[4];
#pragma unroll
  for (int i = 0; i < 4; i++) a2[i] = make_float2(0.f, 0.f);
  for (int y = 0; y < cM; y++) {
    float2 k = KsT[y][e];
#pragma unroll
    for (int i = 0; i < 4; i++) {
      float2 qk = qks[y][xg * 4 + i];
      a2[i].x += qk.x * k.x - qk.y * k.y;
      a2[i].y += qk.x * k.y + qk.y * k.x;
    }
  }
  __syncthreads();
  float2(*Qv)[cM] = (float2(*)[cM])smem;
#pragma unroll
  for (int i = 0; i < 4; i++) Qv[e][xg * 4 + i] = a2[i];
  __syncthreads();
  { // phase 3: mix + transposed bf16 store; 4 o per thread
    int x = threadIdx.x & 63, og = threadIdx.x >> 6;
    float2 m[4];
#pragma unroll
    for (int i = 0; i < 4; i++) m[i] = make_float2(0.f, 0.f);
    for (int ee = 0; ee < cE; ee++) {
      float2 f = Qv[ee][x];
#pragma unroll
      for (int i = 0; i < 4; i++) {
        int o = og * 4 + i;
        unsigned int wu = *(const unsigned int*)&W[((((long)h * cE + ee) * cE + o) * cM + x) * 2];
        float wx = bf2f((unsigned short)wu), wy = bf2f((unsigned short)(wu >> 16));
        m[i].x += f.x * wx - f.y * wy;
        m[i].y += f.x * wy + f.y * wx;
      }
    }
    short(*ot)[72] = (short(*)[72])(smem + 32768);
#pragma unroll
    for (int i = 0; i < 4; i++) {
      int o = og * 4 + i;
      ot[2 * x][o] = (short)f2bf(m[i].x * scale);
      ot[2 * x + 1][o] = (short)f2bf(m[i].y * scale);
    }
    __syncthreads();
    short* gb = Gt + (long)b * (M2 * cDM) + h * cE;
    int u = threadIdx.x; // exactly 1024 segments
    {
      int row = u >> 3, seg = u & 7;
      *(uint4*)&gb[(long)row * cDM + seg * 8] =
          *(const uint4*)&((short(*)[72])(smem + 32768))[row][seg * 8];
    }
  }
}

// ================= f32 shader GEMM (tiny p1 only) =================
constexpr int GBM = 128, GBN = 128, GBK = 16, LPAD = 132;

__global__ __launch_bounds__(256) void gemm_kernel(const float* __restrict__ A,
                                                   const float* __restrict__ B,
                                                   const float* __restrict__ bias,
                                                   float* __restrict__ C, int M, int N, int K) {
  __shared__ float As[GBK][LPAD];
  __shared__ float Bs[GBK][LPAD];
  int n0 = blockIdx.x * GBN, m0 = blockIdx.y * GBM;
  int tid = threadIdx.x;
  int tx = tid & 15, ty = tid >> 4;
  float acc[8][8];
#pragma unroll
  for (int i = 0; i < 8; i++)
#pragma unroll
    for (int j = 0; j < 8; j++) acc[i][j] = 0.f;

  for (int k0 = 0; k0 < K; k0 += GBK) {
#pragma unroll
    for (int p = 0; p < 8; p++) {
      int i = p * 256 + tid;
      int mm = i >> 4, kk = i & 15;
      int gm = m0 + mm;
      As[kk][mm] = (gm < M && k0 + kk < K) ? A[(long)gm * K + k0 + kk] : 0.f;
    }
#pragma unroll
    for (int p = 0; p < 8; p++) {
      int i = p * 256 + tid;
      int nn = i >> 4, kk = i & 15;
      int gn = n0 + nn;
      Bs[kk][nn] = (gn < N && k0 + kk < K) ? B[(long)gn * K + k0 + kk] : 0.f;
    }
    __syncthreads();
#pragma unroll
    for (int kk = 0; kk < GBK; kk++) {
      float a[8], bb[8];
      *(float4*)&a[0] = *(const float4*)&As[kk][ty * 8];
      *(float4*)&a[4] = *(const float4*)&As[kk][ty * 8 + 4];
      *(float4*)&bb[0] = *(const float4*)&Bs[kk][tx * 8];
      *(float4*)&bb[4] = *(const float4*)&Bs[kk][tx * 8 + 4];
#pragma unroll
      for (int i = 0; i < 8; i++)
#pragma unroll
        for (int j = 0; j < 8; j++) acc[i][j] += a[i] * bb[j];
    }
    __syncthreads();
  }

  for (int i = 0; i < 8; i++) {
    int gm = m0 + ty * 8 + i;
    if (gm >= M) break;
    long rowoff = (long)gm * N;
    for (int j = 0; j < 8; j++) {
      int gn = n0 + tx * 8 + j;
      if (gn < N) C[rowoff + gn] = acc[i][j] + (bias ? bias[gn] : 0.f);
    }
  }
}

// ===== bf16 MFMA GEMM 128x128 (m97 single-buffer, swizzled, XCD-chunked) =====
__global__ __launch_bounds__(256) void mfma_gemm_bf(
    const short* __restrict__ A, const short* __restrict__ B, const float* __restrict__ bias,
    const float* __restrict__ addend, const short* __restrict__ addendb,
    const float* __restrict__ pe, const float* __restrict__ m0b, float* __restrict__ Cf,
    short* __restrict__ Cb, int M, int N, int K, int lda, long sA, long sB, long sC, int relu,
    int Nreal, int ldc, int amode) {
  __shared__ __align__(16) short As[8192];
  __shared__ __align__(16) short Bs[8192];
  int nwg = gridDim.x * gridDim.y * gridDim.z;
  int orig = blockIdx.x + gridDim.x * (blockIdx.y + gridDim.y * blockIdx.z);
  int q = nwg >> 3, r = nwg & 7;
  int xcd = orig & 7, ii = orig >> 3;
  int flat = (xcd < r ? xcd * (q + 1) : r * (q + 1) + (xcd - r) * q) + ii;
  int bx = flat % (int)gridDim.x;
  int tmp = flat / (int)gridDim.x;
  int by = tmp % (int)gridDim.y;
  int bz = tmp / (int)gridDim.y;

  int z = bz;
  A += (long)z * sA;
  B += (long)z * sB;
  if (Cf) Cf += (long)z * sC;
  if (Cb) Cb += (long)z * sC;
  const float* Ad = addend ? addend + (long)z * sC : nullptr;
  const short* Adb = addendb ? addendb + (long)z * sC : nullptr;
  int n0 = bx * 128, m0 = by * 128;
  int tid = threadIdx.x;
  int lane = tid & 63;
  int w = tid >> 6;
  int wm = w & 1, wn = w >> 1;
  int lr = lane & 15, lg = lane >> 4;
  int lrow = lane >> 3;
  int scol = ((lane & 7) * 8) ^ (lrow << 3);

  float4v acc[4][4];
#pragma unroll
  for (int i = 0; i < 4; i++)
#pragma unroll
    for (int j = 0; j < 4; j++) acc[i][j] = (float4v){0.f, 0.f, 0.f, 0.f};

  auto stage = [&](int k0) {
#pragma unroll
    for (int j = 0; j < 4; j++) {
      int seg = w * 4 + j;
      int row = seg * 8 + lrow;
      const short* ga;
      if (amode == 0) {
        ga = A + (long)(m0 + row) * lda + k0 + scol;
      } else {
        int r2 = m0 + row;
        int bb = r2 >> 10, t = r2 & 1023;
        int jj = k0 >> 9, c0 = k0 & 511;
        ga = A + ((((long)(bb << 10)) | ((t + jj + 1023) & 1023)) << 9) + c0 + scol;
      }
      gld16(ga, &As[seg * 512]);
      const short* gb = B + (long)(n0 + row) * K + k0 + scol;
      gld16(gb, &Bs[seg * 512]);
    }
  };

  int nk = K >> 6;
  int swr = (lr & 7) << 3;
  for (int t = 0; t < nk; ++t) {
    stage(t << 6);
    asm volatile("s_waitcnt vmcnt(0)" ::: "memory");
    __syncthreads();
#pragma unroll
    for (int ks = 0; ks < 2; ks++) {
      short8v af[4], bfr[4];
#pragma unroll
      for (int mi = 0; mi < 4; mi++)
        af[mi] = *(const short8v*)&As[(wm * 64 + mi * 16 + lr) * 64 + ((ks * 32 + lg * 8) ^ swr)];
#pragma unroll
      for (int ni = 0; ni < 4; ni++)
        bfr[ni] = *(const short8v*)&Bs[(wn * 64 + ni * 16 + lr) * 64 + ((ks * 32 + lg * 8) ^ swr)];
#pragma unroll
      for (int mi = 0; mi < 4; mi++)
#pragma unroll
        for (int ni = 0; ni < 4; ni++)
          acc[mi][ni] =
              __builtin_amdgcn_mfma_f32_16x16x32_bf16(af[mi], bfr[ni], acc[mi][ni], 0, 0, 0);
    }
    __syncthreads();
  }

#pragma unroll
  for (int mi = 0; mi < 4; mi++) {
#pragma unroll
    for (int i = 0; i < 4; i++) {
      int gr = m0 + wm * 64 + mi * 16 + lg * 4 + i;
      long rowoff = (long)gr * ldc;
#pragma unroll
      for (int ni = 0; ni < 4; ni++) {
        int gc = n0 + wn * 64 + ni * 16 + lr;
        if (gc < Nreal) {
          float v = acc[mi][ni][i];
          if (bias) v += bias[gc];
          if (pe) v += pe[((gr & (cL - 1)) << 9) + gc];
          if (m0b && gc == 0) v += 1024.f * m0b[gr];
          if (Ad) v += Ad[rowoff + gc];
          if (Adb) v += bf2f((unsigned short)Adb[rowoff + gc]);
          if (relu) v = fmaxf(v, 0.f);
          if (Cf) Cf[rowoff + gc] = v;
          if (Cb) Cb[rowoff + gc] = (short)f2bf(v);
        }
      }
    }
  }
}

// ===== bf16 MFMA GEMM 64x64 (small/latency-bound shapes; full epilogue; zsplit) =====
__global__ __launch_bounds__(256) void mfma_gemm64(
    const short* __restrict__ A, const short* __restrict__ B, const float* __restrict__ bias,
    const float* __restrict__ addf, const short* __restrict__ addb,
    const float* __restrict__ m0b, float* __restrict__ Cf, short* __restrict__ Cb, int M, int N,
    int K, int lda, long sA, long sB, long sC, int Nreal, int ldc, int amode,
    const short* __restrict__ A2, const short* __restrict__ B2, const float* __restrict__ m0b2,
    float* __restrict__ Cf2, int zsplit) {
  __shared__ __align__(16) short As[4096];
  __shared__ __align__(16) short Bs[4096];
  int nwg = gridDim.x * gridDim.y * gridDim.z;
  int orig = blockIdx.x + gridDim.x * (blockIdx.y + gridDim.y * blockIdx.z);
  int q = nwg >> 3, r = nwg & 7;
  int xcd = orig & 7, ii = orig >> 3;
  int flat = (xcd < r ? xcd * (q + 1) : r * (q + 1) + (xcd - r) * q) + ii;
  int bx = flat % (int)gridDim.x;
  int tmp = flat / (int)gridDim.x;
  int by = tmp % (int)gridDim.y;
  int bz = tmp / (int)gridDim.y;

  int z = bz;
  if (zsplit > 0 && bz >= zsplit) {
    A = A2;
    B = B2;
    m0b = m0b2;
    Cf = Cf2;
    z = bz - zsplit;
  }
  A += (long)z * sA;
  B += (long)z * sB;
  if (Cf) Cf += (long)z * sC;
  if (Cb) Cb += (long)z * sC;
  const float* Ad = addf ? addf + (long)z * sC : nullptr;
  const short* Adb = addb ? addb + (long)z * sC : nullptr;
  int n0 = bx * 64, m0 = by * 64;
  int tid = threadIdx.x;
  int lane = tid & 63;
  int w = tid >> 6;
  int wm = w & 1, wn = w >> 1;
  int lr = lane & 15, lg = lane >> 4;
  int lrow = lane >> 3;
  int scol = ((lane & 7) * 8) ^ (lrow << 3);

  float4v acc[2][2];
#pragma unroll
  for (int i = 0; i < 2; i++)
#pragma unroll
    for (int j = 0; j < 2; j++) acc[i][j] = (float4v){0.f, 0.f, 0.f, 0.f};

  int nk = K >> 6;
  int swr = (lr & 7) << 3;
  for (int t = 0; t < nk; ++t) {
    int k0 = t << 6;
#pragma unroll
    for (int j = 0; j < 2; j++) {
      int seg = w * 2 + j;
      int row = seg * 8 + lrow;
      const short* ga;
      if (amode == 0) {
        ga = A + (long)(m0 + row) * lda + k0 + scol;
      } else {
        int r2 = m0 + row;
        int bb = r2 >> 10, tt = r2 & 1023;
        int jj = k0 >> 9, c0 = k0 & 511;
        ga = A + ((((long)(bb << 10)) | ((tt + jj + 1023) & 1023)) << 9) + c0 + scol;
      }
      gld16(ga, &As[seg * 512]);
      gld16(B + (long)(n0 + row) * K + k0 + scol, &Bs[seg * 512]);
    }
    asm volatile("s_waitcnt vmcnt(0)" ::: "memory");
    __syncthreads();
#pragma unroll
    for (int ks = 0; ks < 2; ks++) {
      short8v af[2], bfr[2];
#pragma unroll
      for (int mi = 0; mi < 2; mi++)
        af[mi] = *(const short8v*)&As[(wm * 32 + mi * 16 + lr) * 64 + ((ks * 32 + lg * 8) ^ swr)];
#pragma unroll
      for (int ni = 0; ni < 2; ni++)
        bfr[ni] = *(const short8v*)&Bs[(wn * 32 + ni * 16 + lr) * 64 + ((ks * 32 + lg * 8) ^ swr)];
#pragma unroll
      for (int mi = 0; mi < 2; mi++)
#pragma unroll
        for (int ni = 0; ni < 2; ni++)
          acc[mi][ni] =
              __builtin_amdgcn_mfma_f32_16x16x32_bf16(af[mi], bfr[ni], acc[mi][ni], 0, 0, 0);
    }
    __syncthreads();
  }

#pragma unroll
  for (int mi = 0; mi < 2; mi++) {
#pragma unroll
    for (int i = 0; i < 4; i++) {
      int gr = m0 + wm * 32 + mi * 16 + lg * 4 + i;
      long rowoff = (long)gr * ldc;
#pragma unroll
      for (int ni = 0; ni < 2; ni++) {
        int gc = n0 + wn * 32 + ni * 16 + lr;
        if (gc < Nreal) {
          float v = acc[mi][ni][i];
          if (bias) v += bias[gc];
          if (m0b && gc == 0) v += 1024.f * m0b[gr];
          if (Ad) v += Ad[rowoff + gc];
          if (Adb) v += bf2f((unsigned short)Adb[rowoff + gc]);
          if (Cf) Cf[rowoff + gc] = v;
          if (Cb) Cb[rowoff + gc] = (short)f2bf(v);
        }
      }
    }
  }
}

} // namespace

extern "C" void kernel_launch(void* const* d_in, const int* in_sizes, int n_in, void* d_out,
                              int out_size, void* d_ws, size_t ws_size, hipStream_t stream) {
  const float* x_enc = (const float*)d_in[0];
  const float* tok_W = (const float*)d_in[1];
  const float* enc_Wq = (const float*)d_in[2];
  const float* enc_Wo = (const float*)d_in[5];
  const float* enc_bq = (const float*)d_in[6];
  const float* enc_bo = (const float*)d_in[9];
  const float* dsWq = (const float*)d_in[10];
  const float* dsWo = (const float*)d_in[13];
  const float* dsbq = (const float*)d_in[14];
  const float* dsbo = (const float*)d_in[17];
  const float* dcWq = (const float*)d_in[18];
  const float* dcWk = (const float*)d_in[19];
  const float* dcWo = (const float*)d_in[21];
  const float* dcbq = (const float*)d_in[22];
  const float* dcbk = (const float*)d_in[23];
  const float* dcbo = (const float*)d_in[25];
  const float* enc_c1W = (const float*)d_in[26];
  const float* enc_c1b = (const float*)d_in[27];
  const float* enc_c2W = (const float*)d_in[28];
  const float* enc_c2b = (const float*)d_in[29];
  const float* dec_c1W = (const float*)d_in[30];
  const float* dec_c1b = (const float*)d_in[31];
  const float* dec_c2W = (const float*)d_in[32];
  const float* dec_c2b = (const float*)d_in[33];
  const float* dec_trW = (const float*)d_in[34];
  const float* fb_enc = (const float*)d_in[35];
  const float* fb_dec = (const float*)d_in[36];
  const float* fc_w = (const float*)d_in[37];
  const float* p1W = (const float*)d_in[38];
  const float* p1b = (const float*)d_in[39];
  const float* p2W = (const float*)d_in[40];
  const float* p2b = (const float*)d_in[41];
  const float* p3W = (const float*)d_in[42];
  const float* p3b = (const float*)d_in[43];

  constexpr long MIXW = 8L * 64 * 64 * 64 * 2;

  // ---- layout sizing (dry-run) ----
  auto layout_bytes = [&](long BG, long RH) -> size_t {
    size_t t = 0;
    auto add = [&](size_t b) { t = (t + b + 255) & ~(size_t)255; };
    add(2 * 262144 * 2); add(2 * 262144 * 2);
    add(262144 * 2); add(262144 * 2); add(262144 * 2); add(262144 * 2); add(262144 * 2);
    add(2 * 1048576 * 2); add(2 * 1048576 * 2); add(1048576 * 2); add(1048576 * 2);
    add(131072 * 2); add(131072 * 2); add(65536 * 2); add(196608 * 2); add(65536 * 2);
    add(128 * 4); add(524288 * 4);
    add(MIXW * 2); add(MIXW * 2); add(MIXW * 2);
    long GA = BG * cL * cDM;
    add(GA * 2); add(GA * 2); add(GA * 2); add(GA * 2); add(GA * 2); // Eb Xb Ab Sb Yb
    add(BG * cL * 128 * 2);
    size_t ub = (size_t)GA * 2;
    size_t hd = (size_t)RH * cDFF * 2;
    add(ub > hd ? ub : hd);
    add(BG * 65536 * 4); add(BG * 65536 * 4);
    add(BG * 65536 * 2); add(BG * 65536 * 2); add(BG * 65536 * 2); add(BG * 65536 * 2);
    add(BG * cL * cCIN * 4); add(BG * cL * cCIN * 4); add(BG * cL * cCIN * 4);
    return t;
  };
  int BG = cB;
  while (BG > 1 && layout_bytes(BG, 512) > ws_size) BG >>= 1;
  long RH = (long)BG * cL;
  while (RH > 512 && layout_bytes(BG, RH) > ws_size) RH >>= 1;

  long GBL = (long)BG * cL;
  char* base = (char*)d_ws;
  size_t off = 0;
  auto alloc = [&](size_t bytes) -> void* {
    void* p = base + off;
    off = (off + bytes + 255) & ~(size_t)255;
    return p;
  };
  short* WqbE = (short*)alloc(2 * 262144 * 2);
  short* WobE = (short*)alloc(2 * 262144 * 2);
  short* dsWqb = (short*)alloc(262144 * 2);
  short* dsWob = (short*)alloc(262144 * 2);
  short* dcWqb = (short*)alloc(262144 * 2);
  short* dcWkb = (short*)alloc(262144 * 2);
  short* dcWob = (short*)alloc(262144 * 2);
  short* c1bE = (short*)alloc(2 * 1048576 * 2);
  short* c2bE = (short*)alloc(2 * 1048576 * 2);
  short* c1bD = (short*)alloc(1048576 * 2);
  short* c2bD = (short*)alloc(1048576 * 2);
  short* basisdb = (short*)alloc(131072 * 2);
  short* basisib = (short*)alloc(131072 * 2);
  short* Bpadb = (short*)alloc(65536 * 2);
  short* Wtr3b = (short*)alloc(196608 * 2);
  short* p3padb = (short*)alloc(65536 * 2);
  float* p3bpadf = (float*)alloc(128 * 4);
  float* pe = (float*)alloc(524288 * 4);
  short* fbEb = (short*)alloc(MIXW * 2);
  short* fbDb = (short*)alloc(MIXW * 2);
  short* fcwb = (short*)alloc(MIXW * 2);
  long GA = GBL * cDM;
  short* Eb = (short*)alloc(GA * 2);
  short* Xb = (short*)alloc(GA * 2);
  short* Ab = (short*)alloc(GA * 2);
  short* Sb = (short*)alloc(GA * 2);
  short* Yb = (short*)alloc(GA * 2);
  short* winb = (short*)alloc(GBL * 128 * 2);
  size_t ubsz = (size_t)GA * 2;
  size_t hdsz = (size_t)RH * cDFF * 2;
  short* UB = (short*)alloc(ubsz > hdsz ? ubsz : hdsz);
  short* Tb = UB;
  short* HDb = UB;
  float* Fq = (float*)alloc((size_t)BG * 65536 * 4);
  float* Fk = (float*)alloc((size_t)BG * 65536 * 4);
  short* FEb = (short*)alloc((size_t)BG * 65536 * 2);
  short* FXb = (short*)alloc((size_t)BG * 65536 * 2);
  short* Gtb = (short*)alloc((size_t)BG * 65536 * 2);
  short* Hb = (short*)alloc((size_t)BG * 65536 * 2);
  float* TRD = (float*)alloc(GBL * cCIN * 4);
  float* O1 = (float*)alloc(GBL * cCIN * 4);
  float* O2 = (float*)alloc(GBL * cCIN * 4);

  auto mg = [&](const short* Am, const short* Bm, const float* bias, const float* add,
                const short* adb, const float* peA, const float* m0b, float* Cf, short* Cb,
                int Mm, int Nn, int Kk, int lda, long sA, long sB, long sC, int batch, int relu,
                int Nreal, int ldc, int amode) {
    dim3 g(Nn / 128, Mm / 128, batch);
    mfma_gemm_bf<<<g, 256, 0, stream>>>(Am, Bm, bias, add, adb, peA, m0b, Cf, Cb, Mm, Nn, Kk,
                                        lda, sA, sB, sC, relu, Nreal, ldc, amode);
  };
  auto mg64 = [&](const short* Am, const short* Bm, const float* bias, const float* addf,
                  const short* addb, const float* m0b, float* Cf, short* Cb, int Mm, int Nn,
                  int Kk, int lda, long sA, long sB, long sC, int batch, int Nreal, int ldc,
                  int amode) {
    dim3 g(Nn / 64, Mm / 64, batch);
    mfma_gemm64<<<g, 256, 0, stream>>>(Am, Bm, bias, addf, addb, m0b, Cf, Cb, Mm, Nn, Kk, lda,
                                       sA, sB, sC, Nreal, ldc, amode, nullptr, nullptr, nullptr,
                                       nullptr, 0);
  };
  auto decompf = [&](const float* x, float* maf, long total, int C_) {
    int n8 = (int)(total / 8);
    decomp_kernel<<<(n8 + 255) / 256, 256, 0, stream>>>(x, maf, n8, C_);
  };
  auto decompb = [&](const short* x, short* sb, short* mab, int maacc, long total, int C_) {
    int n8 = (int)(total / 8);
    decompb_kernel<<<(n8 + 255) / 256, 256, 0, stream>>>(x, sb, mab, maacc, n8, C_);
  };
  auto dft = [&](const short* srcb, short* Fout) {
    transpose_bf<<<dim3(16, 32, BG), 256, 0, stream>>>(srcb, Tb);
    mg64(basisdb, Tb, nullptr, nullptr, nullptr, nullptr, nullptr, Fout, M2, cDM, cL, cL, 0,
         (long)cDM * cL, 65536, BG, cDM, cDM, 0);
  };
  auto modeproj = [&](const short* Wb, const short* Fin, const float* m0b, float* Cf, short* Cb) {
    mg64(Wb, Fin, nullptr, nullptr, nullptr, m0b, Cf, Cb, cDM, M2, cDM, cDM, 0, 65536, 65536, BG,
         M2, M2, 0);
  };
  auto modeproj2 = [&](const short* Wa, const short* Fa, const float* ba, float* Ca,
                       const short* Wb2, const short* Fb2, const float* bb2, float* Cb2) {
    dim3 g(M2 / 64, cDM / 64, 2 * BG);
    mfma_gemm64<<<g, 256, 0, stream>>>(Wa, Fa, nullptr, nullptr, nullptr, ba, Ca, nullptr, cDM,
                                       M2, cDM, cDM, 0, 65536, 65536, M2, M2, 0, Wb2, Fb2, bb2,
                                       Cb2, BG);
  };
  auto idft = [&](const short* Hin, const float* bias, const short* adb, short* Cbout) {
    mg64(basisib, Hin, bias, nullptr, adb, nullptr, nullptr, Cbout, cL, cDM, M2, M2, 0, 65536,
         (long)cL * cDM, BG, cDM, cDM, 0);
  };
  auto ffn = [&](const short* inb, const short* addb, short* outb, const short* c1w,
                 const float* c1bias, const short* c2w, const float* c2bias) {
    for (long r = 0; r < GBL; r += RH) {
      mg(inb + r * cDM, c1w, c1bias, nullptr, nullptr, nullptr, nullptr, nullptr, HDb, (int)RH,
         cDFF, cDM, cDM, 0, 0, 0, 1, 1, cDFF, cDFF, 0);
      mg(HDb, c2w, c2bias, nullptr, addb + r * cDM, nullptr, nullptr, nullptr, outb + r * cDM,
         (int)RH, cDM, cDFF, cDFF, 0, 0, 0, 1, 0, cDM, cDM, 0);
    }
  };
  auto trendg = [&](const short* mab) {
    mg64(mab, Wtr3b, nullptr, TRD, nullptr, nullptr, TRD, nullptr, (int)GBL, 64, 1536, 512, 0, 0,
         0, 1, cCIN, cCIN, 1);
  };
  auto mixt = [&](const float* F, const short* W, float scale) {
    modemix_t_kernel<<<dim3(BG, cH), 512, 0, stream>>>(F, (const unsigned short*)W, Gtb, scale);
  };

  // ---- one-time setup ----
  basis_kernel<<<(M2 * cL) / 256, 256, 0, stream>>>(basisdb, basisib);
  pe_kernel<<<(cL * cDM) / 256, 256, 0, stream>>>(pe);
  prep_kernel<<<768, 256, 0, stream>>>(tok_W, dec_trW, p3W, p3b, Bpadb, Wtr3b, p3padb, p3bpadf);
  {
    CvtArgs ca;
    const float* srcs[NJOB] = {enc_Wq, enc_Wo, dsWq, dsWo, dcWq, dcWk, dcWo,
                               enc_c1W, enc_c2W, dec_c1W, dec_c2W, fb_enc, fb_dec, fc_w};
    short* dsts[NJOB] = {WqbE, WobE, dsWqb, dsWob, dcWqb, dcWkb, dcWob,
                         c1bE, c2bE, c1bD, c2bD, fbEb, fbDb, fcwb};
    int ns[NJOB] = {524288, 524288, 262144, 262144, 262144, 262144, 262144,
                    2097152, 2097152, 1048576, 1048576, (int)MIXW, (int)MIXW, (int)MIXW};
    for (int j = 0; j < NJOB; j++) {
      ca.src[j] = srcs[j];
      ca.dst[j] = dsts[j];
      ca.n[j] = ns[j];
    }
    cvtm_kernel<<<dim3(256, NJOB), 256, 0, stream>>>(ca);
  }

  for (int b0 = 0; b0 < cB; b0 += BG) {
    const float* xg = x_enc + (long)b0 * cL * cCIN;

    decompf(xg, TRD, GBL * cCIN, cCIN); // trend_init -> TRD (f32)
    winbuild_kernel<<<(int)(GBL * 32 / 256), 256, 0, stream>>>(xg, winb);
    mg(winb, Bpadb, nullptr, nullptr, nullptr, pe, nullptr, nullptr, Eb, (int)GBL, cDM, 128, 128,
       0, 0, 0, 1, 0, cDM, cDM, 0); // embedding -> Eb

    // ---- encoder ----
    for (int l = 0; l < 2; l++) {
      dft(Eb, FEb);
      modeproj(WqbE + (long)l * 262144, FEb, enc_bq + l * cDM, Fq, nullptr);
      mixt(Fq, fbEb, 1.0f);
      modeproj(WobE + (long)l * 262144, Gtb, nullptr, nullptr, Hb);
      idft(Hb, enc_bo + l * cDM, Eb, Yb);                     // x + attn -> Yb (bf16)
      decompb(Yb, Xb, nullptr, 0, GA, cDM);                   // h -> Xb
      ffn(Xb, Xb, Yb, c1bE + (long)l * 1048576, enc_c1b + l * cDFF, c2bE + (long)l * 1048576,
          enc_c2b + l * cDM);                                 // h + y -> Yb
      decompb(Yb, Eb, nullptr, 0, GA, cDM);                   // stream -> Eb
    }

    // ---- decoder ----
    dft(Eb, FEb);
    modeproj(dsWqb, FEb, dsbq, Fq, nullptr);
    mixt(Fq, fbDb, 1.0f);
    modeproj(dsWob, Gtb, nullptr, nullptr, Hb);
    idft(Hb, dsbo, Eb, Yb);                                   // x1 -> Yb
    decompb(Yb, Xb, Sb, 0, GA, cDM);                          // x2 -> Xb; ma -> Sb (fresh)
    dft(Xb, FXb);
    modeproj2(dcWqb, FXb, dcbq, Fq, dcWkb, FEb, dcbk, Fk);
    fused_cross_kernel<<<dim3(BG, cH), 1024, 0, stream>>>(Fq, Fk, (const unsigned short*)fcwb,
                                                          Gtb, 1.0f / (float)(cDM * cDM));
    modeproj(dcWob, Gtb, nullptr, nullptr, Hb);
    idft(Hb, dcbo, Xb, Yb);                                   // x3 -> Yb
    decompb(Yb, Ab, Sb, 1, GA, cDM);                          // x4 -> Ab; ma += Sb
    ffn(Ab, Ab, Yb, c1bD, dec_c1b, c2bD, dec_c2b);            // x4 + y -> Yb
    decompb(Yb, Xb, Sb, 1, GA, cDM);                          // x5 -> Xb; ma += Sb
    trendg(Sb);                                               // conv(t1+t2+t3)

    // ---- final projections ----
    mg64(Xb, p3padb, p3bpadf, TRD, nullptr, nullptr, O1, nullptr, (int)GBL, 64, cDM, cDM, 0, 0,
         0, 1, cCIN, cCIN, 0);                                // trend + x@p3
    gemm_kernel<<<dim3(1, (int)(GBL / 128)), 256, 0, stream>>>(O1, p1W, p1b, O2, (int)GBL, cCIN,
                                                               cCIN);
    p2_kernel<<<dim3(BG, 32), 256, 0, stream>>>(O2, p2W, p2b,
                                                (float*)d_out + (long)b0 * cPRED * cCIN);
  }
}

// Round 16
// 2101.129 us; speedup vs baseline: 2.0483x; 1.0394x over previous
//
#include <hip/hip_runtime.h>
#include <math.h>

namespace {

constexpr int cB = 32, cL = 1024, cCIN = 32, cDM = 512, cDFF = 2048;
constexpr int cH = 8, cE = 64, cM = 64, cPRED = 256;
constexpr int M2 = 2 * cM; // 128

typedef __attribute__((ext_vector_type(8))) short short8v;
typedef __attribute__((ext_vector_type(4))) float float4v;

__device__ inline unsigned short f2bf(float f) {
  unsigned int u = __builtin_bit_cast(unsigned int, f);
  u += 0x7FFFu + ((u >> 16) & 1u); // RNE
  return (unsigned short)(u >> 16);
}
__device__ inline float bf2f(unsigned short s) {
  return __builtin_bit_cast(float, (unsigned int)s << 16);
}

typedef const __attribute__((address_space(1))) unsigned int gu32_t;
typedef __attribute__((address_space(3))) unsigned int lu32_t;
__device__ inline void gld16(const void* g, void* l) {
  __builtin_amdgcn_global_load_lds((gu32_t*)g, (lu32_t*)l, 16, 0, 0);
}

// ================= one-time tables =================
__global__ void basis_kernel(short* __restrict__ basisdb, short* __restrict__ basisib) {
  int idx = blockIdx.x * 256 + threadIdx.x;
  if (idx >= M2 * cL) return;
  int t = idx & (cL - 1);
  int m2 = idx >> 10;
  int m = m2 >> 1;
  float ang = 6.2831853071795864f * (float)((m * t) & (cL - 1)) / (float)cL;
  float cv = cosf(ang), sv = sinf(ang);
  float vd = (m2 & 1) ? -sv : cv;
  basisdb[idx] = (short)f2bf(vd);
  float s = (m == 0) ? ((m2 & 1) ? 0.f : (1.f / (float)cL)) : (2.f / (float)cL);
  basisib[t * M2 + m2] = (short)f2bf(vd * s);
}

__global__ void pe_kernel(float* __restrict__ pe) {
  int idx = blockIdx.x * 256 + threadIdx.x;
  int o = idx & (cDM - 1), t = idx >> 9;
  int i = o >> 1;
  float freq = __expf((float)(2 * i) * (-9.210340371976184f / (float)cDM));
  float ang = freq * (float)t;
  pe[idx] = (o & 1) ? cosf(ang) : sinf(ang);
}

constexpr int NJOB = 14;
struct CvtArgs {
  const float* src[NJOB];
  short* dst[NJOB];
  int n[NJOB];
};
__global__ void cvtm_kernel(CvtArgs a) {
  int j = blockIdx.y;
  const float* s = a.src[j];
  short* d = a.dst[j];
  int n = a.n[j];
  for (int i = blockIdx.x * 256 + threadIdx.x; i < n; i += gridDim.x * 256)
    d[i] = (short)f2bf(s[i]);
}

// Bpadb[o][j*32+c]=tok_W[o][c][j]; Wtr3b[o][j*512+c]=trW[o][c][j] (o<32); p3padb; p3bpadf
__global__ void prep_kernel(const float* __restrict__ tok_W, const float* __restrict__ trW,
                            const float* __restrict__ p3W, const float* __restrict__ p3b,
                            short* __restrict__ Bpadb, short* __restrict__ Wtr3b,
                            short* __restrict__ p3padb, float* __restrict__ p3bpadf) {
  int idx = blockIdx.x * 256 + threadIdx.x;
  if (idx < 512 * 128) {
    int o = idx >> 7, s = idx & 127, j = s >> 5, c = s & 31;
    Bpadb[idx] = (j < 3) ? (short)f2bf(tok_W[o * 96 + c * 3 + j]) : (short)0;
  }
  if (idx < 128 * 1536) {
    int o = idx / 1536, r = idx % 1536, j = r >> 9, c = r & 511;
    Wtr3b[idx] = (o < 32) ? (short)f2bf(trW[(long)o * 1536 + c * 3 + j]) : (short)0;
  }
  if (idx < 128 * 512) {
    int o = idx >> 9, k = idx & 511;
    p3padb[idx] = (o < 32) ? (short)f2bf(p3W[o * 512 + k]) : (short)0;
  }
  if (idx < 128) p3bpadf[idx] = (idx < 32) ? p3b[idx] : 0.f;
}

// win[row][128] bf16 = [x[t-1,:], x[t,:], x[t+1,:], 0] circular
__global__ void winbuild_kernel(const float* __restrict__ x, short* __restrict__ win) {
  int idx = blockIdx.x * 256 + threadIdx.x;
  int s4 = idx & 31;
  int row = idx >> 5;
  int t = row & (cL - 1), b = row >> 10;
  int j = s4 >> 3, c4 = s4 & 7;
  unsigned int lo = 0, hi = 0;
  if (j < 3) {
    int ts = (t + j + cL - 1) & (cL - 1);
    float4 v = *(const float4*)&x[((long)b * cL + ts) * cCIN + c4 * 4];
    lo = (unsigned int)f2bf(v.x) | ((unsigned int)f2bf(v.y) << 16);
    hi = (unsigned int)f2bf(v.z) | ((unsigned int)f2bf(v.w) << 16);
  }
  *(uint2*)&win[row * 128 + s4 * 4] = make_uint2(lo, hi);
}

// batched bf16 transpose: in [B][1024][512] -> out [B][512][1024]
__global__ __launch_bounds__(256) void transpose_bf(const short* __restrict__ in,
                                                    short* __restrict__ out) {
  __shared__ short tile[32][33];
  int b = blockIdx.z;
  in += (long)b * cL * cDM;
  out += (long)b * cL * cDM;
  int c0 = blockIdx.x * 32, t0 = blockIdx.y * 32;
  int tx = threadIdx.x & 31, ty = threadIdx.x >> 5;
#pragma unroll
  for (int r = 0; r < 32; r += 8) tile[ty + r][tx] = in[(long)(t0 + ty + r) * cDM + c0 + tx];
  __syncthreads();
#pragma unroll
  for (int r = 0; r < 32; r += 8)
    out[(long)(c0 + ty + r) * cL + t0 + tx] = tile[tx][ty + r];
}

// ==== f32-input decomp (trend-init only): ma -> maf ====
__global__ void decomp_kernel(const float* __restrict__ x, float* __restrict__ maf, int n8,
                              int C) {
  int idx = blockIdx.x * 256 + threadIdx.x;
  if (idx >= n8) return;
  int c = idx % C;
  int u = idx / C;
  int t0 = (u & 127) * 8;
  int b = u >> 7;
  long base = (long)b * cL * C + c;
  float s = 0.f;
#pragma unroll
  for (int j = -12; j <= 12; j++) {
    int tt = t0 + j;
    tt = tt < 0 ? 0 : (tt >= cL ? cL - 1 : tt);
    s += x[base + (long)tt * C];
  }
#pragma unroll
  for (int k = 0; k < 8; k++) {
    int t = t0 + k;
    maf[base + (long)t * C] = s * (1.0f / 25.0f);
    int ta = t + 13;
    ta = ta >= cL ? cL - 1 : ta;
    int td = t - 12;
    td = td < 0 ? 0 : td;
    s += x[base + (long)ta * C] - x[base + (long)td * C];
  }
}

// ==== bf16-input decomp: seasonal bf16 + optional accumulated ma bf16 ====
__global__ void decompb_kernel(const short* __restrict__ x, short* __restrict__ sb,
                               short* __restrict__ mab, int maacc, int n8, int C) {
  int idx = blockIdx.x * 256 + threadIdx.x;
  if (idx >= n8) return;
  int c = idx % C;
  int u = idx / C;
  int t0 = (u & 127) * 8;
  int b = u >> 7;
  long base = (long)b * cL * C + c;
  float s = 0.f;
#pragma unroll
  for (int j = -12; j <= 12; j++) {
    int tt = t0 + j;
    tt = tt < 0 ? 0 : (tt >= cL ? cL - 1 : tt);
    s += bf2f((unsigned short)x[base + (long)tt * C]);
  }
#pragma unroll
  for (int k = 0; k < 8; k++) {
    int t = t0 + k;
    long e = base + (long)t * C;
    float ma = s * (1.0f / 25.0f);
    if (sb) sb[e] = (short)f2bf(bf2f((unsigned short)x[e]) - ma);
    if (mab) {
      float v = maacc ? bf2f((unsigned short)mab[e]) + ma : ma;
      mab[e] = (short)f2bf(v);
    }
    int ta = t + 13;
    ta = ta >= cL ? cL - 1 : ta;
    int td = t - 12;
    td = td < 0 ? 0 : td;
    s += bf2f((unsigned short)x[base + (long)ta * C]) - bf2f((unsigned short)x[base + (long)td * C]);
  }
}

// ================= final time projection =================
__global__ __launch_bounds__(256) void p2_kernel(const float* __restrict__ x,
                                                 const float* __restrict__ W,
                                                 const float* __restrict__ bias,
                                                 float* __restrict__ out) {
  __shared__ float tile[256 * 32];
  int b = blockIdx.x;
  int p0 = blockIdx.y * 8;
  int c = threadIdx.x & 31, pl = threadIdx.x >> 5;
  const float* xb = x + (long)b * cL * cCIN;
  const float* w = W + (long)(p0 + pl) * cL;
  float s = 0.f;
  for (int l0 = 0; l0 < cL; l0 += 256) {
    __syncthreads();
    for (int i = threadIdx.x; i < 256 * 32; i += 256) tile[i] = xb[(long)l0 * 32 + i];
    __syncthreads();
#pragma unroll 8
    for (int l = 0; l < 256; l++) s += tile[l * 32 + c] * w[l0 + l];
  }
  out[((long)b * cPRED + p0 + pl) * cCIN + c] = s + bias[p0 + pl];
}

// ====== per-(h,mode) complex mode mix; W bf16; 512 threads; transposed bf16 out ======
__global__ __launch_bounds__(512) void modemix_t_kernel(const float* __restrict__ F,
                                                        const unsigned short* __restrict__ W,
                                                        short* __restrict__ Gt, float scale) {
  int b = blockIdx.x, h = blockIdx.y;
  __shared__ float2 Fs[cE][cM];
  __shared__ short ot[128][72];
  const float* Fb = F + ((long)b * cDM + h * cE) * M2;
  for (int i = threadIdx.x; i < cE * cM; i += 512) {
    int e = i >> 6, x = i & 63;
    Fs[e][x] = ((const float2*)(Fb + (long)e * M2))[x];
  }
  __syncthreads();
  int x = threadIdx.x & 63, og = threadIdx.x >> 6; // og in [0,8)
  float2 acc[8];
#pragma unroll
  for (int i = 0; i < 8; i++) acc[i] = make_float2(0.f, 0.f);
  for (int e = 0; e < cE; e++) {
    float2 f = Fs[e][x];
#pragma unroll
    for (int i = 0; i < 8; i++) {
      int o = og * 8 + i;
      unsigned int wu = *(const unsigned int*)&W[((((long)h * cE + e) * cE + o) * cM + x) * 2];
      float wx = bf2f((unsigned short)wu), wy = bf2f((unsigned short)(wu >> 16));
      acc[i].x += f.x * wx - f.y * wy;
      acc[i].y += f.x * wy + f.y * wx;
    }
  }
#pragma unroll
  for (int i = 0; i < 8; i++) {
    int o = og * 8 + i;
    ot[2 * x][o] = (short)f2bf(acc[i].x * scale);
    ot[2 * x + 1][o] = (short)f2bf(acc[i].y * scale);
  }
  __syncthreads();
  short* gb = Gt + (long)b * (M2 * cDM) + h * cE;
  for (int u = threadIdx.x; u < 1024; u += 512) {
    int row = u >> 3, seg = u & 7;
    *(uint4*)&gb[(long)row * cDM + seg * 8] = *(const uint4*)&ot[row][seg * 8];
  }
}

// ====== fused cross attention (W bf16, 1024 threads, conflict-free LDS layouts) ======
__global__ __launch_bounds__(1024) void fused_cross_kernel(const float* __restrict__ Fq,
                                                           const float* __restrict__ Fk,
                                                           const unsigned short* __restrict__ W,
                                                           short* __restrict__ Gt, float scale) {
  __shared__ __align__(16) char smem[65536];
  float2(*KsT)[cE] = (float2(*)[cE])smem;            // [y][e]
  float2(*qks)[cM] = (float2(*)[cM])(smem + 32768);  // [y][x]
  int b = blockIdx.x, h = blockIdx.y;
  const float* kb = Fk + ((long)b * cDM + h * cE) * M2;
  for (int i = threadIdx.x; i < cE * cM; i += 1024) {
    int e = i >> 6, y = i & 63;
    KsT[y][e] = ((const float2*)(kb + (long)e * M2))[y];
  }
  __syncthreads();
  { // phase 1: qk[y][x] = tanh(sum_e q[e][x] * k[e][y]); 4 y per thread
    int x = threadIdx.x & 63, yg = threadIdx.x >> 6; // yg in [0,16)
    const float* qb = Fq + ((long)b * cDM + h * cE) * M2;
    float2 acc[4];
#pragma unroll
    for (int i = 0; i < 4; i++) acc[i] = make_float2(0.f, 0.f);
    for (int e = 0; e < cE; e++) {
      float2 q = ((const float2*)(qb + (long)e * M2))[x];
#pragma unroll
      for (int i = 0; i < 4; i++) {
        float2 k = KsT[yg * 4 + i][e];
        acc[i].x += q.x * k.x - q.y * k.y;
        acc[i].y += q.x * k.y + q.y * k.x;
      }
    }
#pragma unroll
    for (int i = 0; i < 4; i++) {
      int y = yg * 4 + i;
      float a = acc[i].x, bi = acc[i].y;
      float re, im;
      float t2a = 2.f * a;
      if (fabsf(t2a) > 60.f) {
        re = t2a > 0.f ? 1.f : -1.f;
        im = 0.f;
      } else {
        float denom = coshf(t2a) + cosf(2.f * bi);
        re = sinhf(t2a) / denom;
        im = sinf(2.f * bi) / denom;
      }
      qks[y][x] = make_float2(re, im);
    }
  }
  __syncthreads();
  // phase 2: qkv[e][x] = sum_y qk[y][x] * k[e][y]; 4 x per thread
  int e = threadIdx.x & 63, xg = threadIdx.x >> 6;
  float2 a2[4];
#pragma unroll
  for (int i = 0; i < 4; i++) a2[i] = make_float2(0.f, 0.f);
  for (int y = 0; y < cM; y++) {
    float2 k = KsT[y][e];
#pragma unroll
    for (int i = 0; i < 4; i++) {
      float2 qk = qks[y][xg * 4 + i];
      a2[i].x += qk.x * k.x - qk.y * k.y;
      a2[i].y += qk.x * k.y + qk.y * k.x;
    }
  }
  __syncthreads();
  float2(*Qv)[cM] = (float2(*)[cM])smem;
#pragma unroll
  for (int i = 0; i < 4; i++) Qv[e][xg * 4 + i] = a2[i];
  __syncthreads();
  { // phase 3: mix + transposed bf16 store; 4 o per thread
    int x = threadIdx.x & 63, og = threadIdx.x >> 6;
    float2 m[4];
#pragma unroll
    for (int i = 0; i < 4; i++) m[i] = make_float2(0.f, 0.f);
    for (int ee = 0; ee < cE; ee++) {
      float2 f = Qv[ee][x];
#pragma unroll
      for (int i = 0; i < 4; i++) {
        int o = og * 4 + i;
        unsigned int wu = *(const unsigned int*)&W[((((long)h * cE + ee) * cE + o) * cM + x) * 2];
        float wx = bf2f((unsigned short)wu), wy = bf2f((unsigned short)(wu >> 16));
        m[i].x += f.x * wx - f.y * wy;
        m[i].y += f.x * wy + f.y * wx;
      }
    }
    short(*ot)[72] = (short(*)[72])(smem + 32768);
#pragma unroll
    for (int i = 0; i < 4; i++) {
      int o = og * 4 + i;
      ot[2 * x][o] = (short)f2bf(m[i].x * scale);
      ot[2 * x + 1][o] = (short)f2bf(m[i].y * scale);
    }
    __syncthreads();
    short* gb = Gt + (long)b * (M2 * cDM) + h * cE;
    int u = threadIdx.x;
    {
      int row = u >> 3, seg = u & 7;
      *(uint4*)&gb[(long)row * cDM + seg * 8] =
          *(const uint4*)&((short(*)[72])(smem + 32768))[row][seg * 8];
    }
  }
}

// ================= f32 shader GEMM (tiny p1 only) =================
constexpr int GBM = 128, GBN = 128, GBK = 16, LPAD = 132;

__global__ __launch_bounds__(256) void gemm_kernel(const float* __restrict__ A,
                                                   const float* __restrict__ B,
                                                   const float* __restrict__ bias,
                                                   float* __restrict__ C, int M, int N, int K) {
  __shared__ float As[GBK][LPAD];
  __shared__ float Bs[GBK][LPAD];
  int n0 = blockIdx.x * GBN, m0 = blockIdx.y * GBM;
  int tid = threadIdx.x;
  int tx = tid & 15, ty = tid >> 4;
  float acc[8][8];
#pragma unroll
  for (int i = 0; i < 8; i++)
#pragma unroll
    for (int j = 0; j < 8; j++) acc[i][j] = 0.f;

  for (int k0 = 0; k0 < K; k0 += GBK) {
#pragma unroll
    for (int p = 0; p < 8; p++) {
      int i = p * 256 + tid;
      int mm = i >> 4, kk = i & 15;
      int gm = m0 + mm;
      As[kk][mm] = (gm < M && k0 + kk < K) ? A[(long)gm * K + k0 + kk] : 0.f;
    }
#pragma unroll
    for (int p = 0; p < 8; p++) {
      int i = p * 256 + tid;
      int nn = i >> 4, kk = i & 15;
      int gn = n0 + nn;
      Bs[kk][nn] = (gn < N && k0 + kk < K) ? B[(long)gn * K + k0 + kk] : 0.f;
    }
    __syncthreads();
#pragma unroll
    for (int kk = 0; kk < GBK; kk++) {
      float a[8], bb[8];
      *(float4*)&a[0] = *(const float4*)&As[kk][ty * 8];
      *(float4*)&a[4] = *(const float4*)&As[kk][ty * 8 + 4];
      *(float4*)&bb[0] = *(const float4*)&Bs[kk][tx * 8];
      *(float4*)&bb[4] = *(const float4*)&Bs[kk][tx * 8 + 4];
#pragma unroll
      for (int i = 0; i < 8; i++)
#pragma unroll
        for (int j = 0; j < 8; j++) acc[i][j] += a[i] * bb[j];
    }
    __syncthreads();
  }

  for (int i = 0; i < 8; i++) {
    int gm = m0 + ty * 8 + i;
    if (gm >= M) break;
    long rowoff = (long)gm * N;
    for (int j = 0; j < 8; j++) {
      int gn = n0 + tx * 8 + j;
      if (gn < N) C[rowoff + gn] = acc[i][j] + (bias ? bias[gn] : 0.f);
    }
  }
}

// ===== bf16 MFMA GEMM 256x128 tile, 512 threads / 8 waves (ffn + embedding) =====
// Same single-buffer structure/swizzle/XCD remap as the 128^2 kernel; wave (wm,wn) in 4x2.
__global__ __launch_bounds__(512) void mfma_gemm256(
    const short* __restrict__ A, const short* __restrict__ B, const float* __restrict__ bias,
    const short* __restrict__ addendb, const float* __restrict__ pe, float* __restrict__ Cf,
    short* __restrict__ Cb, int M, int N, int K, int lda, int relu, int ldc) {
  __shared__ __align__(16) short As[16384]; // 256 x 64
  __shared__ __align__(16) short Bs[8192];  // 128 x 64
  int nwg = gridDim.x * gridDim.y;
  int orig = blockIdx.x + gridDim.x * blockIdx.y;
  int q = nwg >> 3, r = nwg & 7;
  int xcd = orig & 7, ii = orig >> 3;
  int flat = (xcd < r ? xcd * (q + 1) : r * (q + 1) + (xcd - r) * q) + ii;
  int bx = flat % (int)gridDim.x;
  int by = flat / (int)gridDim.x;

  int n0 = bx * 128, m0 = by * 256;
  int tid = threadIdx.x;
  int lane = tid & 63;
  int w = tid >> 6;       // 0..7
  int wm = w >> 1;        // 0..3 (M quadrant)
  int wn = w & 1;         // 0..1 (N quadrant)
  int lr = lane & 15, lg = lane >> 4;
  int lrow = lane >> 3;
  int scol = ((lane & 7) * 8) ^ (lrow << 3);

  float4v acc[4][4];
#pragma unroll
  for (int i = 0; i < 4; i++)
#pragma unroll
    for (int j = 0; j < 4; j++) acc[i][j] = (float4v){0.f, 0.f, 0.f, 0.f};

  int nk = K >> 6;
  int swr = (lr & 7) << 3;
  for (int t = 0; t < nk; ++t) {
    int k0 = t << 6;
#pragma unroll
    for (int j = 0; j < 4; j++) { // A: 32 segments x 8 rows
      int seg = w * 4 + j;
      int row = seg * 8 + lrow;
      gld16(A + (long)(m0 + row) * lda + k0 + scol, &As[seg * 512]);
    }
#pragma unroll
    for (int j = 0; j < 2; j++) { // B: 16 segments x 8 rows
      int seg = w * 2 + j;
      int row = seg * 8 + lrow;
      gld16(B + (long)(n0 + row) * K + k0 + scol, &Bs[seg * 512]);
    }
    asm volatile("s_waitcnt vmcnt(0)" ::: "memory");
    __syncthreads();
#pragma unroll
    for (int ks = 0; ks < 2; ks++) {
      short8v af[4], bfr[4];
#pragma unroll
      for (int mi = 0; mi < 4; mi++)
        af[mi] = *(const short8v*)&As[(wm * 64 + mi * 16 + lr) * 64 + ((ks * 32 + lg * 8) ^ swr)];
#pragma unroll
      for (int ni = 0; ni < 4; ni++)
        bfr[ni] = *(const short8v*)&Bs[(wn * 64 + ni * 16 + lr) * 64 + ((ks * 32 + lg * 8) ^ swr)];
#pragma unroll
      for (int mi = 0; mi < 4; mi++)
#pragma unroll
        for (int ni = 0; ni < 4; ni++)
          acc[mi][ni] =
              __builtin_amdgcn_mfma_f32_16x16x32_bf16(af[mi], bfr[ni], acc[mi][ni], 0, 0, 0);
    }
    __syncthreads();
  }

#pragma unroll
  for (int mi = 0; mi < 4; mi++) {
#pragma unroll
    for (int i = 0; i < 4; i++) {
      int gr = m0 + wm * 64 + mi * 16 + lg * 4 + i;
      long rowoff = (long)gr * ldc;
#pragma unroll
      for (int ni = 0; ni < 4; ni++) {
        int gc = n0 + wn * 64 + ni * 16 + lr;
        float v = acc[mi][ni][i];
        if (bias) v += bias[gc];
        if (pe) v += pe[((gr & (cL - 1)) << 9) + gc];
        if (addendb) v += bf2f((unsigned short)addendb[rowoff + gc]);
        if (relu) v = fmaxf(v, 0.f);
        if (Cf) Cf[rowoff + gc] = v;
        if (Cb) Cb[rowoff + gc] = (short)f2bf(v);
      }
    }
  }
}

// ===== bf16 MFMA GEMM 64x64 (small/latency-bound shapes; full epilogue; zsplit) =====
__global__ __launch_bounds__(256) void mfma_gemm64(
    const short* __restrict__ A, const short* __restrict__ B, const float* __restrict__ bias,
    const float* __restrict__ addf, const short* __restrict__ addb,
    const float* __restrict__ m0b, float* __restrict__ Cf, short* __restrict__ Cb, int M, int N,
    int K, int lda, long sA, long sB, long sC, int Nreal, int ldc, int amode,
    const short* __restrict__ A2, const short* __restrict__ B2, const float* __restrict__ m0b2,
    float* __restrict__ Cf2, int zsplit) {
  __shared__ __align__(16) short As[4096];
  __shared__ __align__(16) short Bs[4096];
  int nwg = gridDim.x * gridDim.y * gridDim.z;
  int orig = blockIdx.x + gridDim.x * (blockIdx.y + gridDim.y * blockIdx.z);
  int q = nwg >> 3, r = nwg & 7;
  int xcd = orig & 7, ii = orig >> 3;
  int flat = (xcd < r ? xcd * (q + 1) : r * (q + 1) + (xcd - r) * q) + ii;
  int bx = flat % (int)gridDim.x;
  int tmp = flat / (int)gridDim.x;
  int by = tmp % (int)gridDim.y;
  int bz = tmp / (int)gridDim.y;

  int z = bz;
  if (zsplit > 0 && bz >= zsplit) {
    A = A2;
    B = B2;
    m0b = m0b2;
    Cf = Cf2;
    z = bz - zsplit;
  }
  A += (long)z * sA;
  B += (long)z * sB;
  if (Cf) Cf += (long)z * sC;
  if (Cb) Cb += (long)z * sC;
  const float* Ad = addf ? addf + (long)z * sC : nullptr;
  const short* Adb = addb ? addb + (long)z * sC : nullptr;
  int n0 = bx * 64, m0 = by * 64;
  int tid = threadIdx.x;
  int lane = tid & 63;
  int w = tid >> 6;
  int wm = w & 1, wn = w >> 1;
  int lr = lane & 15, lg = lane >> 4;
  int lrow = lane >> 3;
  int scol = ((lane & 7) * 8) ^ (lrow << 3);

  float4v acc[2][2];
#pragma unroll
  for (int i = 0; i < 2; i++)
#pragma unroll
    for (int j = 0; j < 2; j++) acc[i][j] = (float4v){0.f, 0.f, 0.f, 0.f};

  int nk = K >> 6;
  int swr = (lr & 7) << 3;
  for (int t = 0; t < nk; ++t) {
    int k0 = t << 6;
#pragma unroll
    for (int j = 0; j < 2; j++) {
      int seg = w * 2 + j;
      int row = seg * 8 + lrow;
      const short* ga;
      if (amode == 0) {
        ga = A + (long)(m0 + row) * lda + k0 + scol;
      } else {
        int r2 = m0 + row;
        int bb = r2 >> 10, tt = r2 & 1023;
        int jj = k0 >> 9, c0 = k0 & 511;
        ga = A + ((((long)(bb << 10)) | ((tt + jj + 1023) & 1023)) << 9) + c0 + scol;
      }
      gld16(ga, &As[seg * 512]);
      gld16(B + (long)(n0 + row) * K + k0 + scol, &Bs[seg * 512]);
    }
    asm volatile("s_waitcnt vmcnt(0)" ::: "memory");
    __syncthreads();
#pragma unroll
    for (int ks = 0; ks < 2; ks++) {
      short8v af[2], bfr[2];
#pragma unroll
      for (int mi = 0; mi < 2; mi++)
        af[mi] = *(const short8v*)&As[(wm * 32 + mi * 16 + lr) * 64 + ((ks * 32 + lg * 8) ^ swr)];
#pragma unroll
      for (int ni = 0; ni < 2; ni++)
        bfr[ni] = *(const short8v*)&Bs[(wn * 32 + ni * 16 + lr) * 64 + ((ks * 32 + lg * 8) ^ swr)];
#pragma unroll
      for (int mi = 0; mi < 2; mi++)
#pragma unroll
        for (int ni = 0; ni < 2; ni++)
          acc[mi][ni] =
              __builtin_amdgcn_mfma_f32_16x16x32_bf16(af[mi], bfr[ni], acc[mi][ni], 0, 0, 0);
    }
    __syncthreads();
  }

#pragma unroll
  for (int mi = 0; mi < 2; mi++) {
#pragma unroll
    for (int i = 0; i < 4; i++) {
      int gr = m0 + wm * 32 + mi * 16 + lg * 4 + i;
      long rowoff = (long)gr * ldc;
#pragma unroll
      for (int ni = 0; ni < 2; ni++) {
        int gc = n0 + wn * 32 + ni * 16 + lr;
        if (gc < Nreal) {
          float v = acc[mi][ni][i];
          if (bias) v += bias[gc];
          if (m0b && gc == 0) v += 1024.f * m0b[gr];
          if (Ad) v += Ad[rowoff + gc];
          if (Adb) v += bf2f((unsigned short)Adb[rowoff + gc]);
          if (Cf) Cf[rowoff + gc] = v;
          if (Cb) Cb[rowoff + gc] = (short)f2bf(v);
        }
      }
    }
  }
}

} // namespace

extern "C" void kernel_launch(void* const* d_in, const int* in_sizes, int n_in, void* d_out,
                              int out_size, void* d_ws, size_t ws_size, hipStream_t stream) {
  const float* x_enc = (const float*)d_in[0];
  const float* tok_W = (const float*)d_in[1];
  const float* enc_Wq = (const float*)d_in[2];
  const float* enc_Wo = (const float*)d_in[5];
  const float* enc_bq = (const float*)d_in[6];
  const float* enc_bo = (const float*)d_in[9];
  const float* dsWq = (const float*)d_in[10];
  const float* dsWo = (const float*)d_in[13];
  const float* dsbq = (const float*)d_in[14];
  const float* dsbo = (const float*)d_in[17];
  const float* dcWq = (const float*)d_in[18];
  const float* dcWk = (const float*)d_in[19];
  const float* dcWo = (const float*)d_in[21];
  const float* dcbq = (const float*)d_in[22];
  const float* dcbk = (const float*)d_in[23];
  const float* dcbo = (const float*)d_in[25];
  const float* enc_c1W = (const float*)d_in[26];
  const float* enc_c1b = (const float*)d_in[27];
  const float* enc_c2W = (const float*)d_in[28];
  const float* enc_c2b = (const float*)d_in[29];
  const float* dec_c1W = (const float*)d_in[30];
  const float* dec_c1b = (const float*)d_in[31];
  const float* dec_c2W = (const float*)d_in[32];
  const float* dec_c2b = (const float*)d_in[33];
  const float* dec_trW = (const float*)d_in[34];
  const float* fb_enc = (const float*)d_in[35];
  const float* fb_dec = (const float*)d_in[36];
  const float* fc_w = (const float*)d_in[37];
  const float* p1W = (const float*)d_in[38];
  const float* p1b = (const float*)d_in[39];
  const float* p2W = (const float*)d_in[40];
  const float* p2b = (const float*)d_in[41];
  const float* p3W = (const float*)d_in[42];
  const float* p3b = (const float*)d_in[43];

  constexpr long MIXW = 8L * 64 * 64 * 64 * 2;

  // ---- layout sizing (dry-run) ----
  auto layout_bytes = [&](long BG, long RH) -> size_t {
    size_t t = 0;
    auto add = [&](size_t b) { t = (t + b + 255) & ~(size_t)255; };
    add(2 * 262144 * 2); add(2 * 262144 * 2);
    add(262144 * 2); add(262144 * 2); add(262144 * 2); add(262144 * 2); add(262144 * 2);
    add(2 * 1048576 * 2); add(2 * 1048576 * 2); add(1048576 * 2); add(1048576 * 2);
    add(131072 * 2); add(131072 * 2); add(65536 * 2); add(196608 * 2); add(65536 * 2);
    add(128 * 4); add(524288 * 4);
    add(MIXW * 2); add(MIXW * 2); add(MIXW * 2);
    long GA = BG * cL * cDM;
    add(GA * 2); add(GA * 2); add(GA * 2); add(GA * 2); add(GA * 2); // Eb Xb Ab Sb Yb
    add(BG * cL * 128 * 2);
    size_t ub = (size_t)GA * 2;
    size_t hd = (size_t)RH * cDFF * 2;
    add(ub > hd ? ub : hd);
    add(BG * 65536 * 4); add(BG * 65536 * 4);
    add(BG * 65536 * 2); add(BG * 65536 * 2); add(BG * 65536 * 2); add(BG * 65536 * 2);
    add(BG * cL * cCIN * 4); add(BG * cL * cCIN * 4); add(BG * cL * cCIN * 4);
    return t;
  };
  int BG = cB;
  while (BG > 1 && layout_bytes(BG, 512) > ws_size) BG >>= 1;
  long RH = (long)BG * cL;
  while (RH > 512 && layout_bytes(BG, RH) > ws_size) RH >>= 1;

  long GBL = (long)BG * cL;
  char* base = (char*)d_ws;
  size_t off = 0;
  auto alloc = [&](size_t bytes) -> void* {
    void* p = base + off;
    off = (off + bytes + 255) & ~(size_t)255;
    return p;
  };
  short* WqbE = (short*)alloc(2 * 262144 * 2);
  short* WobE = (short*)alloc(2 * 262144 * 2);
  short* dsWqb = (short*)alloc(262144 * 2);
  short* dsWob = (short*)alloc(262144 * 2);
  short* dcWqb = (short*)alloc(262144 * 2);
  short* dcWkb = (short*)alloc(262144 * 2);
  short* dcWob = (short*)alloc(262144 * 2);
  short* c1bE = (short*)alloc(2 * 1048576 * 2);
  short* c2bE = (short*)alloc(2 * 1048576 * 2);
  short* c1bD = (short*)alloc(1048576 * 2);
  short* c2bD = (short*)alloc(1048576 * 2);
  short* basisdb = (short*)alloc(131072 * 2);
  short* basisib = (short*)alloc(131072 * 2);
  short* Bpadb = (short*)alloc(65536 * 2);
  short* Wtr3b = (short*)alloc(196608 * 2);
  short* p3padb = (short*)alloc(65536 * 2);
  float* p3bpadf = (float*)alloc(128 * 4);
  float* pe = (float*)alloc(524288 * 4);
  short* fbEb = (short*)alloc(MIXW * 2);
  short* fbDb = (short*)alloc(MIXW * 2);
  short* fcwb = (short*)alloc(MIXW * 2);
  long GA = GBL * cDM;
  short* Eb = (short*)alloc(GA * 2);
  short* Xb = (short*)alloc(GA * 2);
  short* Ab = (short*)alloc(GA * 2);
  short* Sb = (short*)alloc(GA * 2);
  short* Yb = (short*)alloc(GA * 2);
  short* winb = (short*)alloc(GBL * 128 * 2);
  size_t ubsz = (size_t)GA * 2;
  size_t hdsz = (size_t)RH * cDFF * 2;
  short* UB = (short*)alloc(ubsz > hdsz ? ubsz : hdsz);
  short* Tb = UB;
  short* HDb = UB;
  float* Fq = (float*)alloc((size_t)BG * 65536 * 4);
  float* Fk = (float*)alloc((size_t)BG * 65536 * 4);
  short* FEb = (short*)alloc((size_t)BG * 65536 * 2);
  short* FXb = (short*)alloc((size_t)BG * 65536 * 2);
  short* Gtb = (short*)alloc((size_t)BG * 65536 * 2);
  short* Hb = (short*)alloc((size_t)BG * 65536 * 2);
  float* TRD = (float*)alloc(GBL * cCIN * 4);
  float* O1 = (float*)alloc(GBL * cCIN * 4);
  float* O2 = (float*)alloc(GBL * cCIN * 4);

  auto mg256 = [&](const short* Am, const short* Bm, const float* bias, const short* adb,
                   const float* peA, float* Cf, short* Cb, int Mm, int Nn, int Kk, int lda,
                   int relu, int ldc) {
    dim3 g(Nn / 128, Mm / 256);
    mfma_gemm256<<<g, 512, 0, stream>>>(Am, Bm, bias, adb, peA, Cf, Cb, Mm, Nn, Kk, lda, relu,
                                        ldc);
  };
  auto mg64 = [&](const short* Am, const short* Bm, const float* bias, const float* addf,
                  const short* addb, const float* m0b, float* Cf, short* Cb, int Mm, int Nn,
                  int Kk, int lda, long sA, long sB, long sC, int batch, int Nreal, int ldc,
                  int amode) {
    dim3 g(Nn / 64, Mm / 64, batch);
    mfma_gemm64<<<g, 256, 0, stream>>>(Am, Bm, bias, addf, addb, m0b, Cf, Cb, Mm, Nn, Kk, lda,
                                       sA, sB, sC, Nreal, ldc, amode, nullptr, nullptr, nullptr,
                                       nullptr, 0);
  };
  auto decompf = [&](const float* x, float* maf, long total, int C_) {
    int n8 = (int)(total / 8);
    decomp_kernel<<<(n8 + 255) / 256, 256, 0, stream>>>(x, maf, n8, C_);
  };
  auto decompb = [&](const short* x, short* sb, short* mab, int maacc, long total, int C_) {
    int n8 = (int)(total / 8);
    decompb_kernel<<<(n8 + 255) / 256, 256, 0, stream>>>(x, sb, mab, maacc, n8, C_);
  };
  auto dft = [&](const short* srcb, short* Fout) {
    transpose_bf<<<dim3(16, 32, BG), 256, 0, stream>>>(srcb, Tb);
    mg64(basisdb, Tb, nullptr, nullptr, nullptr, nullptr, nullptr, Fout, M2, cDM, cL, cL, 0,
         (long)cDM * cL, 65536, BG, cDM, cDM, 0);
  };
  auto modeproj = [&](const short* Wb, const short* Fin, const float* m0b, float* Cf, short* Cb) {
    mg64(Wb, Fin, nullptr, nullptr, nullptr, m0b, Cf, Cb, cDM, M2, cDM, cDM, 0, 65536, 65536, BG,
         M2, M2, 0);
  };
  auto modeproj2 = [&](const short* Wa, const short* Fa, const float* ba, float* Ca,
                       const short* Wb2, const short* Fb2, const float* bb2, float* Cb2) {
    dim3 g(M2 / 64, cDM / 64, 2 * BG);
    mfma_gemm64<<<g, 256, 0, stream>>>(Wa, Fa, nullptr, nullptr, nullptr, ba, Ca, nullptr, cDM,
                                       M2, cDM, cDM, 0, 65536, 65536, M2, M2, 0, Wb2, Fb2, bb2,
                                       Cb2, BG);
  };
  auto idft = [&](const short* Hin, const float* bias, const short* adb, short* Cbout) {
    mg64(basisib, Hin, bias, nullptr, adb, nullptr, nullptr, Cbout, cL, cDM, M2, M2, 0, 65536,
         (long)cL * cDM, BG, cDM, cDM, 0);
  };
  auto ffn = [&](const short* inb, const short* addb, short* outb, const short* c1w,
                 const float* c1bias, const short* c2w, const float* c2bias) {
    for (long r = 0; r < GBL; r += RH) {
      mg256(inb + r * cDM, c1w, c1bias, nullptr, nullptr, nullptr, HDb, (int)RH, cDFF, cDM, cDM,
            1, cDFF);
      mg256(HDb, c2w, c2bias, addb + r * cDM, nullptr, nullptr, outb + r * cDM, (int)RH, cDM,
            cDFF, cDFF, 0, cDM);
    }
  };
  auto trendg = [&](const short* mab) {
    mg64(mab, Wtr3b, nullptr, TRD, nullptr, nullptr, TRD, nullptr, (int)GBL, 64, 1536, 512, 0, 0,
         0, 1, cCIN, cCIN, 1);
  };
  auto mixt = [&](const float* F, const short* W, float scale) {
    modemix_t_kernel<<<dim3(BG, cH), 512, 0, stream>>>(F, (const unsigned short*)W, Gtb, scale);
  };

  // ---- one-time setup ----
  basis_kernel<<<(M2 * cL) / 256, 256, 0, stream>>>(basisdb, basisib);
  pe_kernel<<<(cL * cDM) / 256, 256, 0, stream>>>(pe);
  prep_kernel<<<768, 256, 0, stream>>>(tok_W, dec_trW, p3W, p3b, Bpadb, Wtr3b, p3padb, p3bpadf);
  {
    CvtArgs ca;
    const float* srcs[NJOB] = {enc_Wq, enc_Wo, dsWq, dsWo, dcWq, dcWk, dcWo,
                               enc_c1W, enc_c2W, dec_c1W, dec_c2W, fb_enc, fb_dec, fc_w};
    short* dsts[NJOB] = {WqbE, WobE, dsWqb, dsWob, dcWqb, dcWkb, dcWob,
                         c1bE, c2bE, c1bD, c2bD, fbEb, fbDb, fcwb};
    int ns[NJOB] = {524288, 524288, 262144, 262144, 262144, 262144, 262144,
                    2097152, 2097152, 1048576, 1048576, (int)MIXW, (int)MIXW, (int)MIXW};
    for (int j = 0; j < NJOB; j++) {
      ca.src[j] = srcs[j];
      ca.dst[j] = dsts[j];
      ca.n[j] = ns[j];
    }
    cvtm_kernel<<<dim3(256, NJOB), 256, 0, stream>>>(ca);
  }

  for (int b0 = 0; b0 < cB; b0 += BG) {
    const float* xg = x_enc + (long)b0 * cL * cCIN;

    decompf(xg, TRD, GBL * cCIN, cCIN); // trend_init -> TRD (f32)
    winbuild_kernel<<<(int)(GBL * 32 / 256), 256, 0, stream>>>(xg, winb);
    mg256(winb, Bpadb, nullptr, nullptr, pe, nullptr, Eb, (int)GBL, cDM, 128, 128, 0, cDM);

    // ---- encoder ----
    for (int l = 0; l < 2; l++) {
      dft(Eb, FEb);
      modeproj(WqbE + (long)l * 262144, FEb, enc_bq + l * cDM, Fq, nullptr);
      mixt(Fq, fbEb, 1.0f);
      modeproj(WobE + (long)l * 262144, Gtb, nullptr, nullptr, Hb);
      idft(Hb, enc_bo + l * cDM, Eb, Yb);                     // x + attn -> Yb (bf16)
      decompb(Yb, Xb, nullptr, 0, GA, cDM);                   // h -> Xb
      ffn(Xb, Xb, Yb, c1bE + (long)l * 1048576, enc_c1b + l * cDFF, c2bE + (long)l * 1048576,
          enc_c2b + l * cDM);                                 // h + y -> Yb
      decompb(Yb, Eb, nullptr, 0, GA, cDM);                   // stream -> Eb
    }

    // ---- decoder ----
    dft(Eb, FEb);
    modeproj(dsWqb, FEb, dsbq, Fq, nullptr);
    mixt(Fq, fbDb, 1.0f);
    modeproj(dsWob, Gtb, nullptr, nullptr, Hb);
    idft(Hb, dsbo, Eb, Yb);                                   // x1 -> Yb
    decompb(Yb, Xb, Sb, 0, GA, cDM);                          // x2 -> Xb; ma -> Sb (fresh)
    dft(Xb, FXb);
    modeproj2(dcWqb, FXb, dcbq, Fq, dcWkb, FEb, dcbk, Fk);
    fused_cross_kernel<<<dim3(BG, cH), 1024, 0, stream>>>(Fq, Fk, (const unsigned short*)fcwb,
                                                          Gtb, 1.0f / (float)(cDM * cDM));
    modeproj(dcWob, Gtb, nullptr, nullptr, Hb);
    idft(Hb, dcbo, Xb, Yb);                                   // x3 -> Yb
    decompb(Yb, Ab, Sb, 1, GA, cDM);                          // x4 -> Ab; ma += Sb
    ffn(Ab, Ab, Yb, c1bD, dec_c1b, c2bD, dec_c2b);            // x4 + y -> Yb
    decompb(Yb, Xb, Sb, 1, GA, cDM);                          // x5 -> Xb; ma += Sb
    trendg(Sb);                                               // conv(t1+t2+t3)

    // ---- final projections ----
    mg64(Xb, p3padb, p3bpadf, TRD, nullptr, nullptr, O1, nullptr, (int)GBL, 64, cDM, cDM, 0, 0,
         0, 1, cCIN, cCIN, 0);                                // trend + x@p3
    gemm_kernel<<<dim3(1, (int)(GBL / 128)), 256, 0, stream>>>(O1, p1W, p1b, O2, (int)GBL, cCIN,
                                                               cCIN);
    p2_kernel<<<dim3(BG, 32), 256, 0, stream>>>(O2, p2W, p2b,
                                                (float*)d_out + (long)b0 * cPRED * cCIN);
  }
}

// Round 17
// 2078.553 us; speedup vs baseline: 2.0706x; 1.0109x over previous
//
#include <hip/hip_runtime.h>
#include <math.h>

namespace {

constexpr int cB = 32, cL = 1024, cCIN = 32, cDM = 512, cDFF = 2048;
constexpr int cH = 8, cE = 64, cM = 64, cPRED = 256;
constexpr int M2 = 2 * cM; // 128

typedef __attribute__((ext_vector_type(8))) short short8v;
typedef __attribute__((ext_vector_type(4))) float float4v;

__device__ inline unsigned short f2bf(float f) {
  unsigned int u = __builtin_bit_cast(unsigned int, f);
  u += 0x7FFFu + ((u >> 16) & 1u); // RNE
  return (unsigned short)(u >> 16);
}
__device__ inline float bf2f(unsigned short s) {
  return __builtin_bit_cast(float, (unsigned int)s << 16);
}

typedef const __attribute__((address_space(1))) unsigned int gu32_t;
typedef __attribute__((address_space(3))) unsigned int lu32_t;
__device__ inline void gld16(const void* g, void* l) {
  __builtin_amdgcn_global_load_lds((gu32_t*)g, (lu32_t*)l, 16, 0, 0);
}

// ================= one-time tables =================
__global__ void basis_kernel(short* __restrict__ basisdb, short* __restrict__ basisib) {
  int idx = blockIdx.x * 256 + threadIdx.x;
  if (idx >= M2 * cL) return;
  int t = idx & (cL - 1);
  int m2 = idx >> 10;
  int m = m2 >> 1;
  float ang = 6.2831853071795864f * (float)((m * t) & (cL - 1)) / (float)cL;
  float cv = cosf(ang), sv = sinf(ang);
  float vd = (m2 & 1) ? -sv : cv;
  basisdb[idx] = (short)f2bf(vd);
  float s = (m == 0) ? ((m2 & 1) ? 0.f : (1.f / (float)cL)) : (2.f / (float)cL);
  basisib[t * M2 + m2] = (short)f2bf(vd * s);
}

__global__ void pe_kernel(float* __restrict__ pe) {
  int idx = blockIdx.x * 256 + threadIdx.x;
  int o = idx & (cDM - 1), t = idx >> 9;
  int i = o >> 1;
  float freq = __expf((float)(2 * i) * (-9.210340371976184f / (float)cDM));
  float ang = freq * (float)t;
  pe[idx] = (o & 1) ? cosf(ang) : sinf(ang);
}

constexpr int NJOB = 14;
struct CvtArgs {
  const float* src[NJOB];
  short* dst[NJOB];
  int n[NJOB];
};
__global__ void cvtm_kernel(CvtArgs a) {
  int j = blockIdx.y;
  const float* s = a.src[j];
  short* d = a.dst[j];
  int n = a.n[j];
  for (int i = blockIdx.x * 256 + threadIdx.x; i < n; i += gridDim.x * 256)
    d[i] = (short)f2bf(s[i]);
}

// Bpadb[o][j*32+c]=tok_W[o][c][j]; Wtr3b[o][j*512+c]=trW[o][c][j] (o<32); p3padb; p3bpadf
__global__ void prep_kernel(const float* __restrict__ tok_W, const float* __restrict__ trW,
                            const float* __restrict__ p3W, const float* __restrict__ p3b,
                            short* __restrict__ Bpadb, short* __restrict__ Wtr3b,
                            short* __restrict__ p3padb, float* __restrict__ p3bpadf) {
  int idx = blockIdx.x * 256 + threadIdx.x;
  if (idx < 512 * 128) {
    int o = idx >> 7, s = idx & 127, j = s >> 5, c = s & 31;
    Bpadb[idx] = (j < 3) ? (short)f2bf(tok_W[o * 96 + c * 3 + j]) : (short)0;
  }
  if (idx < 128 * 1536) {
    int o = idx / 1536, r = idx % 1536, j = r >> 9, c = r & 511;
    Wtr3b[idx] = (o < 32) ? (short)f2bf(trW[(long)o * 1536 + c * 3 + j]) : (short)0;
  }
  if (idx < 128 * 512) {
    int o = idx >> 9, k = idx & 511;
    p3padb[idx] = (o < 32) ? (short)f2bf(p3W[o * 512 + k]) : (short)0;
  }
  if (idx < 128) p3bpadf[idx] = (idx < 32) ? p3b[idx] : 0.f;
}

// win[row][128] bf16 = [x[t-1,:], x[t,:], x[t+1,:], 0] circular
__global__ void winbuild_kernel(const float* __restrict__ x, short* __restrict__ win) {
  int idx = blockIdx.x * 256 + threadIdx.x;
  int s4 = idx & 31;
  int row = idx >> 5;
  int t = row & (cL - 1), b = row >> 10;
  int j = s4 >> 3, c4 = s4 & 7;
  unsigned int lo = 0, hi = 0;
  if (j < 3) {
    int ts = (t + j + cL - 1) & (cL - 1);
    float4 v = *(const float4*)&x[((long)b * cL + ts) * cCIN + c4 * 4];
    lo = (unsigned int)f2bf(v.x) | ((unsigned int)f2bf(v.y) << 16);
    hi = (unsigned int)f2bf(v.z) | ((unsigned int)f2bf(v.w) << 16);
  }
  *(uint2*)&win[row * 128 + s4 * 4] = make_uint2(lo, hi);
}

// batched bf16 transpose, 64x64 tiles: in [B][1024][512] -> out [B][512][1024]
__global__ __launch_bounds__(256) void transpose_bf(const short* __restrict__ in,
                                                    short* __restrict__ out) {
  __shared__ short tile[64][65];
  int b = blockIdx.z;
  in += (long)b * cL * cDM;
  out += (long)b * cL * cDM;
  int c0 = blockIdx.x * 64, t0 = blockIdx.y * 64;
  int tx = threadIdx.x & 63, ty = threadIdx.x >> 6;
#pragma unroll
  for (int r = 0; r < 64; r += 4) tile[ty + r][tx] = in[(long)(t0 + ty + r) * cDM + c0 + tx];
  __syncthreads();
#pragma unroll
  for (int r = 0; r < 64; r += 4)
    out[(long)(c0 + ty + r) * cL + t0 + tx] = tile[tx][ty + r];
}

// ==== f32-input decomp (trend-init only): ma -> maf ====
__global__ void decomp_kernel(const float* __restrict__ x, float* __restrict__ maf, int n8,
                              int C) {
  int idx = blockIdx.x * 256 + threadIdx.x;
  if (idx >= n8) return;
  int c = idx % C;
  int u = idx / C;
  int t0 = (u & 127) * 8;
  int b = u >> 7;
  long base = (long)b * cL * C + c;
  float s = 0.f;
#pragma unroll
  for (int j = -12; j <= 12; j++) {
    int tt = t0 + j;
    tt = tt < 0 ? 0 : (tt >= cL ? cL - 1 : tt);
    s += x[base + (long)tt * C];
  }
#pragma unroll
  for (int k = 0; k < 8; k++) {
    int t = t0 + k;
    maf[base + (long)t * C] = s * (1.0f / 25.0f);
    int ta = t + 13;
    ta = ta >= cL ? cL - 1 : ta;
    int td = t - 12;
    td = td < 0 ? 0 : td;
    s += x[base + (long)ta * C] - x[base + (long)td * C];
  }
}

// ==== bf16-input decomp: seasonal bf16 + optional accumulated ma bf16 ====
__global__ void decompb_kernel(const short* __restrict__ x, short* __restrict__ sb,
                               short* __restrict__ mab, int maacc, int n8, int C) {
  int idx = blockIdx.x * 256 + threadIdx.x;
  if (idx >= n8) return;
  int c = idx % C;
  int u = idx / C;
  int t0 = (u & 127) * 8;
  int b = u >> 7;
  long base = (long)b * cL * C + c;
  float s = 0.f;
#pragma unroll
  for (int j = -12; j <= 12; j++) {
    int tt = t0 + j;
    tt = tt < 0 ? 0 : (tt >= cL ? cL - 1 : tt);
    s += bf2f((unsigned short)x[base + (long)tt * C]);
  }
#pragma unroll
  for (int k = 0; k < 8; k++) {
    int t = t0 + k;
    long e = base + (long)t * C;
    float ma = s * (1.0f / 25.0f);
    if (sb) sb[e] = (short)f2bf(bf2f((unsigned short)x[e]) - ma);
    if (mab) {
      float v = maacc ? bf2f((unsigned short)mab[e]) + ma : ma;
      mab[e] = (short)f2bf(v);
    }
    int ta = t + 13;
    ta = ta >= cL ? cL - 1 : ta;
    int td = t - 12;
    td = td < 0 ? 0 : td;
    s += bf2f((unsigned short)x[base + (long)ta * C]) - bf2f((unsigned short)x[base + (long)td * C]);
  }
}

// ================= final time projection =================
__global__ __launch_bounds__(256) void p2_kernel(const float* __restrict__ x,
                                                 const float* __restrict__ W,
                                                 const float* __restrict__ bias,
                                                 float* __restrict__ out) {
  __shared__ float tile[256 * 32];
  int b = blockIdx.x;
  int p0 = blockIdx.y * 8;
  int c = threadIdx.x & 31, pl = threadIdx.x >> 5;
  const float* xb = x + (long)b * cL * cCIN;
  const float* w = W + (long)(p0 + pl) * cL;
  float s = 0.f;
  for (int l0 = 0; l0 < cL; l0 += 256) {
    __syncthreads();
    for (int i = threadIdx.x; i < 256 * 32; i += 256) tile[i] = xb[(long)l0 * 32 + i];
    __syncthreads();
#pragma unroll 8
    for (int l = 0; l < 256; l++) s += tile[l * 32 + c] * w[l0 + l];
  }
  out[((long)b * cPRED + p0 + pl) * cCIN + c] = s + bias[p0 + pl];
}

// ====== fused q-modeproj + complex mode mix; one block per (b,h) ======
// Fsl[e=64][m2=128] = W[h*64+e][:] . Fin_b[m2][:]  (MFMA, identical order to mg64);
// then om[o][x] = sum_e Fsl[e][x] * wc[h][e][o][x]; transposed bf16 store to Gt.
__global__ __launch_bounds__(256) void projmix_kernel(const short* __restrict__ W,
                                                      const short* __restrict__ Fin,
                                                      const float* __restrict__ bias,
                                                      const unsigned short* __restrict__ Wm,
                                                      short* __restrict__ Gt, float scale) {
  __shared__ __align__(16) char smem[51968];
  short* As = (short*)smem;           // 64x64 bf16
  short* Bs = (short*)(smem + 8192);  // 128x64 bf16
  int b = blockIdx.x, h = blockIdx.y;
  const short* Wa = W + (long)(h * 64) * 512;
  const short* Fb = Fin + (long)b * 65536;
  int tid = threadIdx.x;
  int lane = tid & 63;
  int w = tid >> 6;
  int lr = lane & 15, lg = lane >> 4;
  int lrow = lane >> 3;
  int scol = ((lane & 7) * 8) ^ (lrow << 3);
  int swr = (lr & 7) << 3;

  float4v acc[4][2];
#pragma unroll
  for (int i = 0; i < 4; i++)
#pragma unroll
    for (int j = 0; j < 2; j++) acc[i][j] = (float4v){0.f, 0.f, 0.f, 0.f};

  for (int t = 0; t < 8; ++t) {
    int k0 = t << 6;
#pragma unroll
    for (int j = 0; j < 2; j++) { // A: 8 segs (64 rows)
      int seg = w * 2 + j;
      int row = seg * 8 + lrow;
      gld16(Wa + (long)row * 512 + k0 + scol, &As[seg * 512]);
    }
#pragma unroll
    for (int j = 0; j < 4; j++) { // B: 16 segs (128 rows)
      int seg = w * 4 + j;
      int row = seg * 8 + lrow;
      gld16(Fb + (long)row * 512 + k0 + scol, &Bs[seg * 512]);
    }
    asm volatile("s_waitcnt vmcnt(0)" ::: "memory");
    __syncthreads();
#pragma unroll
    for (int ks = 0; ks < 2; ks++) {
      short8v af[4], bfr[2];
#pragma unroll
      for (int mi = 0; mi < 4; mi++)
        af[mi] = *(const short8v*)&As[(mi * 16 + lr) * 64 + ((ks * 32 + lg * 8) ^ swr)];
#pragma unroll
      for (int ni = 0; ni < 2; ni++)
        bfr[ni] = *(const short8v*)&Bs[(w * 32 + ni * 16 + lr) * 64 + ((ks * 32 + lg * 8) ^ swr)];
#pragma unroll
      for (int mi = 0; mi < 4; mi++)
#pragma unroll
        for (int ni = 0; ni < 2; ni++)
          acc[mi][ni] =
              __builtin_amdgcn_mfma_f32_16x16x32_bf16(af[mi], bfr[ni], acc[mi][ni], 0, 0, 0);
    }
    __syncthreads();
  }

  // F-slice -> LDS f32 [64][130] (+ mode-0 bias)
  float* Fsf = (float*)smem;                        // 33280 B
  short(*ot)[72] = (short(*)[72])(smem + 33280);    // 18432 B
#pragma unroll
  for (int mi = 0; mi < 4; mi++) {
#pragma unroll
    for (int i = 0; i < 4; i++) {
      int gr = mi * 16 + lg * 4 + i;
#pragma unroll
      for (int ni = 0; ni < 2; ni++) {
        int gc = w * 32 + ni * 16 + lr;
        float v = acc[mi][ni][i];
        if (gc == 0 && bias) v += 1024.f * bias[h * 64 + gr];
        Fsf[gr * 130 + gc] = v;
      }
    }
  }
  __syncthreads();

  // mix: thread handles (x, 16 o's)
  int x = tid & 63, og = tid >> 6;
  float2 m[16];
#pragma unroll
  for (int i = 0; i < 16; i++) m[i] = make_float2(0.f, 0.f);
  for (int e = 0; e < cE; e++) {
    float2 f = *(const float2*)&Fsf[e * 130 + 2 * x];
#pragma unroll
    for (int i = 0; i < 16; i++) {
      int o = og * 16 + i;
      unsigned int wu = *(const unsigned int*)&Wm[((((long)h * cE + e) * cE + o) * cM + x) * 2];
      float wx = bf2f((unsigned short)wu), wy = bf2f((unsigned short)(wu >> 16));
      m[i].x += f.x * wx - f.y * wy;
      m[i].y += f.x * wy + f.y * wx;
    }
  }
#pragma unroll
  for (int i = 0; i < 16; i++) {
    int o = og * 16 + i;
    ot[2 * x][o] = (short)f2bf(m[i].x * scale);
    ot[2 * x + 1][o] = (short)f2bf(m[i].y * scale);
  }
  __syncthreads();
  short* gb = Gt + (long)b * (M2 * cDM) + h * cE;
  for (int u = tid; u < 1024; u += 256) {
    int row = u >> 3, seg = u & 7;
    *(uint4*)&gb[(long)row * cDM + seg * 8] = *(const uint4*)&ot[row][seg * 8];
  }
}

// ====== fused cross attention (W bf16, 1024 threads, conflict-free LDS layouts) ======
__global__ __launch_bounds__(1024) void fused_cross_kernel(const float* __restrict__ Fq,
                                                           const float* __restrict__ Fk,
                                                           const unsigned short* __restrict__ W,
                                                           short* __restrict__ Gt, float scale) {
  __shared__ __align__(16) char smem[65536];
  float2(*KsT)[cE] = (float2(*)[cE])smem;            // [y][e]
  float2(*qks)[cM] = (float2(*)[cM])(smem + 32768);  // [y][x]
  int b = blockIdx.x, h = blockIdx.y;
  const float* kb = Fk + ((long)b * cDM + h * cE) * M2;
  for (int i = threadIdx.x; i < cE * cM; i += 1024) {
    int e = i >> 6, y = i & 63;
    KsT[y][e] = ((const float2*)(kb + (long)e * M2))[y];
  }
  __syncthreads();
  { // phase 1
    int x = threadIdx.x & 63, yg = threadIdx.x >> 6;
    const float* qb = Fq + ((long)b * cDM + h * cE) * M2;
    float2 acc[4];
#pragma unroll
    for (int i = 0; i < 4; i++) acc[i] = make_float2(0.f, 0.f);
    for (int e = 0; e < cE; e++) {
      float2 q = ((const float2*)(qb + (long)e * M2))[x];
#pragma unroll
      for (int i = 0; i < 4; i++) {
        float2 k = KsT[yg * 4 + i][e];
        acc[i].x += q.x * k.x - q.y * k.y;
        acc[i].y += q.x * k.y + q.y * k.x;
      }
    }
#pragma unroll
    for (int i = 0; i < 4; i++) {
      int y = yg * 4 + i;
      float a = acc[i].x, bi = acc[i].y;
      float re, im;
      float t2a = 2.f * a;
      if (fabsf(t2a) > 60.f) {
        re = t2a > 0.f ? 1.f : -1.f;
        im = 0.f;
      } else {
        float denom = coshf(t2a) + cosf(2.f * bi);
        re = sinhf(t2a) / denom;
        im = sinf(2.f * bi) / denom;
      }
      qks[y][x] = make_float2(re, im);
    }
  }
  __syncthreads();
  // phase 2
  int e = threadIdx.x & 63, xg = threadIdx.x >> 6;
  float2 a2[4];
#pragma unroll
  for (int i = 0; i < 4; i++) a2[i] = make_float2(0.f, 0.f);
  for (int y = 0; y < cM; y++) {
    float2 k = KsT[y][e];
#pragma unroll
    for (int i = 0; i < 4; i++) {
      float2 qk = qks[y][xg * 4 + i];
      a2[i].x += qk.x * k.x - qk.y * k.y;
      a2[i].y += qk.x * k.y + qk.y * k.x;
    }
  }
  __syncthreads();
  float2(*Qv)[cM] = (float2(*)[cM])smem;
#pragma unroll
  for (int i = 0; i < 4; i++) Qv[e][xg * 4 + i] = a2[i];
  __syncthreads();
  { // phase 3
    int x = threadIdx.x & 63, og = threadIdx.x >> 6;
    float2 m[4];
#pragma unroll
    for (int i = 0; i < 4; i++) m[i] = make_float2(0.f, 0.f);
    for (int ee = 0; ee < cE; ee++) {
      float2 f = Qv[ee][x];
#pragma unroll
      for (int i = 0; i < 4; i++) {
        int o = og * 4 + i;
        unsigned int wu = *(const unsigned int*)&W[((((long)h * cE + ee) * cE + o) * cM + x) * 2];
        float wx = bf2f((unsigned short)wu), wy = bf2f((unsigned short)(wu >> 16));
        m[i].x += f.x * wx - f.y * wy;
        m[i].y += f.x * wy + f.y * wx;
      }
    }
    short(*ot)[72] = (short(*)[72])(smem + 32768);
#pragma unroll
    for (int i = 0; i < 4; i++) {
      int o = og * 4 + i;
      ot[2 * x][o] = (short)f2bf(m[i].x * scale);
      ot[2 * x + 1][o] = (short)f2bf(m[i].y * scale);
    }
    __syncthreads();
    short* gb = Gt + (long)b * (M2 * cDM) + h * cE;
    int u = threadIdx.x;
    {
      int row = u >> 3, seg = u & 7;
      *(uint4*)&gb[(long)row * cDM + seg * 8] =
          *(const uint4*)&((short(*)[72])(smem + 32768))[row][seg * 8];
    }
  }
}

// ================= f32 shader GEMM (tiny p1 only) =================
constexpr int GBM = 128, GBN = 128, GBK = 16, LPAD = 132;

__global__ __launch_bounds__(256) void gemm_kernel(const float* __restrict__ A,
                                                   const float* __restrict__ B,
                                                   const float* __restrict__ bias,
                                                   float* __restrict__ C, int M, int N, int K) {
  __shared__ float As[GBK][LPAD];
  __shared__ float Bs[GBK][LPAD];
  int n0 = blockIdx.x * GBN, m0 = blockIdx.y * GBM;
  int tid = threadIdx.x;
  int tx = tid & 15, ty = tid >> 4;
  float acc[8][8];
#pragma unroll
  for (int i = 0; i < 8; i++)
#pragma unroll
    for (int j = 0; j < 8; j++) acc[i][j] = 0.f;

  for (int k0 = 0; k0 < K; k0 += GBK) {
#pragma unroll
    for (int p = 0; p < 8; p++) {
      int i = p * 256 + tid;
      int mm = i >> 4, kk = i & 15;
      int gm = m0 + mm;
      As[kk][mm] = (gm < M && k0 + kk < K) ? A[(long)gm * K + k0 + kk] : 0.f;
    }
#pragma unroll
    for (int p = 0; p < 8; p++) {
      int i = p * 256 + tid;
      int nn = i >> 4, kk = i & 15;
      int gn = n0 + nn;
      Bs[kk][nn] = (gn < N && k0 + kk < K) ? B[(long)gn * K + k0 + kk] : 0.f;
    }
    __syncthreads();
#pragma unroll
    for (int kk = 0; kk < GBK; kk++) {
      float a[8], bb[8];
      *(float4*)&a[0] = *(const float4*)&As[kk][ty * 8];
      *(float4*)&a[4] = *(const float4*)&As[kk][ty * 8 + 4];
      *(float4*)&bb[0] = *(const float4*)&Bs[kk][tx * 8];
      *(float4*)&bb[4] = *(const float4*)&Bs[kk][tx * 8 + 4];
#pragma unroll
      for (int i = 0; i < 8; i++)
#pragma unroll
        for (int j = 0; j < 8; j++) acc[i][j] += a[i] * bb[j];
    }
    __syncthreads();
  }

  for (int i = 0; i < 8; i++) {
    int gm = m0 + ty * 8 + i;
    if (gm >= M) break;
    long rowoff = (long)gm * N;
    for (int j = 0; j < 8; j++) {
      int gn = n0 + tx * 8 + j;
      if (gn < N) C[rowoff + gn] = acc[i][j] + (bias ? bias[gn] : 0.f);
    }
  }
}

// ===== bf16 MFMA GEMM 256x128 tile, 512 threads / 8 waves (ffn + embedding) =====
__global__ __launch_bounds__(512) void mfma_gemm256(
    const short* __restrict__ A, const short* __restrict__ B, const float* __restrict__ bias,
    const short* __restrict__ addendb, const float* __restrict__ pe, float* __restrict__ Cf,
    short* __restrict__ Cb, int M, int N, int K, int lda, int relu, int ldc) {
  __shared__ __align__(16) short As[16384]; // 256 x 64
  __shared__ __align__(16) short Bs[8192];  // 128 x 64
  int nwg = gridDim.x * gridDim.y;
  int orig = blockIdx.x + gridDim.x * blockIdx.y;
  int q = nwg >> 3, r = nwg & 7;
  int xcd = orig & 7, ii = orig >> 3;
  int flat = (xcd < r ? xcd * (q + 1) : r * (q + 1) + (xcd - r) * q) + ii;
  int bx = flat % (int)gridDim.x;
  int by = flat / (int)gridDim.x;

  int n0 = bx * 128, m0 = by * 256;
  int tid = threadIdx.x;
  int lane = tid & 63;
  int w = tid >> 6;
  int wm = w >> 1;
  int wn = w & 1;
  int lr = lane & 15, lg = lane >> 4;
  int lrow = lane >> 3;
  int scol = ((lane & 7) * 8) ^ (lrow << 3);

  float4v acc[4][4];
#pragma unroll
  for (int i = 0; i < 4; i++)
#pragma unroll
    for (int j = 0; j < 4; j++) acc[i][j] = (float4v){0.f, 0.f, 0.f, 0.f};

  int nk = K >> 6;
  int swr = (lr & 7) << 3;
  for (int t = 0; t < nk; ++t) {
    int k0 = t << 6;
#pragma unroll
    for (int j = 0; j < 4; j++) {
      int seg = w * 4 + j;
      int row = seg * 8 + lrow;
      gld16(A + (long)(m0 + row) * lda + k0 + scol, &As[seg * 512]);
    }
#pragma unroll
    for (int j = 0; j < 2; j++) {
      int seg = w * 2 + j;
      int row = seg * 8 + lrow;
      gld16(B + (long)(n0 + row) * K + k0 + scol, &Bs[seg * 512]);
    }
    asm volatile("s_waitcnt vmcnt(0)" ::: "memory");
    __syncthreads();
#pragma unroll
    for (int ks = 0; ks < 2; ks++) {
      short8v af[4], bfr[4];
#pragma unroll
      for (int mi = 0; mi < 4; mi++)
        af[mi] = *(const short8v*)&As[(wm * 64 + mi * 16 + lr) * 64 + ((ks * 32 + lg * 8) ^ swr)];
#pragma unroll
      for (int ni = 0; ni < 4; ni++)
        bfr[ni] = *(const short8v*)&Bs[(wn * 64 + ni * 16 + lr) * 64 + ((ks * 32 + lg * 8) ^ swr)];
#pragma unroll
      for (int mi = 0; mi < 4; mi++)
#pragma unroll
        for (int ni = 0; ni < 4; ni++)
          acc[mi][ni] =
              __builtin_amdgcn_mfma_f32_16x16x32_bf16(af[mi], bfr[ni], acc[mi][ni], 0, 0, 0);
    }
    __syncthreads();
  }

#pragma unroll
  for (int mi = 0; mi < 4; mi++) {
#pragma unroll
    for (int i = 0; i < 4; i++) {
      int gr = m0 + wm * 64 + mi * 16 + lg * 4 + i;
      long rowoff = (long)gr * ldc;
#pragma unroll
      for (int ni = 0; ni < 4; ni++) {
        int gc = n0 + wn * 64 + ni * 16 + lr;
        float v = acc[mi][ni][i];
        if (bias) v += bias[gc];
        if (pe) v += pe[((gr & (cL - 1)) << 9) + gc];
        if (addendb) v += bf2f((unsigned short)addendb[rowoff + gc]);
        if (relu) v = fmaxf(v, 0.f);
        if (Cf) Cf[rowoff + gc] = v;
        if (Cb) Cb[rowoff + gc] = (short)f2bf(v);
      }
    }
  }
}

// ===== bf16 MFMA GEMM 64x64 (small/latency-bound shapes; full epilogue; zsplit) =====
__global__ __launch_bounds__(256) void mfma_gemm64(
    const short* __restrict__ A, const short* __restrict__ B, const float* __restrict__ bias,
    const float* __restrict__ addf, const short* __restrict__ addb,
    const float* __restrict__ m0b, float* __restrict__ Cf, short* __restrict__ Cb, int M, int N,
    int K, int lda, long sA, long sB, long sC, int Nreal, int ldc, int amode,
    const short* __restrict__ A2, const short* __restrict__ B2, const float* __restrict__ m0b2,
    float* __restrict__ Cf2, int zsplit) {
  __shared__ __align__(16) short As[4096];
  __shared__ __align__(16) short Bs[4096];
  int nwg = gridDim.x * gridDim.y * gridDim.z;
  int orig = blockIdx.x + gridDim.x * (blockIdx.y + gridDim.y * blockIdx.z);
  int q = nwg >> 3, r = nwg & 7;
  int xcd = orig & 7, ii = orig >> 3;
  int flat = (xcd < r ? xcd * (q + 1) : r * (q + 1) + (xcd - r) * q) + ii;
  int bx = flat % (int)gridDim.x;
  int tmp = flat / (int)gridDim.x;
  int by = tmp % (int)gridDim.y;
  int bz = tmp / (int)gridDim.y;

  int z = bz;
  if (zsplit > 0 && bz >= zsplit) {
    A = A2;
    B = B2;
    m0b = m0b2;
    Cf = Cf2;
    z = bz - zsplit;
  }
  A += (long)z * sA;
  B += (long)z * sB;
  if (Cf) Cf += (long)z * sC;
  if (Cb) Cb += (long)z * sC;
  const float* Ad = addf ? addf + (long)z * sC : nullptr;
  const short* Adb = addb ? addb + (long)z * sC : nullptr;
  int n0 = bx * 64, m0 = by * 64;
  int tid = threadIdx.x;
  int lane = tid & 63;
  int w = tid >> 6;
  int wm = w & 1, wn = w >> 1;
  int lr = lane & 15, lg = lane >> 4;
  int lrow = lane >> 3;
  int scol = ((lane & 7) * 8) ^ (lrow << 3);

  float4v acc[2][2];
#pragma unroll
  for (int i = 0; i < 2; i++)
#pragma unroll
    for (int j = 0; j < 2; j++) acc[i][j] = (float4v){0.f, 0.f, 0.f, 0.f};

  int nk = K >> 6;
  int swr = (lr & 7) << 3;
  for (int t = 0; t < nk; ++t) {
    int k0 = t << 6;
#pragma unroll
    for (int j = 0; j < 2; j++) {
      int seg = w * 2 + j;
      int row = seg * 8 + lrow;
      const short* ga;
      if (amode == 0) {
        ga = A + (long)(m0 + row) * lda + k0 + scol;
      } else {
        int r2 = m0 + row;
        int bb = r2 >> 10, tt = r2 & 1023;
        int jj = k0 >> 9, c0 = k0 & 511;
        ga = A + ((((long)(bb << 10)) | ((tt + jj + 1023) & 1023)) << 9) + c0 + scol;
      }
      gld16(ga, &As[seg * 512]);
      gld16(B + (long)(n0 + row) * K + k0 + scol, &Bs[seg * 512]);
    }
    asm volatile("s_waitcnt vmcnt(0)" ::: "memory");
    __syncthreads();
#pragma unroll
    for (int ks = 0; ks < 2; ks++) {
      short8v af[2], bfr[2];
#pragma unroll
      for (int mi = 0; mi < 2; mi++)
        af[mi] = *(const short8v*)&As[(wm * 32 + mi * 16 + lr) * 64 + ((ks * 32 + lg * 8) ^ swr)];
#pragma unroll
      for (int ni = 0; ni < 2; ni++)
        bfr[ni] = *(const short8v*)&Bs[(wn * 32 + ni * 16 + lr) * 64 + ((ks * 32 + lg * 8) ^ swr)];
#pragma unroll
      for (int mi = 0; mi < 2; mi++)
#pragma unroll
        for (int ni = 0; ni < 2; ni++)
          acc[mi][ni] =
              __builtin_amdgcn_mfma_f32_16x16x32_bf16(af[mi], bfr[ni], acc[mi][ni], 0, 0, 0);
    }
    __syncthreads();
  }

#pragma unroll
  for (int mi = 0; mi < 2; mi++) {
#pragma unroll
    for (int i = 0; i < 4; i++) {
      int gr = m0 + wm * 32 + mi * 16 + lg * 4 + i;
      long rowoff = (long)gr * ldc;
#pragma unroll
      for (int ni = 0; ni < 2; ni++) {
        int gc = n0 + wn * 32 + ni * 16 + lr;
        if (gc < Nreal) {
          float v = acc[mi][ni][i];
          if (bias) v += bias[gc];
          if (m0b && gc == 0) v += 1024.f * m0b[gr];
          if (Ad) v += Ad[rowoff + gc];
          if (Adb) v += bf2f((unsigned short)Adb[rowoff + gc]);
          if (Cf) Cf[rowoff + gc] = v;
          if (Cb) Cb[rowoff + gc] = (short)f2bf(v);
        }
      }
    }
  }
}

} // namespace

extern "C" void kernel_launch(void* const* d_in, const int* in_sizes, int n_in, void* d_out,
                              int out_size, void* d_ws, size_t ws_size, hipStream_t stream) {
  const float* x_enc = (const float*)d_in[0];
  const float* tok_W = (const float*)d_in[1];
  const float* enc_Wq = (const float*)d_in[2];
  const float* enc_Wo = (const float*)d_in[5];
  const float* enc_bq = (const float*)d_in[6];
  const float* enc_bo = (const float*)d_in[9];
  const float* dsWq = (const float*)d_in[10];
  const float* dsWo = (const float*)d_in[13];
  const float* dsbq = (const float*)d_in[14];
  const float* dsbo = (const float*)d_in[17];
  const float* dcWq = (const float*)d_in[18];
  const float* dcWk = (const float*)d_in[19];
  const float* dcWo = (const float*)d_in[21];
  const float* dcbq = (const float*)d_in[22];
  const float* dcbk = (const float*)d_in[23];
  const float* dcbo = (const float*)d_in[25];
  const float* enc_c1W = (const float*)d_in[26];
  const float* enc_c1b = (const float*)d_in[27];
  const float* enc_c2W = (const float*)d_in[28];
  const float* enc_c2b = (const float*)d_in[29];
  const float* dec_c1W = (const float*)d_in[30];
  const float* dec_c1b = (const float*)d_in[31];
  const float* dec_c2W = (const float*)d_in[32];
  const float* dec_c2b = (const float*)d_in[33];
  const float* dec_trW = (const float*)d_in[34];
  const float* fb_enc = (const float*)d_in[35];
  const float* fb_dec = (const float*)d_in[36];
  const float* fc_w = (const float*)d_in[37];
  const float* p1W = (const float*)d_in[38];
  const float* p1b = (const float*)d_in[39];
  const float* p2W = (const float*)d_in[40];
  const float* p2b = (const float*)d_in[41];
  const float* p3W = (const float*)d_in[42];
  const float* p3b = (const float*)d_in[43];

  constexpr long MIXW = 8L * 64 * 64 * 64 * 2;

  // ---- layout sizing (dry-run) ----
  auto layout_bytes = [&](long BG, long RH) -> size_t {
    size_t t = 0;
    auto add = [&](size_t b) { t = (t + b + 255) & ~(size_t)255; };
    add(2 * 262144 * 2); add(2 * 262144 * 2);
    add(262144 * 2); add(262144 * 2); add(262144 * 2); add(262144 * 2); add(262144 * 2);
    add(2 * 1048576 * 2); add(2 * 1048576 * 2); add(1048576 * 2); add(1048576 * 2);
    add(131072 * 2); add(131072 * 2); add(65536 * 2); add(196608 * 2); add(65536 * 2);
    add(128 * 4); add(524288 * 4);
    add(MIXW * 2); add(MIXW * 2); add(MIXW * 2);
    long GA = BG * cL * cDM;
    add(GA * 2); add(GA * 2); add(GA * 2); add(GA * 2); add(GA * 2); // Eb Xb Ab Sb Yb
    add(BG * cL * 128 * 2);
    size_t ub = (size_t)GA * 2;
    size_t hd = (size_t)RH * cDFF * 2;
    add(ub > hd ? ub : hd);
    add(BG * 65536 * 4); add(BG * 65536 * 4);
    add(BG * 65536 * 2); add(BG * 65536 * 2); add(BG * 65536 * 2); add(BG * 65536 * 2);
    add(BG * cL * cCIN * 4); add(BG * cL * cCIN * 4); add(BG * cL * cCIN * 4);
    return t;
  };
  int BG = cB;
  while (BG > 1 && layout_bytes(BG, 512) > ws_size) BG >>= 1;
  long RH = (long)BG * cL;
  while (RH > 512 && layout_bytes(BG, RH) > ws_size) RH >>= 1;

  long GBL = (long)BG * cL;
  char* base = (char*)d_ws;
  size_t off = 0;
  auto alloc = [&](size_t bytes) -> void* {
    void* p = base + off;
    off = (off + bytes + 255) & ~(size_t)255;
    return p;
  };
  short* WqbE = (short*)alloc(2 * 262144 * 2);
  short* WobE = (short*)alloc(2 * 262144 * 2);
  short* dsWqb = (short*)alloc(262144 * 2);
  short* dsWob = (short*)alloc(262144 * 2);
  short* dcWqb = (short*)alloc(262144 * 2);
  short* dcWkb = (short*)alloc(262144 * 2);
  short* dcWob = (short*)alloc(262144 * 2);
  short* c1bE = (short*)alloc(2 * 1048576 * 2);
  short* c2bE = (short*)alloc(2 * 1048576 * 2);
  short* c1bD = (short*)alloc(1048576 * 2);
  short* c2bD = (short*)alloc(1048576 * 2);
  short* basisdb = (short*)alloc(131072 * 2);
  short* basisib = (short*)alloc(131072 * 2);
  short* Bpadb = (short*)alloc(65536 * 2);
  short* Wtr3b = (short*)alloc(196608 * 2);
  short* p3padb = (short*)alloc(65536 * 2);
  float* p3bpadf = (float*)alloc(128 * 4);
  float* pe = (float*)alloc(524288 * 4);
  short* fbEb = (short*)alloc(MIXW * 2);
  short* fbDb = (short*)alloc(MIXW * 2);
  short* fcwb = (short*)alloc(MIXW * 2);
  long GA = GBL * cDM;
  short* Eb = (short*)alloc(GA * 2);
  short* Xb = (short*)alloc(GA * 2);
  short* Ab = (short*)alloc(GA * 2);
  short* Sb = (short*)alloc(GA * 2);
  short* Yb = (short*)alloc(GA * 2);
  short* winb = (short*)alloc(GBL * 128 * 2);
  size_t ubsz = (size_t)GA * 2;
  size_t hdsz = (size_t)RH * cDFF * 2;
  short* UB = (short*)alloc(ubsz > hdsz ? ubsz : hdsz);
  short* Tb = UB;
  short* HDb = UB;
  float* Fq = (float*)alloc((size_t)BG * 65536 * 4);
  float* Fk = (float*)alloc((size_t)BG * 65536 * 4);
  short* FEb = (short*)alloc((size_t)BG * 65536 * 2);
  short* FXb = (short*)alloc((size_t)BG * 65536 * 2);
  short* Gtb = (short*)alloc((size_t)BG * 65536 * 2);
  short* Hb = (short*)alloc((size_t)BG * 65536 * 2);
  float* TRD = (float*)alloc(GBL * cCIN * 4);
  float* O1 = (float*)alloc(GBL * cCIN * 4);
  float* O2 = (float*)alloc(GBL * cCIN * 4);

  auto mg256 = [&](const short* Am, const short* Bm, const float* bias, const short* adb,
                   const float* peA, float* Cf, short* Cb, int Mm, int Nn, int Kk, int lda,
                   int relu, int ldc) {
    dim3 g(Nn / 128, Mm / 256);
    mfma_gemm256<<<g, 512, 0, stream>>>(Am, Bm, bias, adb, peA, Cf, Cb, Mm, Nn, Kk, lda, relu,
                                        ldc);
  };
  auto mg64 = [&](const short* Am, const short* Bm, const float* bias, const float* addf,
                  const short* addb, const float* m0b, float* Cf, short* Cb, int Mm, int Nn,
                  int Kk, int lda, long sA, long sB, long sC, int batch, int Nreal, int ldc,
                  int amode) {
    dim3 g(Nn / 64, Mm / 64, batch);
    mfma_gemm64<<<g, 256, 0, stream>>>(Am, Bm, bias, addf, addb, m0b, Cf, Cb, Mm, Nn, Kk, lda,
                                       sA, sB, sC, Nreal, ldc, amode, nullptr, nullptr, nullptr,
                                       nullptr, 0);
  };
  auto decompf = [&](const float* x, float* maf, long total, int C_) {
    int n8 = (int)(total / 8);
    decomp_kernel<<<(n8 + 255) / 256, 256, 0, stream>>>(x, maf, n8, C_);
  };
  auto decompb = [&](const short* x, short* sb, short* mab, int maacc, long total, int C_) {
    int n8 = (int)(total / 8);
    decompb_kernel<<<(n8 + 255) / 256, 256, 0, stream>>>(x, sb, mab, maacc, n8, C_);
  };
  auto dft = [&](const short* srcb, short* Fout) {
    transpose_bf<<<dim3(8, 16, BG), 256, 0, stream>>>(srcb, Tb);
    mg64(basisdb, Tb, nullptr, nullptr, nullptr, nullptr, nullptr, Fout, M2, cDM, cL, cL, 0,
         (long)cDM * cL, 65536, BG, cDM, cDM, 0);
  };
  auto projmix = [&](const short* Wq, const short* Fin, const float* bq, const short* Wmix) {
    projmix_kernel<<<dim3(BG, cH), 256, 0, stream>>>(Wq, Fin, bq, (const unsigned short*)Wmix,
                                                     Gtb, 1.0f);
  };
  auto modeproj = [&](const short* Wb, const short* Fin, const float* m0b, float* Cf, short* Cb) {
    mg64(Wb, Fin, nullptr, nullptr, nullptr, m0b, Cf, Cb, cDM, M2, cDM, cDM, 0, 65536, 65536, BG,
         M2, M2, 0);
  };
  auto modeproj2 = [&](const short* Wa, const short* Fa, const float* ba, float* Ca,
                       const short* Wb2, const short* Fb2, const float* bb2, float* Cb2) {
    dim3 g(M2 / 64, cDM / 64, 2 * BG);
    mfma_gemm64<<<g, 256, 0, stream>>>(Wa, Fa, nullptr, nullptr, nullptr, ba, Ca, nullptr, cDM,
                                       M2, cDM, cDM, 0, 65536, 65536, M2, M2, 0, Wb2, Fb2, bb2,
                                       Cb2, BG);
  };
  auto idft = [&](const short* Hin, const float* bias, const short* adb, short* Cbout) {
    mg64(basisib, Hin, bias, nullptr, adb, nullptr, nullptr, Cbout, cL, cDM, M2, M2, 0, 65536,
         (long)cL * cDM, BG, cDM, cDM, 0);
  };
  auto ffn = [&](const short* inb, const short* addb, short* outb, const short* c1w,
                 const float* c1bias, const short* c2w, const float* c2bias) {
    for (long r = 0; r < GBL; r += RH) {
      mg256(inb + r * cDM, c1w, c1bias, nullptr, nullptr, nullptr, HDb, (int)RH, cDFF, cDM, cDM,
            1, cDFF);
      mg256(HDb, c2w, c2bias, addb + r * cDM, nullptr, nullptr, outb + r * cDM, (int)RH, cDM,
            cDFF, cDFF, 0, cDM);
    }
  };
  auto trendg = [&](const short* mab) {
    mg64(mab, Wtr3b, nullptr, TRD, nullptr, nullptr, TRD, nullptr, (int)GBL, 64, 1536, 512, 0, 0,
         0, 1, cCIN, cCIN, 1);
  };

  // ---- one-time setup ----
  basis_kernel<<<(M2 * cL) / 256, 256, 0, stream>>>(basisdb, basisib);
  pe_kernel<<<(cL * cDM) / 256, 256, 0, stream>>>(pe);
  prep_kernel<<<768, 256, 0, stream>>>(tok_W, dec_trW, p3W, p3b, Bpadb, Wtr3b, p3padb, p3bpadf);
  {
    CvtArgs ca;
    const float* srcs[NJOB] = {enc_Wq, enc_Wo, dsWq, dsWo, dcWq, dcWk, dcWo,
                               enc_c1W, enc_c2W, dec_c1W, dec_c2W, fb_enc, fb_dec, fc_w};
    short* dsts[NJOB] = {WqbE, WobE, dsWqb, dsWob, dcWqb, dcWkb, dcWob,
                         c1bE, c2bE, c1bD, c2bD, fbEb, fbDb, fcwb};
    int ns[NJOB] = {524288, 524288, 262144, 262144, 262144, 262144, 262144,
                    2097152, 2097152, 1048576, 1048576, (int)MIXW, (int)MIXW, (int)MIXW};
    for (int j = 0; j < NJOB; j++) {
      ca.src[j] = srcs[j];
      ca.dst[j] = dsts[j];
      ca.n[j] = ns[j];
    }
    cvtm_kernel<<<dim3(256, NJOB), 256, 0, stream>>>(ca);
  }

  for (int b0 = 0; b0 < cB; b0 += BG) {
    const float* xg = x_enc + (long)b0 * cL * cCIN;

    decompf(xg, TRD, GBL * cCIN, cCIN); // trend_init -> TRD (f32)
    winbuild_kernel<<<(int)(GBL * 32 / 256), 256, 0, stream>>>(xg, winb);
    mg256(winb, Bpadb, nullptr, nullptr, pe, nullptr, Eb, (int)GBL, cDM, 128, 128, 0, cDM);

    // ---- encoder ----
    for (int l = 0; l < 2; l++) {
      dft(Eb, FEb);
      projmix(WqbE + (long)l * 262144, FEb, enc_bq + l * cDM, fbEb);  // q-proj + mix -> Gtb
      modeproj(WobE + (long)l * 262144, Gtb, nullptr, nullptr, Hb);
      idft(Hb, enc_bo + l * cDM, Eb, Yb);                     // x + attn -> Yb (bf16)
      decompb(Yb, Xb, nullptr, 0, GA, cDM);                   // h -> Xb
      ffn(Xb, Xb, Yb, c1bE + (long)l * 1048576, enc_c1b + l * cDFF, c2bE + (long)l * 1048576,
          enc_c2b + l * cDM);                                 // h + y -> Yb
      decompb(Yb, Eb, nullptr, 0, GA, cDM);                   // stream -> Eb
    }

    // ---- decoder ----
    dft(Eb, FEb);
    projmix(dsWqb, FEb, dsbq, fbDb);                          // dec-self q-proj + mix -> Gtb
    modeproj(dsWob, Gtb, nullptr, nullptr, Hb);
    idft(Hb, dsbo, Eb, Yb);                                   // x1 -> Yb
    decompb(Yb, Xb, Sb, 0, GA, cDM);                          // x2 -> Xb; ma -> Sb (fresh)
    dft(Xb, FXb);
    modeproj2(dcWqb, FXb, dcbq, Fq, dcWkb, FEb, dcbk, Fk);
    fused_cross_kernel<<<dim3(BG, cH), 1024, 0, stream>>>(Fq, Fk, (const unsigned short*)fcwb,
                                                          Gtb, 1.0f / (float)(cDM * cDM));
    modeproj(dcWob, Gtb, nullptr, nullptr, Hb);
    idft(Hb, dcbo, Xb, Yb);                                   // x3 -> Yb
    decompb(Yb, Ab, Sb, 1, GA, cDM);                          // x4 -> Ab; ma += Sb
    ffn(Ab, Ab, Yb, c1bD, dec_c1b, c2bD, dec_c2b);            // x4 + y -> Yb
    decompb(Yb, Xb, Sb, 1, GA, cDM);                          // x5 -> Xb; ma += Sb
    trendg(Sb);                                               // conv(t1+t2+t3)

    // ---- final projections ----
    mg64(Xb, p3padb, p3bpadf, TRD, nullptr, nullptr, O1, nullptr, (int)GBL, 64, cDM, cDM, 0, 0,
         0, 1, cCIN, cCIN, 0);                                // trend + x@p3
    gemm_kernel<<<dim3(1, (int)(GBL / 128)), 256, 0, stream>>>(O1, p1W, p1b, O2, (int)GBL, cCIN,
                                                               cCIN);
    p2_kernel<<<dim3(BG, 32), 256, 0, stream>>>(O2, p2W, p2b,
                                                (float*)d_out + (long)b0 * cPRED * cCIN);
  }
}